// Round 5
// baseline (1321.600 us; speedup 1.0000x reference)
//
#include <hip/hip_runtime.h>
#include <cstdint>
#include <cstddef>

#define NPTS 4096
#define CDIM 64
#define BDIM 8
#define KNN  20
#define ODIM 64
#define NT   32          // 128-col tiles per batch

typedef unsigned long long u64;
typedef unsigned int u32;
typedef _Float16 f16;
using f16x8 = __attribute__((ext_vector_type(8))) _Float16;
using f32x4 = __attribute__((ext_vector_type(4))) float;
#define SENT (~0ull)
#define FINF (__builtin_inff())

__device__ __forceinline__ int swz(int r) { return (r & 7) ^ ((r >> 3) & 7); }

// order-preserving float->u32 flip (ascending float == ascending u32)
__device__ __forceinline__ unsigned flip_f32(float d) {
  unsigned bits = __float_as_uint(d);
  return bits ^ (unsigned)(((int)bits >> 31) | 0x80000000u);
}

// wave64 all-reduce min (DPP), result uniform via readlane 63  (R3-validated)
__device__ __forceinline__ unsigned wave_min_u32(unsigned v) {
  unsigned t;
  t = (unsigned)__builtin_amdgcn_update_dpp((int)v, (int)v, 0x111, 0xF, 0xF, false); v = t < v ? t : v;
  t = (unsigned)__builtin_amdgcn_update_dpp((int)v, (int)v, 0x112, 0xF, 0xF, false); v = t < v ? t : v;
  t = (unsigned)__builtin_amdgcn_update_dpp((int)v, (int)v, 0x114, 0xF, 0xF, false); v = t < v ? t : v;
  t = (unsigned)__builtin_amdgcn_update_dpp((int)v, (int)v, 0x118, 0xF, 0xF, false); v = t < v ? t : v;
  t = (unsigned)__builtin_amdgcn_update_dpp((int)v, (int)v, 0x142, 0xA, 0xF, false); v = t < v ? t : v;
  t = (unsigned)__builtin_amdgcn_update_dpp((int)v, (int)v, 0x143, 0xC, 0xF, false); v = t < v ? t : v;
  return (unsigned)__builtin_amdgcn_readlane((int)v, 63);
}

// 16-lane (quarter) all-reduce min: quad xor1, xor2, then ror4, ror8.
__device__ __forceinline__ float rmin16f(float v) {
  int t;
  t = __builtin_amdgcn_update_dpp(__float_as_int(v), __float_as_int(v), 0xB1,  0xF, 0xF, false);
  v = fminf(v, __int_as_float(t));
  t = __builtin_amdgcn_update_dpp(__float_as_int(v), __float_as_int(v), 0x4E,  0xF, 0xF, false);
  v = fminf(v, __int_as_float(t));
  t = __builtin_amdgcn_update_dpp(__float_as_int(v), __float_as_int(v), 0x124, 0xF, 0xF, false);
  v = fminf(v, __int_as_float(t));
  t = __builtin_amdgcn_update_dpp(__float_as_int(v), __float_as_int(v), 0x128, 0xF, 0xF, false);
  v = fminf(v, __int_as_float(t));
  return v;
}
__device__ __forceinline__ u32 rmin16u(u32 v) {
  int t;
  t = __builtin_amdgcn_update_dpp((int)v, (int)v, 0xB1,  0xF, 0xF, false); v = ((u32)t < v) ? (u32)t : v;
  t = __builtin_amdgcn_update_dpp((int)v, (int)v, 0x4E,  0xF, 0xF, false); v = ((u32)t < v) ? (u32)t : v;
  t = __builtin_amdgcn_update_dpp((int)v, (int)v, 0x124, 0xF, 0xF, false); v = ((u32)t < v) ? (u32)t : v;
  t = __builtin_amdgcn_update_dpp((int)v, (int)v, 0x128, 0xF, 0xF, false); v = ((u32)t < v) ? (u32)t : v;
  return v;
}

// branchless stable insert into ascending sorted-5 (float keys + u32 m);
// dsc tracks min discarded key (exactness bound for drained lanes).
__device__ __forceinline__ void ins5(float& k0, float& k1, float& k2, float& k3, float& k4,
                                     u32& m0, u32& m1, u32& m2, u32& m3, u32& m4,
                                     float& dsc, float v, u32 mv) {
  bool c0 = v < k0, c1 = v < k1, c2 = v < k2, c3 = v < k3, c4 = v < k4;
  dsc = fminf(dsc, fmaxf(v, k4));
  float n1 = __builtin_amdgcn_fmed3f(v, k0, k1);
  float n2 = __builtin_amdgcn_fmed3f(v, k1, k2);
  float n3 = __builtin_amdgcn_fmed3f(v, k2, k3);
  float n4 = __builtin_amdgcn_fmed3f(v, k3, k4);
  u32 p1 = c1 ? (c0 ? m0 : mv) : m1;
  u32 p2 = c2 ? (c1 ? m1 : mv) : m2;
  u32 p3 = c3 ? (c2 ? m2 : mv) : m3;
  u32 p4 = c4 ? (c3 ? m3 : mv) : m4;
  k0 = fminf(v, k0); k1 = n1; k2 = n2; k3 = n3; k4 = n4;
  m0 = c0 ? mv : m0; m1 = p1; m2 = p2; m3 = p3; m4 = p4;
}

// branchless insert into ascending sorted-4 (u64 keys) — R3-validated
__device__ __forceinline__ void ins4(u64& l0, u64& l1, u64& l2, u64& l3, u64 v) {
  u64 a = v < l0 ? v : l0;
  u64 b = v < l0 ? l0 : v;
  u64 c = b < l1 ? b : l1;
  u64 d = b < l1 ? l1 : b;
  u64 e = d < l2 ? d : l2;
  u64 f = d < l2 ? l2 : d;
  u64 g = f < l3 ? f : l3;
  l0 = a; l1 = c; l2 = e; l3 = g;
}

// ---------------------------------------------------------------------------
// sq[b][n] = sum_c x[b][c][n]^2   (ascending c — bit-identical to R3/R4)
// ---------------------------------------------------------------------------
__global__ __launch_bounds__(256) void sq_kernel(const float* __restrict__ x,
                                                 float* __restrict__ sq) {
  int g = blockIdx.x * 256 + threadIdx.x;
  int b = g >> 12, n = g & (NPTS - 1);
  const float* xb = x + (size_t)b * CDIM * NPTS + n;
  float s = 0.f;
  #pragma unroll
  for (int c = 0; c < CDIM; ++c) { float v = xb[(size_t)c * NPTS]; s += v * v; }
  sq[g] = s;
}

// ---------------------------------------------------------------------------
// prep: build per-(b,tile) fp16 hi/lo images in the EXACT swizzled LDS byte
// layout: byte(n',c) = (n'*128 + c*2) ^ (swz(n')<<4); hi at +0, lo at +16384.
// Staging in fused_knn is then a pure linear 32KB copy.
// ---------------------------------------------------------------------------
__global__ __launch_bounds__(256) void prep_kernel(const float* __restrict__ x,
                                                   char* __restrict__ img) {
  __shared__ char limg[32768];
  const int tid = threadIdx.x;
  const int b = blockIdx.x >> 5;       // NT=32 tiles per batch
  const int t = blockIdx.x & 31;
  const int np = tid & 127;
  const int ch = tid >> 7;
  const float* xb = x + (size_t)b * CDIM * NPTS + t * 128 + np;
  const int sw = swz(np) << 4;
  #pragma unroll
  for (int cc = 0; cc < 32; ++cc) {
    int c = ch * 32 + cc;
    float v = xb[(size_t)c * NPTS];
    f16 h = (f16)v;
    f16 l = (f16)(v - (float)h);
    int byt = (np * 128 + c * 2) ^ sw;
    *(f16*)(limg + byt) = h;
    *(f16*)(limg + 16384 + byt) = l;
  }
  __syncthreads();
  char* dst = img + (size_t)blockIdx.x * 32768;
  #pragma unroll
  for (int i = 0; i < 8; ++i)
    *(float4*)(dst + i * 4096 + tid * 16) = *(const float4*)(limg + i * 4096 + tid * 16);
}

// ---------------------------------------------------------------------------
// Fused dist+top20. Block = 64 rows of one batch; sweep 32 col-tiles.
// Per wave: 16 rows; MFMA fp16x3 (order identical to R4 => bit-identical
// dists); stream accumulator values into per-(row,lane-of-16) sorted-5;
// 20 rounds of 16-lane DPP min (dist,m)-lexicographic; flag rows whose
// winner could be hidden by a drained lane's discards (exact bound).
// ---------------------------------------------------------------------------
__global__ __launch_bounds__(256) void fused_knn(const char* __restrict__ img,
                                                 const float* __restrict__ sq,
                                                 int* __restrict__ knn,
                                                 int* __restrict__ flags) {
  __shared__ char XB[32768];
  __shared__ char XA[16384];
  __shared__ float sqM[128];

  const int tid = threadIdx.x;
  const int lane = tid & 63;
  const int w = tid >> 6;
  const int q = lane >> 4;
  const int s = lane & 15;

  const int blk = blockIdx.x;
  const int b  = blk >> 6;
  const int r0 = (blk & 63) * 64;
  const char* imgb = img + (size_t)b * (NT * 32768);
  const float* sqb = sq + (size_t)b * NPTS;

  {  // stage XA (block's 64 rows; swz(64+j)==swz(j) keeps layout valid) + XB(0) + sqM(0)
    const char* srcA = imgb + (r0 >> 7) * 32768 + (r0 & 64) * 128;
    float4 pa0 = *(const float4*)(srcA + tid * 16);
    float4 pa1 = *(const float4*)(srcA + 4096 + tid * 16);
    float4 pa2 = *(const float4*)(srcA + 16384 + tid * 16);
    float4 pa3 = *(const float4*)(srcA + 16384 + 4096 + tid * 16);
    float4 pb[8];
    #pragma unroll
    for (int i = 0; i < 8; ++i) pb[i] = *(const float4*)(imgb + i * 4096 + tid * 16);
    *(float4*)(XA + tid * 16) = pa0;
    *(float4*)(XA + 4096 + tid * 16) = pa1;
    *(float4*)(XA + 8192 + tid * 16) = pa2;
    *(float4*)(XA + 12288 + tid * 16) = pa3;
    #pragma unroll
    for (int i = 0; i < 8; ++i) *(float4*)(XB + i * 4096 + tid * 16) = pb[i];
    if (tid < 128) sqM[tid] = sqb[tid];
  }

  float sqr[4];
  #pragma unroll
  for (int reg = 0; reg < 4; ++reg) sqr[reg] = sqb[r0 + w * 16 + q * 4 + reg];

  float lk[4][5]; u32 lm[4][5]; float dsc[4];
  #pragma unroll
  for (int reg = 0; reg < 4; ++reg) {
    #pragma unroll
    for (int j = 0; j < 5; ++j) { lk[reg][j] = FINF; lm[reg][j] = 0; }
    dsc[reg] = FINF;
  }
  __syncthreads();

  // A fragments (persist whole kernel)
  const int rowA = w * 16 + s;
  const int swA = swz(rowA) << 4;
  f16x8 Ah[2], Al[2];
  #pragma unroll
  for (int ks = 0; ks < 2; ++ks) {
    int byt = (rowA * 128 + (ks * 32 + q * 8) * 2) ^ swA;
    Ah[ks] = *(const f16x8*)(XA + byt);
    Al[ks] = *(const f16x8*)(XA + 8192 + byt);
  }

  for (int t = 0; t < NT; ++t) {
    float4 pf[8];                       // T14: issue next-tile loads early
    if (t + 1 < NT) {
      const char* srcB = imgb + (size_t)(t + 1) * 32768;
      #pragma unroll
      for (int i = 0; i < 8; ++i) pf[i] = *(const float4*)(srcB + i * 4096 + tid * 16);
    }
    const int mbase = t * 128;
    #pragma unroll
    for (int mp = 0; mp < 4; ++mp) {
      f32x4 aE = {0.f, 0.f, 0.f, 0.f}, aO = {0.f, 0.f, 0.f, 0.f};
      {
        const int mE = (2 * mp) * 16 + s;
        const int swB = swz(mE) << 4;
        #pragma unroll
        for (int ks = 0; ks < 2; ++ks) {
          int byt = (mE * 128 + (ks * 32 + q * 8) * 2) ^ swB;
          f16x8 Bh = *(const f16x8*)(XB + byt);
          f16x8 Bl = *(const f16x8*)(XB + 16384 + byt);
          aE = __builtin_amdgcn_mfma_f32_16x16x32_f16(Ah[ks], Bh, aE, 0, 0, 0);
          aE = __builtin_amdgcn_mfma_f32_16x16x32_f16(Ah[ks], Bl, aE, 0, 0, 0);
          aE = __builtin_amdgcn_mfma_f32_16x16x32_f16(Al[ks], Bh, aE, 0, 0, 0);
        }
      }
      {
        const int mO = (2 * mp + 1) * 16 + s;
        const int swB = swz(mO) << 4;
        #pragma unroll
        for (int ks = 0; ks < 2; ++ks) {
          int byt = (mO * 128 + (ks * 32 + q * 8) * 2) ^ swB;
          f16x8 Bh = *(const f16x8*)(XB + byt);
          f16x8 Bl = *(const f16x8*)(XB + 16384 + byt);
          aO = __builtin_amdgcn_mfma_f32_16x16x32_f16(Ah[ks], Bh, aO, 0, 0, 0);
          aO = __builtin_amdgcn_mfma_f32_16x16x32_f16(Ah[ks], Bl, aO, 0, 0, 0);
          aO = __builtin_amdgcn_mfma_f32_16x16x32_f16(Al[ks], Bh, aO, 0, 0, 0);
        }
      }
      {
        float sm = sqM[(2 * mp) * 16 + s];
        u32 mc = (u32)(mbase + (2 * mp) * 16 + s);
        #pragma unroll
        for (int reg = 0; reg < 4; ++reg) {
          float v = (sqr[reg] + sm) - 2.0f * aE[reg];
          ins5(lk[reg][0], lk[reg][1], lk[reg][2], lk[reg][3], lk[reg][4],
               lm[reg][0], lm[reg][1], lm[reg][2], lm[reg][3], lm[reg][4],
               dsc[reg], v, mc);
        }
      }
      {
        float sm = sqM[(2 * mp + 1) * 16 + s];
        u32 mc = (u32)(mbase + (2 * mp + 1) * 16 + s);
        #pragma unroll
        for (int reg = 0; reg < 4; ++reg) {
          float v = (sqr[reg] + sm) - 2.0f * aO[reg];
          ins5(lk[reg][0], lk[reg][1], lk[reg][2], lk[reg][3], lk[reg][4],
               lm[reg][0], lm[reg][1], lm[reg][2], lm[reg][3], lm[reg][4],
               dsc[reg], v, mc);
        }
      }
    }
    __syncthreads();                    // done reading XB/sqM for tile t
    if (t + 1 < NT) {
      #pragma unroll
      for (int i = 0; i < 8; ++i) *(float4*)(XB + i * 4096 + tid * 16) = pf[i];
      if (tid < 128) sqM[tid] = sqb[(t + 1) * 128 + tid];
    }
    __syncthreads();                    // tile t+1 staged
  }

  // pops: 20 rounds per row; 4 quarters resolve 4 different rows concurrently
  int idxA[4], idxB[4]; bool flg[4];
  #pragma unroll
  for (int reg = 0; reg < 4; ++reg) { idxA[reg] = 0; idxB[reg] = 0; flg[reg] = false; }
  #pragma unroll
  for (int reg = 0; reg < 4; ++reg) {
    for (int r = 0; r < KNN; ++r) {
      float wkey = rmin16f(lk[reg][0]);
      u32 cand = (lk[reg][0] == wkey) ? lm[reg][0] : 0xFFFFFFFFu;
      u32 wm = rmin16u(cand);
      float db = (lk[reg][0] == FINF) ? dsc[reg] : FINF;
      flg[reg] = flg[reg] || (rmin16f(db) <= wkey);
      if (r < 16) { if (s == r) idxA[reg] = (int)wm; }
      else if (s == r - 16)     idxB[reg] = (int)wm;
      bool own = (lk[reg][0] == wkey) && (lm[reg][0] == wm);
      if (own) {
        lk[reg][0] = lk[reg][1]; lk[reg][1] = lk[reg][2]; lk[reg][2] = lk[reg][3];
        lk[reg][3] = lk[reg][4]; lk[reg][4] = FINF;
        lm[reg][0] = lm[reg][1]; lm[reg][1] = lm[reg][2]; lm[reg][2] = lm[reg][3];
        lm[reg][3] = lm[reg][4]; lm[reg][4] = 0;
      }
    }
  }
  #pragma unroll
  for (int reg = 0; reg < 4; ++reg) {
    size_t grow = (size_t)b * NPTS + r0 + w * 16 + q * 4 + reg;
    knn[grow * KNN + s] = idxA[reg];
    if (s < 4) knn[grow * KNN + 16 + s] = idxB[reg];
    if (s == 0) flags[grow] = flg[reg] ? 1 : 0;
  }
}

// ---------------------------------------------------------------------------
// Exact fp32 brute-force fallback for flagged rows (~1-2%). One wave per row;
// R3's validated sorted-4 u64 stream + DPP pops + filtered-rebuild, with dist
// recomputed on the fly (ascending-c fp32, identical to R1-R3 dist_gemm).
// ---------------------------------------------------------------------------
__global__ __launch_bounds__(256) void fallback_knn(const float* __restrict__ x,
                                                    const float* __restrict__ sq,
                                                    const int* __restrict__ flags,
                                                    int* __restrict__ knn) {
  const int lane = threadIdx.x & 63;
  const int wv = threadIdx.x >> 6;
  for (int kk = 0; kk < 4; ++kk) {
    const int g = blockIdx.x * 4 + wv + kk * 8192;
    if (!flags[g]) continue;
    const int b = g >> 12, r = g & (NPTS - 1);
    const float* xb = x + (size_t)b * CDIM * NPTS;
    const float* sqb = sq + (size_t)b * NPTS;
    const float sqr = sqb[r];
    float xr[CDIM];
    #pragma unroll
    for (int c = 0; c < CDIM; ++c) xr[c] = xb[(size_t)c * NPTS + r];

    u64 l0 = SENT, l1 = SENT, l2 = SENT, l3 = SENT;
    for (int i = 0; i < 16; ++i) {
      float a0 = 0.f, a1 = 0.f, a2 = 0.f, a3 = 0.f;
      const float* xp = xb + i * 256 + lane * 4;
      #pragma unroll
      for (int c = 0; c < CDIM; ++c) {
        float4 xv = *(const float4*)(xp + (size_t)c * NPTS);
        a0 += xr[c] * xv.x; a1 += xr[c] * xv.y; a2 += xr[c] * xv.z; a3 += xr[c] * xv.w;
      }
      int mb = i * 256 + lane * 4;
      float4 sv = *(const float4*)(sqb + mb);
      float q0 = sqr + sv.x - 2.0f * a0;
      float q1 = sqr + sv.y - 2.0f * a1;
      float q2 = sqr + sv.z - 2.0f * a2;
      float q3 = sqr + sv.w - 2.0f * a3;
      ins4(l0, l1, l2, l3, ((u64)flip_f32(q0) << 12) | (unsigned)mb);
      ins4(l0, l1, l2, l3, ((u64)flip_f32(q1) << 12) | (unsigned)(mb + 1));
      ins4(l0, l1, l2, l3, ((u64)flip_f32(q2) << 12) | (unsigned)(mb + 2));
      ins4(l0, l1, l2, l3, ((u64)flip_f32(q3) << 12) | (unsigned)(mb + 3));
    }

    u64 last = 0; bool done = false; int myidx = 0;
    for (int rr = 0; rr < KNN; ++rr) {
      bool need = (l0 == SENT) && !done;
      if (__any(need)) {
        if (need) {
          l0 = l1 = l2 = l3 = SENT;
          for (int i = 0; i < 16; ++i) {
            float a0 = 0.f, a1 = 0.f, a2 = 0.f, a3 = 0.f;
            const float* xp = xb + i * 256 + lane * 4;
            #pragma unroll
            for (int c = 0; c < CDIM; ++c) {
              float4 xv = *(const float4*)(xp + (size_t)c * NPTS);
              a0 += xr[c] * xv.x; a1 += xr[c] * xv.y; a2 += xr[c] * xv.z; a3 += xr[c] * xv.w;
            }
            int mb = i * 256 + lane * 4;
            float4 sv = *(const float4*)(sqb + mb);
            float q0 = sqr + sv.x - 2.0f * a0;
            float q1 = sqr + sv.y - 2.0f * a1;
            float q2 = sqr + sv.z - 2.0f * a2;
            float q3 = sqr + sv.w - 2.0f * a3;
            u64 v;
            v = ((u64)flip_f32(q0) << 12) | (unsigned)mb;       ins4(l0, l1, l2, l3, v > last ? v : SENT);
            v = ((u64)flip_f32(q1) << 12) | (unsigned)(mb + 1); ins4(l0, l1, l2, l3, v > last ? v : SENT);
            v = ((u64)flip_f32(q2) << 12) | (unsigned)(mb + 2); ins4(l0, l1, l2, l3, v > last ? v : SENT);
            v = ((u64)flip_f32(q3) << 12) | (unsigned)(mb + 3); ins4(l0, l1, l2, l3, v > last ? v : SENT);
          }
          if (l0 == SENT) done = true;
        }
      }
      unsigned keyH = (unsigned)(l0 >> 12);
      unsigned wkey = wave_min_u32(keyH);
      unsigned mc   = (keyH == wkey) ? (unsigned)(l0 & 0xFFF) : 0xFFFFFFFFu;
      unsigned wm   = wave_min_u32(mc);
      myidx = (lane == rr) ? (int)wm : myidx;
      u64 wsel = ((u64)wkey << 12) | wm;
      bool win = (l0 == wsel);
      l0 = win ? l1 : l0;
      l1 = win ? l2 : l1;
      l2 = win ? l3 : l2;
      l3 = win ? SENT : l3;
      last = wsel;
    }
    if (lane < KNN) knn[(size_t)g * KNN + lane] = myidx;
  }
}

// ---------------------------------------------------------------------------
// a[b][n][o]  = sum_c (W[o][c]-W[o][c+64]) * x[b][c][n]
// cc[b][n][o] = sum_c  W[o][c+64]          * x[b][c][n]
// ---------------------------------------------------------------------------
__global__ __launch_bounds__(256) void proj_kernel(const float* __restrict__ x,
                                                   const float* __restrict__ w,
                                                   float* __restrict__ a,
                                                   float* __restrict__ cc) {
  __shared__ float wa[CDIM][ODIM];
  __shared__ float wc[CDIM][ODIM];
  const int tid = threadIdx.x;
  #pragma unroll
  for (int p = 0; p < 16; ++p) {
    int idx = p * 256 + tid;
    int o = idx & 63, c = idx >> 6;
    float w1 = w[o * 128 + c], w2 = w[o * 128 + 64 + c];
    wa[c][o] = w1 - w2;
    wc[c][o] = w2;
  }
  __syncthreads();

  const int og = tid >> 6;
  const int nl = tid & 63;
  const int g0 = blockIdx.x * 128;
  const int b  = g0 >> 12;
  const int n0 = g0 & (NPTS - 1);
  const float* xB = x + (size_t)b * CDIM * NPTS;

  float aa0[16], ac0[16], aa1[16], ac1[16];
  #pragma unroll
  for (int qq = 0; qq < 16; ++qq) { aa0[qq] = ac0[qq] = aa1[qq] = ac1[qq] = 0.f; }

  #pragma unroll 4
  for (int c = 0; c < CDIM; ++c) {
    float xv0 = xB[(size_t)c * NPTS + n0 + nl];
    float xv1 = xB[(size_t)c * NPTS + n0 + 64 + nl];
    #pragma unroll
    for (int q4 = 0; q4 < 4; ++q4) {
      float4 va = *(const float4*)&wa[c][og * 16 + q4 * 4];
      float4 vc = *(const float4*)&wc[c][og * 16 + q4 * 4];
      aa0[q4*4+0] += va.x * xv0; aa0[q4*4+1] += va.y * xv0;
      aa0[q4*4+2] += va.z * xv0; aa0[q4*4+3] += va.w * xv0;
      ac0[q4*4+0] += vc.x * xv0; ac0[q4*4+1] += vc.y * xv0;
      ac0[q4*4+2] += vc.z * xv0; ac0[q4*4+3] += vc.w * xv0;
      aa1[q4*4+0] += va.x * xv1; aa1[q4*4+1] += va.y * xv1;
      aa1[q4*4+2] += va.z * xv1; aa1[q4*4+3] += va.w * xv1;
      ac1[q4*4+0] += vc.x * xv1; ac1[q4*4+1] += vc.y * xv1;
      ac1[q4*4+2] += vc.z * xv1; ac1[q4*4+3] += vc.w * xv1;
    }
  }
  size_t ga0 = (size_t)(g0 + nl) * ODIM + og * 16;
  size_t ga1 = (size_t)(g0 + 64 + nl) * ODIM + og * 16;
  #pragma unroll
  for (int q4 = 0; q4 < 4; ++q4) {
    *(float4*)&a [ga0 + q4 * 4] = *(float4*)&aa0[q4 * 4];
    *(float4*)&cc[ga0 + q4 * 4] = *(float4*)&ac0[q4 * 4];
    *(float4*)&a [ga1 + q4 * 4] = *(float4*)&aa1[q4 * 4];
    *(float4*)&cc[ga1 + q4 * 4] = *(float4*)&ac1[q4 * 4];
  }
}

// ---------------------------------------------------------------------------
// out[b][o][n] = relu(inv[o] * max_k(a[b][n][o] + cc[b][knn[n][k]][o]) + bias[o])
// ---------------------------------------------------------------------------
__global__ __launch_bounds__(256) void out_kernel(const float* __restrict__ a,
                                                  const float* __restrict__ cc,
                                                  const int* __restrict__ knn,
                                                  const float* __restrict__ gamma,
                                                  const float* __restrict__ beta,
                                                  const float* __restrict__ mean,
                                                  const float* __restrict__ var,
                                                  float* __restrict__ out) {
  __shared__ float tile[64][65];
  const int tid = threadIdx.x, lane = tid & 63, wv = tid >> 6;
  const int b = blockIdx.y;
  const int n0 = blockIdx.x * 64;
  float inv  = gamma[lane] / sqrtf(var[lane] + 1e-5f);
  float bias = beta[lane] - mean[lane] * inv;
  for (int t = 0; t < 16; ++t) {
    int nl = wv * 16 + t;
    size_t base = (size_t)b * NPTS + (n0 + nl);
    float av = a[base * ODIM + lane];
    const int* kr = knn + base * KNN;
    float m = -INFINITY;
    #pragma unroll
    for (int k = 0; k < KNN; ++k) {
      int j = kr[k];
      float cv = cc[((size_t)b * NPTS + j) * ODIM + lane];
      m = fmaxf(m, av + cv);
    }
    float v = m * inv + bias;
    tile[nl][lane] = v > 0.f ? v : 0.f;
  }
  __syncthreads();
  for (int t = 0; t < 16; ++t) {
    int o = wv * 16 + t;
    out[((size_t)b * ODIM + o) * NPTS + n0 + lane] = tile[lane][o];
  }
}

// ---------------------------------------------------------------------------
extern "C" void kernel_launch(void* const* d_in, const int* in_sizes, int n_in,
                              void* d_out, int out_size, void* d_ws, size_t ws_size,
                              hipStream_t stream) {
  const float* x     = (const float*)d_in[0];
  const float* w     = (const float*)d_in[1];
  const float* gamma = (const float*)d_in[2];
  const float* beta  = (const float*)d_in[3];
  const float* mean  = (const float*)d_in[4];
  const float* var   = (const float*)d_in[5];
  float* out = (float*)d_out;

  char* wsb = (char*)d_ws;
  size_t off = 0;
  int*   knn   = (int*)(wsb + off);   off += (size_t)BDIM * NPTS * KNN * 4;   // 2.62 MB
  int*   flags = (int*)(wsb + off);   off += (size_t)BDIM * NPTS * 4;         // 0.13 MB
  float* sqw   = (float*)(wsb + off); off += (size_t)BDIM * NPTS * 4;         // 0.13 MB
  float* a     = (float*)(wsb + off); off += (size_t)BDIM * NPTS * ODIM * 4;  // 8 MB
  float* cc    = (float*)(wsb + off); off += (size_t)BDIM * NPTS * ODIM * 4;  // 8 MB
  char*  img   = wsb + off;           off += (size_t)BDIM * NT * 32768;       // 8 MB
  (void)ws_size;

  prep_kernel <<<BDIM * NT, 256, 0, stream>>>(x, img);
  sq_kernel   <<<BDIM * NPTS / 256, 256, 0, stream>>>(x, sqw);
  proj_kernel <<<BDIM * NPTS / 128, 256, 0, stream>>>(x, w, a, cc);
  fused_knn   <<<512, 256, 0, stream>>>(img, sqw, knn, flags);
  fallback_knn<<<2048, 256, 0, stream>>>(x, sqw, flags, knn);
  out_kernel  <<<dim3(NPTS / 64, BDIM), 256, 0, stream>>>(a, cc, knn, gamma, beta,
                                                          mean, var, out);
}

// Round 6
// 582.301 us; speedup vs baseline: 2.2696x; 2.2696x over previous
//
#include <hip/hip_runtime.h>
#include <cstdint>
#include <cstddef>

#define NPTS 4096
#define CDIM 64
#define BDIM 8
#define KNN  20
#define ODIM 64
#define NT128 32          // 128-col tile images per batch (prep layout)
#define NT64  64          // 64-col compute tiles per batch (fused)

typedef unsigned long long u64;
typedef unsigned int u32;
typedef _Float16 f16;
using f16x8 = __attribute__((ext_vector_type(8))) _Float16;
using f32x4 = __attribute__((ext_vector_type(4))) float;
#define SENT (~0ull)
#define FINF (__builtin_inff())

__device__ __forceinline__ int swz(int r) { return (r & 7) ^ ((r >> 3) & 7); }

// order-preserving float->u32 flip (ascending float == ascending u32)
__device__ __forceinline__ unsigned flip_f32(float d) {
  unsigned bits = __float_as_uint(d);
  return bits ^ (unsigned)(((int)bits >> 31) | 0x80000000u);
}

// wave64 all-reduce min (DPP), uniform via readlane 63  (R3-validated)
__device__ __forceinline__ unsigned wave_min_u32(unsigned v) {
  unsigned t;
  t = (unsigned)__builtin_amdgcn_update_dpp((int)v, (int)v, 0x111, 0xF, 0xF, false); v = t < v ? t : v;
  t = (unsigned)__builtin_amdgcn_update_dpp((int)v, (int)v, 0x112, 0xF, 0xF, false); v = t < v ? t : v;
  t = (unsigned)__builtin_amdgcn_update_dpp((int)v, (int)v, 0x114, 0xF, 0xF, false); v = t < v ? t : v;
  t = (unsigned)__builtin_amdgcn_update_dpp((int)v, (int)v, 0x118, 0xF, 0xF, false); v = t < v ? t : v;
  t = (unsigned)__builtin_amdgcn_update_dpp((int)v, (int)v, 0x142, 0xA, 0xF, false); v = t < v ? t : v;
  t = (unsigned)__builtin_amdgcn_update_dpp((int)v, (int)v, 0x143, 0xC, 0xF, false); v = t < v ? t : v;
  return (unsigned)__builtin_amdgcn_readlane((int)v, 63);
}

// 16-lane all-reduce min (quad xor1, xor2, row_ror4, row_ror8) — R5-validated
__device__ __forceinline__ float rmin16f(float v) {
  int t;
  t = __builtin_amdgcn_update_dpp(__float_as_int(v), __float_as_int(v), 0xB1,  0xF, 0xF, false);
  v = fminf(v, __int_as_float(t));
  t = __builtin_amdgcn_update_dpp(__float_as_int(v), __float_as_int(v), 0x4E,  0xF, 0xF, false);
  v = fminf(v, __int_as_float(t));
  t = __builtin_amdgcn_update_dpp(__float_as_int(v), __float_as_int(v), 0x124, 0xF, 0xF, false);
  v = fminf(v, __int_as_float(t));
  t = __builtin_amdgcn_update_dpp(__float_as_int(v), __float_as_int(v), 0x128, 0xF, 0xF, false);
  v = fminf(v, __int_as_float(t));
  return v;
}
__device__ __forceinline__ u32 rmin16u(u32 v) {
  int t;
  t = __builtin_amdgcn_update_dpp((int)v, (int)v, 0xB1,  0xF, 0xF, false); v = ((u32)t < v) ? (u32)t : v;
  t = __builtin_amdgcn_update_dpp((int)v, (int)v, 0x4E,  0xF, 0xF, false); v = ((u32)t < v) ? (u32)t : v;
  t = __builtin_amdgcn_update_dpp((int)v, (int)v, 0x124, 0xF, 0xF, false); v = ((u32)t < v) ? (u32)t : v;
  t = __builtin_amdgcn_update_dpp((int)v, (int)v, 0x128, 0xF, 0xF, false); v = ((u32)t < v) ? (u32)t : v;
  return v;
}

// branchless stable insert into ascending sorted-8 (float keys + u32 m)
__device__ __forceinline__ void ins8(float (&k)[8], u32 (&m)[8], float v, u32 mv) {
  bool c0 = v < k[0], c1 = v < k[1], c2 = v < k[2], c3 = v < k[3],
       c4 = v < k[4], c5 = v < k[5], c6 = v < k[6], c7 = v < k[7];
  float n1 = __builtin_amdgcn_fmed3f(v, k[0], k[1]);
  float n2 = __builtin_amdgcn_fmed3f(v, k[1], k[2]);
  float n3 = __builtin_amdgcn_fmed3f(v, k[2], k[3]);
  float n4 = __builtin_amdgcn_fmed3f(v, k[3], k[4]);
  float n5 = __builtin_amdgcn_fmed3f(v, k[4], k[5]);
  float n6 = __builtin_amdgcn_fmed3f(v, k[5], k[6]);
  float n7 = __builtin_amdgcn_fmed3f(v, k[6], k[7]);
  u32 p1 = c1 ? (c0 ? m[0] : mv) : m[1];
  u32 p2 = c2 ? (c1 ? m[1] : mv) : m[2];
  u32 p3 = c3 ? (c2 ? m[2] : mv) : m[3];
  u32 p4 = c4 ? (c3 ? m[3] : mv) : m[4];
  u32 p5 = c5 ? (c4 ? m[4] : mv) : m[5];
  u32 p6 = c6 ? (c5 ? m[5] : mv) : m[6];
  u32 p7 = c7 ? (c6 ? m[6] : mv) : m[7];
  k[0] = fminf(v, k[0]); k[1] = n1; k[2] = n2; k[3] = n3;
  k[4] = n4; k[5] = n5; k[6] = n6; k[7] = n7;
  m[0] = c0 ? mv : m[0]; m[1] = p1; m[2] = p2; m[3] = p3;
  m[4] = p4; m[5] = p5; m[6] = p6; m[7] = p7;
}

// branchless insert into ascending sorted-8 of u64 keys (bubble, drops max)
__device__ __forceinline__ void ins8u(u64 (&L)[8], u64 v) {
  u64 c = v;
  #pragma unroll
  for (int j = 0; j < 8; ++j) {
    u64 lo = c < L[j] ? c : L[j];
    u64 hi = c < L[j] ? L[j] : c;
    L[j] = lo; c = hi;
  }
}

// async global->LDS, 16B per lane; LDS dest is wave-uniform base + lane*16
__device__ __forceinline__ void gl16(const char* g, char* l) {
  __builtin_amdgcn_global_load_lds(
      (const __attribute__((address_space(1))) unsigned int*)g,
      (__attribute__((address_space(3))) unsigned int*)l, 16, 0, 0);
}
// stage one 64-col tile (hi 8KB + lo 8KB) into a 16KB LDS buffer
__device__ __forceinline__ void stage64(const char* src_hi, char* dst, int tid) {
  const int w = tid >> 6, lane = tid & 63;
  const int off = w * 2048 + (lane << 4);
  gl16(src_hi + off,                 dst + w * 2048);
  gl16(src_hi + off + 1024,          dst + w * 2048 + 1024);
  gl16(src_hi + 16384 + off,         dst + 8192 + w * 2048);
  gl16(src_hi + 16384 + off + 1024,  dst + 8192 + w * 2048 + 1024);
}

// ---------------------------------------------------------------------------
// sq[b][n] = sum_c x[b][c][n]^2   (ascending c — bit-identical to R3-R5)
// ---------------------------------------------------------------------------
__global__ __launch_bounds__(256) void sq_kernel(const float* __restrict__ x,
                                                 float* __restrict__ sq) {
  int g = blockIdx.x * 256 + threadIdx.x;
  int b = g >> 12, n = g & (NPTS - 1);
  const float* xb = x + (size_t)b * CDIM * NPTS + n;
  float s = 0.f;
  #pragma unroll
  for (int c = 0; c < CDIM; ++c) { float v = xb[(size_t)c * NPTS]; s += v * v; }
  sq[g] = s;
}

// ---------------------------------------------------------------------------
// prep: per-(b,128-tile) fp16 hi/lo images in exact swizzled LDS byte layout:
// byte(n',c) = (n'*128 + 2c) ^ (swz(n')<<4); hi at +0, lo at +16384.
// ---------------------------------------------------------------------------
__global__ __launch_bounds__(256) void prep_kernel(const float* __restrict__ x,
                                                   char* __restrict__ img) {
  __shared__ char limg[32768];
  const int tid = threadIdx.x;
  const int b = blockIdx.x >> 5;
  const int t = blockIdx.x & 31;
  const int np = tid & 127;
  const int ch = tid >> 7;
  const float* xb = x + (size_t)b * CDIM * NPTS + t * 128 + np;
  const int sw = swz(np) << 4;
  #pragma unroll
  for (int cc = 0; cc < 32; ++cc) {
    int c = ch * 32 + cc;
    float v = xb[(size_t)c * NPTS];
    f16 h = (f16)v;
    f16 l = (f16)(v - (float)h);
    int byt = (np * 128 + c * 2) ^ sw;
    *(f16*)(limg + byt) = h;
    *(f16*)(limg + 16384 + byt) = l;
  }
  __syncthreads();
  char* dst = img + (size_t)blockIdx.x * 32768;
  #pragma unroll
  for (int i = 0; i < 8; ++i)
    *(float4*)(dst + i * 4096 + tid * 16) = *(const float4*)(limg + i * 4096 + tid * 16);
}

// ---------------------------------------------------------------------------
// Fused dist+top20. Block = 64 rows; 64 col-tiles of 64, double-buffered via
// global_load_lds (T3 2-phase). MFMA fp16x3 order identical to R4/R5 (hh,hl,lh;
// ks ascending) => bit-identical distances. Depth-8 per-lane sorted lists with
// wave-any skip guard; 20 rounds of 16-lane DPP min with (dist,m) lexicographic
// tie-break. Flag = any lane drained during pops (provably conservative).
// ---------------------------------------------------------------------------
__global__ __launch_bounds__(256) void fused_knn(const char* __restrict__ img,
                                                 const float* __restrict__ sq,
                                                 int* __restrict__ knn,
                                                 int* __restrict__ flags) {
  __shared__ char XA[16384];
  __shared__ char XB[2][16384];

  const int tid = threadIdx.x;
  const int lane = tid & 63;
  const int w = tid >> 6;
  const int q = lane >> 4;
  const int s = lane & 15;

  const int blk = blockIdx.x;
  const int b  = blk >> 6;
  const int r0 = (blk & 63) * 64;
  const char* imgb = img + (size_t)b * (NT128 * 32768);
  const float* sqb = sq + (size_t)b * NPTS;

  {  // XA: this block's 64 rows (hi->0, lo->8192). swz(64+j)==swz(j).
    const char* aspan = imgb + (size_t)(r0 >> 7) * 32768 + (size_t)((r0 >> 6) & 1) * 8192;
    #pragma unroll
    for (int i = 0; i < 2; ++i) {
      *(float4*)(XA + i * 4096 + tid * 16) =
          *(const float4*)(aspan + i * 4096 + tid * 16);
      *(float4*)(XA + 8192 + i * 4096 + tid * 16) =
          *(const float4*)(aspan + 16384 + i * 4096 + tid * 16);
    }
  }
  stage64(imgb, XB[0], tid);      // tile 0

  float sqr[4];
  #pragma unroll
  for (int reg = 0; reg < 4; ++reg) sqr[reg] = sqb[r0 + w * 16 + q * 4 + reg];

  float lk[4][8]; u32 lm[4][8];
  #pragma unroll
  for (int reg = 0; reg < 4; ++reg)
    #pragma unroll
    for (int j = 0; j < 8; ++j) { lk[reg][j] = FINF; lm[reg][j] = 0; }

  __syncthreads();                 // XA visible + tile-0 staging drained

  f16x8 Ah[2], Al[2];
  {
    const int j = w * 16 + s;
    const int sw = swz(j) << 4;
    #pragma unroll
    for (int ks = 0; ks < 2; ++ks) {
      int byt = (j * 128 + (ks * 32 + q * 8) * 2) ^ sw;
      Ah[ks] = *(const f16x8*)(XA + byt);
      Al[ks] = *(const f16x8*)(XA + 8192 + byt);
    }
  }

  for (int t = 0; t < NT64; ++t) {
    if (t + 1 < NT64)
      stage64(imgb + (size_t)((t + 1) >> 1) * 32768 + (size_t)((t + 1) & 1) * 8192,
              XB[(t + 1) & 1], tid);
    const char* XBc = XB[t & 1];
    #pragma unroll
    for (int e = 0; e < 4; ++e) {
      const int j = e * 16 + s;
      const int sw = swz(j) << 4;
      f32x4 acc = {0.f, 0.f, 0.f, 0.f};
      #pragma unroll
      for (int ks = 0; ks < 2; ++ks) {
        int byt = (j * 128 + (ks * 32 + q * 8) * 2) ^ sw;
        f16x8 Bh = *(const f16x8*)(XBc + byt);
        f16x8 Bl = *(const f16x8*)(XBc + 8192 + byt);
        acc = __builtin_amdgcn_mfma_f32_16x16x32_f16(Ah[ks], Bh, acc, 0, 0, 0);
        acc = __builtin_amdgcn_mfma_f32_16x16x32_f16(Ah[ks], Bl, acc, 0, 0, 0);
        acc = __builtin_amdgcn_mfma_f32_16x16x32_f16(Al[ks], Bh, acc, 0, 0, 0);
      }
      const int mcol = t * 64 + e * 16 + s;
      const float sm = sqb[mcol];
      #pragma unroll
      for (int reg = 0; reg < 4; ++reg) {
        float v = (sqr[reg] + sm) - 2.0f * acc[reg];
        if (__any(v < lk[reg][7])) ins8(lk[reg], lm[reg], v, (u32)mcol);
      }
    }
    __syncthreads();   // all reads of XB[t&1] done; next-tile staging drained
  }

  // pops: 20 rounds per row; 4 quarters resolve 4 rows concurrently
  #pragma unroll
  for (int reg = 0; reg < 4; ++reg) {
    bool flg = false;
    int iA = 0, iB = 0;
    for (int r = 0; r < KNN; ++r) {
      flg = flg || (rmin16u((lk[reg][0] == FINF) ? 0u : 1u) == 0u);   // any drained
      float wkey = rmin16f(lk[reg][0]);
      u32 cand = (lk[reg][0] == wkey) ? lm[reg][0] : 0xFFFFFFFFu;
      u32 wm = rmin16u(cand);
      if (r < 16) { if (s == r) iA = (int)wm; }
      else if (s == r - 16)     iB = (int)wm;
      bool own = (lk[reg][0] == wkey) && (lm[reg][0] == wm);
      #pragma unroll
      for (int j = 0; j < 7; ++j) {
        lk[reg][j] = own ? lk[reg][j + 1] : lk[reg][j];
        lm[reg][j] = own ? lm[reg][j + 1] : lm[reg][j];
      }
      lk[reg][7] = own ? FINF : lk[reg][7];
      lm[reg][7] = own ? 0u   : lm[reg][7];
    }
    size_t grow = (size_t)b * NPTS + r0 + w * 16 + q * 4 + reg;
    knn[grow * KNN + s] = iA;
    if (s < 4) knn[grow * KNN + 16 + s] = iB;
    if (s == 0) flags[grow] = flg ? 1 : 0;
  }
}

// ---------------------------------------------------------------------------
// Exact fp32 brute-force fallback for flagged rows (~1e-4 of rows). One wave
// per row; depth-8 u64 lists (no rebuild in practice; kept for exactness).
// Dist recomputed ascending-c fp32 (identical to R1-R3 formula).
// ---------------------------------------------------------------------------
__global__ __launch_bounds__(256) void fallback_knn(const float* __restrict__ x,
                                                    const float* __restrict__ sq,
                                                    const int* __restrict__ flags,
                                                    int* __restrict__ knn) {
  const int lane = threadIdx.x & 63;
  const int wv = threadIdx.x >> 6;
  const int g = blockIdx.x * 4 + wv;
  if (!flags[g]) return;
  const int b = g >> 12, r = g & (NPTS - 1);
  const float* xb = x + (size_t)b * CDIM * NPTS;
  const float* sqb = sq + (size_t)b * NPTS;
  const float sqr = sqb[r];
  float xr[CDIM];
  #pragma unroll
  for (int c = 0; c < CDIM; ++c) xr[c] = xb[(size_t)c * NPTS + r];

  u64 L[8];
  #pragma unroll
  for (int j = 0; j < 8; ++j) L[j] = SENT;
  for (int i = 0; i < 16; ++i) {
    float a0 = 0.f, a1 = 0.f, a2 = 0.f, a3 = 0.f;
    const float* xp = xb + i * 256 + lane * 4;
    #pragma unroll
    for (int c = 0; c < CDIM; ++c) {
      float4 xv = *(const float4*)(xp + (size_t)c * NPTS);
      a0 += xr[c] * xv.x; a1 += xr[c] * xv.y; a2 += xr[c] * xv.z; a3 += xr[c] * xv.w;
    }
    int mb = i * 256 + lane * 4;
    float4 sv = *(const float4*)(sqb + mb);
    ins8u(L, ((u64)flip_f32(sqr + sv.x - 2.0f * a0) << 12) | (unsigned)mb);
    ins8u(L, ((u64)flip_f32(sqr + sv.y - 2.0f * a1) << 12) | (unsigned)(mb + 1));
    ins8u(L, ((u64)flip_f32(sqr + sv.z - 2.0f * a2) << 12) | (unsigned)(mb + 2));
    ins8u(L, ((u64)flip_f32(sqr + sv.w - 2.0f * a3) << 12) | (unsigned)(mb + 3));
  }

  u64 last = 0; bool done = false; int myidx = 0;
  for (int rr = 0; rr < KNN; ++rr) {
    bool need = (L[0] == SENT) && !done;
    if (__any(need)) {
      if (need) {                                  // never fires in practice
        #pragma unroll
        for (int j = 0; j < 8; ++j) L[j] = SENT;
        for (int i = 0; i < 16; ++i) {
          float a0 = 0.f, a1 = 0.f, a2 = 0.f, a3 = 0.f;
          const float* xp = xb + i * 256 + lane * 4;
          #pragma unroll
          for (int c = 0; c < CDIM; ++c) {
            float4 xv = *(const float4*)(xp + (size_t)c * NPTS);
            a0 += xr[c] * xv.x; a1 += xr[c] * xv.y; a2 += xr[c] * xv.z; a3 += xr[c] * xv.w;
          }
          int mb = i * 256 + lane * 4;
          float4 sv = *(const float4*)(sqb + mb);
          u64 v;
          v = ((u64)flip_f32(sqr + sv.x - 2.0f * a0) << 12) | (unsigned)mb;       ins8u(L, v > last ? v : SENT);
          v = ((u64)flip_f32(sqr + sv.y - 2.0f * a1) << 12) | (unsigned)(mb + 1); ins8u(L, v > last ? v : SENT);
          v = ((u64)flip_f32(sqr + sv.z - 2.0f * a2) << 12) | (unsigned)(mb + 2); ins8u(L, v > last ? v : SENT);
          v = ((u64)flip_f32(sqr + sv.w - 2.0f * a3) << 12) | (unsigned)(mb + 3); ins8u(L, v > last ? v : SENT);
        }
        if (L[0] == SENT) done = true;
      }
    }
    unsigned keyH = (unsigned)(L[0] >> 12);
    unsigned wkey = wave_min_u32(keyH);
    unsigned mc   = (keyH == wkey) ? (unsigned)(L[0] & 0xFFF) : 0xFFFFFFFFu;
    unsigned wm   = wave_min_u32(mc);
    myidx = (lane == rr) ? (int)wm : myidx;
    u64 wsel = ((u64)wkey << 12) | wm;
    bool win = (L[0] == wsel);
    #pragma unroll
    for (int j = 0; j < 7; ++j) L[j] = win ? L[j + 1] : L[j];
    L[7] = win ? SENT : L[7];
    last = wsel;
  }
  if (lane < KNN) knn[(size_t)g * KNN + lane] = myidx;
}

// ---------------------------------------------------------------------------
// a[b][n][o]  = sum_c (W[o][c]-W[o][c+64]) * x[b][c][n]
// cc[b][n][o] = sum_c  W[o][c+64]          * x[b][c][n]
// ---------------------------------------------------------------------------
__global__ __launch_bounds__(256) void proj_kernel(const float* __restrict__ x,
                                                   const float* __restrict__ w,
                                                   float* __restrict__ a,
                                                   float* __restrict__ cc) {
  __shared__ float wa[CDIM][ODIM];
  __shared__ float wc[CDIM][ODIM];
  const int tid = threadIdx.x;
  #pragma unroll
  for (int p = 0; p < 16; ++p) {
    int idx = p * 256 + tid;
    int o = idx & 63, c = idx >> 6;
    float w1 = w[o * 128 + c], w2 = w[o * 128 + 64 + c];
    wa[c][o] = w1 - w2;
    wc[c][o] = w2;
  }
  __syncthreads();

  const int og = tid >> 6;
  const int nl = tid & 63;
  const int g0 = blockIdx.x * 128;
  const int b  = g0 >> 12;
  const int n0 = g0 & (NPTS - 1);
  const float* xB = x + (size_t)b * CDIM * NPTS;

  float aa0[16], ac0[16], aa1[16], ac1[16];
  #pragma unroll
  for (int qq = 0; qq < 16; ++qq) { aa0[qq] = ac0[qq] = aa1[qq] = ac1[qq] = 0.f; }

  #pragma unroll 4
  for (int c = 0; c < CDIM; ++c) {
    float xv0 = xB[(size_t)c * NPTS + n0 + nl];
    float xv1 = xB[(size_t)c * NPTS + n0 + 64 + nl];
    #pragma unroll
    for (int q4 = 0; q4 < 4; ++q4) {
      float4 va = *(const float4*)&wa[c][og * 16 + q4 * 4];
      float4 vc = *(const float4*)&wc[c][og * 16 + q4 * 4];
      aa0[q4*4+0] += va.x * xv0; aa0[q4*4+1] += va.y * xv0;
      aa0[q4*4+2] += va.z * xv0; aa0[q4*4+3] += va.w * xv0;
      ac0[q4*4+0] += vc.x * xv0; ac0[q4*4+1] += vc.y * xv0;
      ac0[q4*4+2] += vc.z * xv0; ac0[q4*4+3] += vc.w * xv0;
      aa1[q4*4+0] += va.x * xv1; aa1[q4*4+1] += va.y * xv1;
      aa1[q4*4+2] += va.z * xv1; aa1[q4*4+3] += va.w * xv1;
      ac1[q4*4+0] += vc.x * xv1; ac1[q4*4+1] += vc.y * xv1;
      ac1[q4*4+2] += vc.z * xv1; ac1[q4*4+3] += vc.w * xv1;
    }
  }
  size_t ga0 = (size_t)(g0 + nl) * ODIM + og * 16;
  size_t ga1 = (size_t)(g0 + 64 + nl) * ODIM + og * 16;
  #pragma unroll
  for (int q4 = 0; q4 < 4; ++q4) {
    *(float4*)&a [ga0 + q4 * 4] = *(float4*)&aa0[q4 * 4];
    *(float4*)&cc[ga0 + q4 * 4] = *(float4*)&ac0[q4 * 4];
    *(float4*)&a [ga1 + q4 * 4] = *(float4*)&aa1[q4 * 4];
    *(float4*)&cc[ga1 + q4 * 4] = *(float4*)&ac1[q4 * 4];
  }
}

// ---------------------------------------------------------------------------
// out[b][o][n] = relu(inv[o] * max_k(a[b][n][o] + cc[b][knn[n][k]][o]) + bias[o])
// ---------------------------------------------------------------------------
__global__ __launch_bounds__(256) void out_kernel(const float* __restrict__ a,
                                                  const float* __restrict__ cc,
                                                  const int* __restrict__ knn,
                                                  const float* __restrict__ gamma,
                                                  const float* __restrict__ beta,
                                                  const float* __restrict__ mean,
                                                  const float* __restrict__ var,
                                                  float* __restrict__ out) {
  __shared__ float tile[64][65];
  const int tid = threadIdx.x, lane = tid & 63, wv = tid >> 6;
  const int b = blockIdx.y;
  const int n0 = blockIdx.x * 64;
  float inv  = gamma[lane] / sqrtf(var[lane] + 1e-5f);
  float bias = beta[lane] - mean[lane] * inv;
  for (int t = 0; t < 16; ++t) {
    int nl = wv * 16 + t;
    size_t base = (size_t)b * NPTS + (n0 + nl);
    float av = a[base * ODIM + lane];
    const int* kr = knn + base * KNN;
    float m = -INFINITY;
    #pragma unroll
    for (int k = 0; k < KNN; ++k) {
      int j = kr[k];
      float cv = cc[((size_t)b * NPTS + j) * ODIM + lane];
      m = fmaxf(m, av + cv);
    }
    float v = m * inv + bias;
    tile[nl][lane] = v > 0.f ? v : 0.f;
  }
  __syncthreads();
  for (int t = 0; t < 16; ++t) {
    int o = wv * 16 + t;
    out[((size_t)b * ODIM + o) * NPTS + n0 + lane] = tile[lane][o];
  }
}

// ---------------------------------------------------------------------------
extern "C" void kernel_launch(void* const* d_in, const int* in_sizes, int n_in,
                              void* d_out, int out_size, void* d_ws, size_t ws_size,
                              hipStream_t stream) {
  const float* x     = (const float*)d_in[0];
  const float* w     = (const float*)d_in[1];
  const float* gamma = (const float*)d_in[2];
  const float* beta  = (const float*)d_in[3];
  const float* mean  = (const float*)d_in[4];
  const float* var   = (const float*)d_in[5];
  float* out = (float*)d_out;

  char* wsb = (char*)d_ws;
  size_t off = 0;
  int*   knn   = (int*)(wsb + off);   off += (size_t)BDIM * NPTS * KNN * 4;   // 2.62 MB
  int*   flags = (int*)(wsb + off);   off += (size_t)BDIM * NPTS * 4;         // 0.13 MB
  float* sqw   = (float*)(wsb + off); off += (size_t)BDIM * NPTS * 4;         // 0.13 MB
  float* a     = (float*)(wsb + off); off += (size_t)BDIM * NPTS * ODIM * 4;  // 8 MB
  float* cc    = (float*)(wsb + off); off += (size_t)BDIM * NPTS * ODIM * 4;  // 8 MB
  char*  img   = wsb + off;           off += (size_t)BDIM * NT128 * 32768;    // 8 MB
  (void)ws_size;

  prep_kernel <<<BDIM * NT128, 256, 0, stream>>>(x, img);
  sq_kernel   <<<BDIM * NPTS / 256, 256, 0, stream>>>(x, sqw);
  proj_kernel <<<BDIM * NPTS / 128, 256, 0, stream>>>(x, w, a, cc);
  fused_knn   <<<512, 256, 0, stream>>>(img, sqw, knn, flags);
  fallback_knn<<<BDIM * NPTS / 4, 256, 0, stream>>>(x, sqw, flags, knn);
  out_kernel  <<<dim3(NPTS / 64, BDIM), 256, 0, stream>>>(a, cc, knn, gamma, beta,
                                                          mean, var, out);
}

// Round 7
// 401.193 us; speedup vs baseline: 3.2942x; 1.4514x over previous
//
#include <hip/hip_runtime.h>
#include <cstdint>
#include <cstddef>

#define NPTS 4096
#define CDIM 64
#define BDIM 8
#define KNN  20
#define ODIM 64
#define NT128 32          // 128-col tile images per batch (prep layout)
#define NT64  64          // 64-col compute tiles per batch (fused)

typedef unsigned long long u64;
typedef unsigned int u32;
typedef _Float16 f16;
using f16x8 = __attribute__((ext_vector_type(8))) _Float16;
using f32x4 = __attribute__((ext_vector_type(4))) float;
#define SENT (~0ull)
#define FINF (__builtin_inff())

__device__ __forceinline__ int swz(int r) { return (r & 7) ^ ((r >> 3) & 7); }

// order-preserving float->u32 flip (ascending float == ascending u32)
__device__ __forceinline__ unsigned flip_f32(float d) {
  unsigned bits = __float_as_uint(d);
  return bits ^ (unsigned)(((int)bits >> 31) | 0x80000000u);
}

// wave64 all-reduce min (DPP), uniform via readlane 63  (R3-validated)
__device__ __forceinline__ unsigned wave_min_u32(unsigned v) {
  unsigned t;
  t = (unsigned)__builtin_amdgcn_update_dpp((int)v, (int)v, 0x111, 0xF, 0xF, false); v = t < v ? t : v;
  t = (unsigned)__builtin_amdgcn_update_dpp((int)v, (int)v, 0x112, 0xF, 0xF, false); v = t < v ? t : v;
  t = (unsigned)__builtin_amdgcn_update_dpp((int)v, (int)v, 0x114, 0xF, 0xF, false); v = t < v ? t : v;
  t = (unsigned)__builtin_amdgcn_update_dpp((int)v, (int)v, 0x118, 0xF, 0xF, false); v = t < v ? t : v;
  t = (unsigned)__builtin_amdgcn_update_dpp((int)v, (int)v, 0x142, 0xA, 0xF, false); v = t < v ? t : v;
  t = (unsigned)__builtin_amdgcn_update_dpp((int)v, (int)v, 0x143, 0xC, 0xF, false); v = t < v ? t : v;
  return (unsigned)__builtin_amdgcn_readlane((int)v, 63);
}

// 16-lane all-reduce min (quad xor1, xor2, row_ror4, row_ror8) — R5/R6-validated
__device__ __forceinline__ float rmin16f(float v) {
  int t;
  t = __builtin_amdgcn_update_dpp(__float_as_int(v), __float_as_int(v), 0xB1,  0xF, 0xF, false);
  v = fminf(v, __int_as_float(t));
  t = __builtin_amdgcn_update_dpp(__float_as_int(v), __float_as_int(v), 0x4E,  0xF, 0xF, false);
  v = fminf(v, __int_as_float(t));
  t = __builtin_amdgcn_update_dpp(__float_as_int(v), __float_as_int(v), 0x124, 0xF, 0xF, false);
  v = fminf(v, __int_as_float(t));
  t = __builtin_amdgcn_update_dpp(__float_as_int(v), __float_as_int(v), 0x128, 0xF, 0xF, false);
  v = fminf(v, __int_as_float(t));
  return v;
}
__device__ __forceinline__ u32 rmin16u(u32 v) {
  int t;
  t = __builtin_amdgcn_update_dpp((int)v, (int)v, 0xB1,  0xF, 0xF, false); v = ((u32)t < v) ? (u32)t : v;
  t = __builtin_amdgcn_update_dpp((int)v, (int)v, 0x4E,  0xF, 0xF, false); v = ((u32)t < v) ? (u32)t : v;
  t = __builtin_amdgcn_update_dpp((int)v, (int)v, 0x124, 0xF, 0xF, false); v = ((u32)t < v) ? (u32)t : v;
  t = __builtin_amdgcn_update_dpp((int)v, (int)v, 0x128, 0xF, 0xF, false); v = ((u32)t < v) ? (u32)t : v;
  return v;
}

// branchless stable insert into ascending sorted-8 (float keys + u32 m)
__device__ __forceinline__ void ins8(float (&k)[8], u32 (&m)[8], float v, u32 mv) {
  bool c0 = v < k[0], c1 = v < k[1], c2 = v < k[2], c3 = v < k[3],
       c4 = v < k[4], c5 = v < k[5], c6 = v < k[6], c7 = v < k[7];
  float n1 = __builtin_amdgcn_fmed3f(v, k[0], k[1]);
  float n2 = __builtin_amdgcn_fmed3f(v, k[1], k[2]);
  float n3 = __builtin_amdgcn_fmed3f(v, k[2], k[3]);
  float n4 = __builtin_amdgcn_fmed3f(v, k[3], k[4]);
  float n5 = __builtin_amdgcn_fmed3f(v, k[4], k[5]);
  float n6 = __builtin_amdgcn_fmed3f(v, k[5], k[6]);
  float n7 = __builtin_amdgcn_fmed3f(v, k[6], k[7]);
  u32 p1 = c1 ? (c0 ? m[0] : mv) : m[1];
  u32 p2 = c2 ? (c1 ? m[1] : mv) : m[2];
  u32 p3 = c3 ? (c2 ? m[2] : mv) : m[3];
  u32 p4 = c4 ? (c3 ? m[3] : mv) : m[4];
  u32 p5 = c5 ? (c4 ? m[4] : mv) : m[5];
  u32 p6 = c6 ? (c5 ? m[5] : mv) : m[6];
  u32 p7 = c7 ? (c6 ? m[6] : mv) : m[7];
  k[0] = fminf(v, k[0]); k[1] = n1; k[2] = n2; k[3] = n3;
  k[4] = n4; k[5] = n5; k[6] = n6; k[7] = n7;
  m[0] = c0 ? mv : m[0]; m[1] = p1; m[2] = p2; m[3] = p3;
  m[4] = p4; m[5] = p5; m[6] = p6; m[7] = p7;
}

// branchless insert into ascending sorted-8 of u64 keys (bubble, drops max)
__device__ __forceinline__ void ins8u(u64 (&L)[8], u64 v) {
  u64 c = v;
  #pragma unroll
  for (int j = 0; j < 8; ++j) {
    u64 lo = c < L[j] ? c : L[j];
    u64 hi = c < L[j] ? L[j] : c;
    L[j] = lo; c = hi;
  }
}

// async global->LDS, 16B per lane; LDS dest is wave-uniform base + lane*16
__device__ __forceinline__ void gl16(const char* g, char* l) {
  __builtin_amdgcn_global_load_lds(
      (const __attribute__((address_space(1))) unsigned int*)g,
      (__attribute__((address_space(3))) unsigned int*)l, 16, 0, 0);
}
// stage one 64-col tile (hi 8KB + lo 8KB) into a 16KB LDS buffer
__device__ __forceinline__ void stage64(const char* src_hi, char* dst, int tid) {
  const int w = tid >> 6, lane = tid & 63;
  const int off = w * 2048 + (lane << 4);
  gl16(src_hi + off,                 dst + w * 2048);
  gl16(src_hi + off + 1024,          dst + w * 2048 + 1024);
  gl16(src_hi + 16384 + off,         dst + 8192 + w * 2048);
  gl16(src_hi + 16384 + off + 1024,  dst + 8192 + w * 2048 + 1024);
}

// ---------------------------------------------------------------------------
// sq[b][n] = sum_c x[b][c][n]^2   (ascending c — bit-identical to R3-R6)
// Also zeroes the fallback compaction counter (runs before compact in stream).
// ---------------------------------------------------------------------------
__global__ __launch_bounds__(256) void sq_kernel(const float* __restrict__ x,
                                                 float* __restrict__ sq,
                                                 int* __restrict__ cnt) {
  if (blockIdx.x == 0 && threadIdx.x == 0) *cnt = 0;
  int g = blockIdx.x * 256 + threadIdx.x;
  int b = g >> 12, n = g & (NPTS - 1);
  const float* xb = x + (size_t)b * CDIM * NPTS + n;
  float s = 0.f;
  #pragma unroll
  for (int c = 0; c < CDIM; ++c) { float v = xb[(size_t)c * NPTS]; s += v * v; }
  sq[g] = s;
}

// ---------------------------------------------------------------------------
// prep: per-(b,128-tile) fp16 hi/lo images in exact swizzled LDS byte layout:
// byte(n',c) = (n'*128 + 2c) ^ (swz(n')<<4); hi at +0, lo at +16384.
// ---------------------------------------------------------------------------
__global__ __launch_bounds__(256) void prep_kernel(const float* __restrict__ x,
                                                   char* __restrict__ img) {
  __shared__ char limg[32768];
  const int tid = threadIdx.x;
  const int b = blockIdx.x >> 5;
  const int t = blockIdx.x & 31;
  const int np = tid & 127;
  const int ch = tid >> 7;
  const float* xb = x + (size_t)b * CDIM * NPTS + t * 128 + np;
  const int sw = swz(np) << 4;
  #pragma unroll
  for (int cc = 0; cc < 32; ++cc) {
    int c = ch * 32 + cc;
    float v = xb[(size_t)c * NPTS];
    f16 h = (f16)v;
    f16 l = (f16)(v - (float)h);
    int byt = (np * 128 + c * 2) ^ sw;
    *(f16*)(limg + byt) = h;
    *(f16*)(limg + 16384 + byt) = l;
  }
  __syncthreads();
  char* dst = img + (size_t)blockIdx.x * 32768;
  #pragma unroll
  for (int i = 0; i < 8; ++i)
    *(float4*)(dst + i * 4096 + tid * 16) = *(const float4*)(limg + i * 4096 + tid * 16);
}

// ---------------------------------------------------------------------------
// Fused dist+top20 (UNCHANGED from R6 — validated). Flag = any lane drained
// during pops (conservative certificate).
// ---------------------------------------------------------------------------
__global__ __launch_bounds__(256) void fused_knn(const char* __restrict__ img,
                                                 const float* __restrict__ sq,
                                                 int* __restrict__ knn,
                                                 int* __restrict__ flags) {
  __shared__ char XA[16384];
  __shared__ char XB[2][16384];

  const int tid = threadIdx.x;
  const int lane = tid & 63;
  const int w = tid >> 6;
  const int q = lane >> 4;
  const int s = lane & 15;

  const int blk = blockIdx.x;
  const int b  = blk >> 6;
  const int r0 = (blk & 63) * 64;
  const char* imgb = img + (size_t)b * (NT128 * 32768);
  const float* sqb = sq + (size_t)b * NPTS;

  {  // XA: this block's 64 rows (hi->0, lo->8192). swz(64+j)==swz(j).
    const char* aspan = imgb + (size_t)(r0 >> 7) * 32768 + (size_t)((r0 >> 6) & 1) * 8192;
    #pragma unroll
    for (int i = 0; i < 2; ++i) {
      *(float4*)(XA + i * 4096 + tid * 16) =
          *(const float4*)(aspan + i * 4096 + tid * 16);
      *(float4*)(XA + 8192 + i * 4096 + tid * 16) =
          *(const float4*)(aspan + 16384 + i * 4096 + tid * 16);
    }
  }
  stage64(imgb, XB[0], tid);      // tile 0

  float sqr[4];
  #pragma unroll
  for (int reg = 0; reg < 4; ++reg) sqr[reg] = sqb[r0 + w * 16 + q * 4 + reg];

  float lk[4][8]; u32 lm[4][8];
  #pragma unroll
  for (int reg = 0; reg < 4; ++reg)
    #pragma unroll
    for (int j = 0; j < 8; ++j) { lk[reg][j] = FINF; lm[reg][j] = 0; }

  __syncthreads();                 // XA visible + tile-0 staging drained

  f16x8 Ah[2], Al[2];
  {
    const int j = w * 16 + s;
    const int sw = swz(j) << 4;
    #pragma unroll
    for (int ks = 0; ks < 2; ++ks) {
      int byt = (j * 128 + (ks * 32 + q * 8) * 2) ^ sw;
      Ah[ks] = *(const f16x8*)(XA + byt);
      Al[ks] = *(const f16x8*)(XA + 8192 + byt);
    }
  }

  for (int t = 0; t < NT64; ++t) {
    if (t + 1 < NT64)
      stage64(imgb + (size_t)((t + 1) >> 1) * 32768 + (size_t)((t + 1) & 1) * 8192,
              XB[(t + 1) & 1], tid);
    const char* XBc = XB[t & 1];
    #pragma unroll
    for (int e = 0; e < 4; ++e) {
      const int j = e * 16 + s;
      const int sw = swz(j) << 4;
      f32x4 acc = {0.f, 0.f, 0.f, 0.f};
      #pragma unroll
      for (int ks = 0; ks < 2; ++ks) {
        int byt = (j * 128 + (ks * 32 + q * 8) * 2) ^ sw;
        f16x8 Bh = *(const f16x8*)(XBc + byt);
        f16x8 Bl = *(const f16x8*)(XBc + 8192 + byt);
        acc = __builtin_amdgcn_mfma_f32_16x16x32_f16(Ah[ks], Bh, acc, 0, 0, 0);
        acc = __builtin_amdgcn_mfma_f32_16x16x32_f16(Ah[ks], Bl, acc, 0, 0, 0);
        acc = __builtin_amdgcn_mfma_f32_16x16x32_f16(Al[ks], Bh, acc, 0, 0, 0);
      }
      const int mcol = t * 64 + e * 16 + s;
      const float sm = sqb[mcol];
      #pragma unroll
      for (int reg = 0; reg < 4; ++reg) {
        float v = (sqr[reg] + sm) - 2.0f * acc[reg];
        if (__any(v < lk[reg][7])) ins8(lk[reg], lm[reg], v, (u32)mcol);
      }
    }
    __syncthreads();   // all reads of XB[t&1] done; next-tile staging drained
  }

  // pops: 20 rounds per row; 4 quarters resolve 4 rows concurrently
  #pragma unroll
  for (int reg = 0; reg < 4; ++reg) {
    bool flg = false;
    int iA = 0, iB = 0;
    for (int r = 0; r < KNN; ++r) {
      flg = flg || (rmin16u((lk[reg][0] == FINF) ? 0u : 1u) == 0u);   // any drained
      float wkey = rmin16f(lk[reg][0]);
      u32 cand = (lk[reg][0] == wkey) ? lm[reg][0] : 0xFFFFFFFFu;
      u32 wm = rmin16u(cand);
      if (r < 16) { if (s == r) iA = (int)wm; }
      else if (s == r - 16)     iB = (int)wm;
      bool own = (lk[reg][0] == wkey) && (lm[reg][0] == wm);
      #pragma unroll
      for (int j = 0; j < 7; ++j) {
        lk[reg][j] = own ? lk[reg][j + 1] : lk[reg][j];
        lm[reg][j] = own ? lm[reg][j + 1] : lm[reg][j];
      }
      lk[reg][7] = own ? FINF : lk[reg][7];
      lm[reg][7] = own ? 0u   : lm[reg][7];
    }
    size_t grow = (size_t)b * NPTS + r0 + w * 16 + q * 4 + reg;
    knn[grow * KNN + s] = iA;
    if (s < 4) knn[grow * KNN + 16 + s] = iB;
    if (s == 0) flags[grow] = flg ? 1 : 0;
  }
}

// ---------------------------------------------------------------------------
// compact: gather flagged row ids into list[] (order nondeterministic, but
// per-row fallback results are independent -> output deterministic).
// ---------------------------------------------------------------------------
__global__ __launch_bounds__(256) void compact_kernel(const int* __restrict__ flags,
                                                      int* __restrict__ list,
                                                      int* __restrict__ cnt) {
  int g = blockIdx.x * 256 + threadIdx.x;
  if (flags[g]) {
    int p = atomicAdd(cnt, 1);
    list[p] = g;
  }
}

// ---------------------------------------------------------------------------
// Exact fp32 brute-force for flagged rows. One BLOCK per row (grid-strided
// over compacted list): 4 waves x 1024 cols each; wave-local top-20 via
// depth-8 u64 lists + DPP pops (R3-validated machinery, rebuild kept);
// wave 0 merges 4x20 candidates by 20 DPP pops. Key = (flip(d)<<12|m) ==
// jax (dist, index) lexicographic. Dist ascending-c fp32 (R1-R3 formula).
// ---------------------------------------------------------------------------
__global__ __launch_bounds__(256) void fallback_knn(const float* __restrict__ x,
                                                    const float* __restrict__ sq,
                                                    const int* __restrict__ cnt,
                                                    const int* __restrict__ list,
                                                    int* __restrict__ knn) {
  __shared__ float xrl[CDIM];
  __shared__ u64 cand[4 * KNN];
  const int tid = threadIdx.x, lane = tid & 63, wv = tid >> 6;
  const int count = *cnt;

  for (int it = blockIdx.x; it < count; it += gridDim.x) {
    const int g = list[it];
    const int b = g >> 12, r = g & (NPTS - 1);
    const float* xb  = x  + (size_t)b * CDIM * NPTS;
    const float* sqb = sq + (size_t)b * NPTS;
    if (tid < CDIM) xrl[tid] = xb[(size_t)tid * NPTS + r];
    __syncthreads();
    const float sqr = sqb[r];

    u64 L[8];
    #pragma unroll
    for (int j = 0; j < 8; ++j) L[j] = SENT;
    #pragma unroll
    for (int ii = 0; ii < 4; ++ii) {
      const int i = wv * 4 + ii;                    // chunk of 256 cols
      float a0 = 0.f, a1 = 0.f, a2 = 0.f, a3 = 0.f;
      const float* xp = xb + i * 256 + lane * 4;
      #pragma unroll
      for (int c4 = 0; c4 < 16; ++c4) {
        float4 xr4 = *(const float4*)&xrl[c4 * 4];
        #pragma unroll
        for (int j = 0; j < 4; ++j) {
          float4 xv = *(const float4*)(xp + (size_t)(c4 * 4 + j) * NPTS);
          float xr = (&xr4.x)[j];
          a0 += xr * xv.x; a1 += xr * xv.y; a2 += xr * xv.z; a3 += xr * xv.w;
        }
      }
      int mb = i * 256 + lane * 4;
      float4 sv = *(const float4*)(sqb + mb);
      ins8u(L, ((u64)flip_f32(sqr + sv.x - 2.0f * a0) << 12) | (unsigned)mb);
      ins8u(L, ((u64)flip_f32(sqr + sv.y - 2.0f * a1) << 12) | (unsigned)(mb + 1));
      ins8u(L, ((u64)flip_f32(sqr + sv.z - 2.0f * a2) << 12) | (unsigned)(mb + 2));
      ins8u(L, ((u64)flip_f32(sqr + sv.w - 2.0f * a3) << 12) | (unsigned)(mb + 3));
    }

    // wave-local top-20 pops (exact; rebuild path never fires in practice)
    u64 last = 0; bool done = false;
    for (int rr = 0; rr < KNN; ++rr) {
      bool need = (L[0] == SENT) && !done;
      if (__any(need)) {
        if (need) {
          #pragma unroll
          for (int j = 0; j < 8; ++j) L[j] = SENT;
          for (int ii = 0; ii < 4; ++ii) {
            const int i = wv * 4 + ii;
            float a0 = 0.f, a1 = 0.f, a2 = 0.f, a3 = 0.f;
            const float* xp = xb + i * 256 + lane * 4;
            #pragma unroll
            for (int c4 = 0; c4 < 16; ++c4) {
              float4 xr4 = *(const float4*)&xrl[c4 * 4];
              #pragma unroll
              for (int j = 0; j < 4; ++j) {
                float4 xv = *(const float4*)(xp + (size_t)(c4 * 4 + j) * NPTS);
                float xr = (&xr4.x)[j];
                a0 += xr * xv.x; a1 += xr * xv.y; a2 += xr * xv.z; a3 += xr * xv.w;
              }
            }
            int mb = i * 256 + lane * 4;
            float4 sv = *(const float4*)(sqb + mb);
            u64 v;
            v = ((u64)flip_f32(sqr + sv.x - 2.0f * a0) << 12) | (unsigned)mb;       ins8u(L, v > last ? v : SENT);
            v = ((u64)flip_f32(sqr + sv.y - 2.0f * a1) << 12) | (unsigned)(mb + 1); ins8u(L, v > last ? v : SENT);
            v = ((u64)flip_f32(sqr + sv.z - 2.0f * a2) << 12) | (unsigned)(mb + 2); ins8u(L, v > last ? v : SENT);
            v = ((u64)flip_f32(sqr + sv.w - 2.0f * a3) << 12) | (unsigned)(mb + 3); ins8u(L, v > last ? v : SENT);
          }
          if (L[0] == SENT) done = true;
        }
      }
      unsigned keyH = (unsigned)(L[0] >> 12);
      unsigned wkey = wave_min_u32(keyH);
      unsigned mc   = (keyH == wkey) ? (unsigned)(L[0] & 0xFFF) : 0xFFFFFFFFu;
      unsigned wm   = wave_min_u32(mc);
      u64 wsel = ((u64)wkey << 12) | wm;
      if (lane == rr) cand[wv * KNN + rr] = wsel;
      bool win = (L[0] == wsel);
      #pragma unroll
      for (int j = 0; j < 7; ++j) L[j] = win ? L[j + 1] : L[j];
      L[7] = win ? SENT : L[7];
      last = wsel;
    }
    __syncthreads();

    if (wv == 0) {                       // merge 80 candidates -> top 20
      u64 c0 = cand[lane < 4 * KNN ? lane : 0];
      if (lane >= 4 * KNN) c0 = SENT;
      u64 c1 = (lane < 4 * KNN - 64) ? cand[64 + lane] : SENT;
      int myidx = 0;
      for (int rr = 0; rr < KNN; ++rr) {
        u64 mn = c0 < c1 ? c0 : c1;
        unsigned keyH = (unsigned)(mn >> 12);
        unsigned wkey = wave_min_u32(keyH);
        unsigned mc   = (keyH == wkey) ? (unsigned)(mn & 0xFFF) : 0xFFFFFFFFu;
        unsigned wm   = wave_min_u32(mc);
        u64 wsel = ((u64)wkey << 12) | wm;
        if (lane == rr) myidx = (int)wm;
        if (c0 == wsel)      { c0 = c1; c1 = SENT; }
        else if (c1 == wsel) { c1 = SENT; }
      }
      if (lane < KNN) knn[(size_t)g * KNN + lane] = myidx;
    }
    __syncthreads();                     // cand/xrl reusable next iteration
  }
}

// ---------------------------------------------------------------------------
// a[b][n][o]  = sum_c (W[o][c]-W[o][c+64]) * x[b][c][n]
// cc[b][n][o] = sum_c  W[o][c+64]          * x[b][c][n]
// ---------------------------------------------------------------------------
__global__ __launch_bounds__(256) void proj_kernel(const float* __restrict__ x,
                                                   const float* __restrict__ w,
                                                   float* __restrict__ a,
                                                   float* __restrict__ cc) {
  __shared__ float wa[CDIM][ODIM];
  __shared__ float wc[CDIM][ODIM];
  const int tid = threadIdx.x;
  #pragma unroll
  for (int p = 0; p < 16; ++p) {
    int idx = p * 256 + tid;
    int o = idx & 63, c = idx >> 6;
    float w1 = w[o * 128 + c], w2 = w[o * 128 + 64 + c];
    wa[c][o] = w1 - w2;
    wc[c][o] = w2;
  }
  __syncthreads();

  const int og = tid >> 6;
  const int nl = tid & 63;
  const int g0 = blockIdx.x * 128;
  const int b  = g0 >> 12;
  const int n0 = g0 & (NPTS - 1);
  const float* xB = x + (size_t)b * CDIM * NPTS;

  float aa0[16], ac0[16], aa1[16], ac1[16];
  #pragma unroll
  for (int qq = 0; qq < 16; ++qq) { aa0[qq] = ac0[qq] = aa1[qq] = ac1[qq] = 0.f; }

  #pragma unroll 4
  for (int c = 0; c < CDIM; ++c) {
    float xv0 = xB[(size_t)c * NPTS + n0 + nl];
    float xv1 = xB[(size_t)c * NPTS + n0 + 64 + nl];
    #pragma unroll
    for (int q4 = 0; q4 < 4; ++q4) {
      float4 va = *(const float4*)&wa[c][og * 16 + q4 * 4];
      float4 vc = *(const float4*)&wc[c][og * 16 + q4 * 4];
      aa0[q4*4+0] += va.x * xv0; aa0[q4*4+1] += va.y * xv0;
      aa0[q4*4+2] += va.z * xv0; aa0[q4*4+3] += va.w * xv0;
      ac0[q4*4+0] += vc.x * xv0; ac0[q4*4+1] += vc.y * xv0;
      ac0[q4*4+2] += vc.z * xv0; ac0[q4*4+3] += vc.w * xv0;
      aa1[q4*4+0] += va.x * xv1; aa1[q4*4+1] += va.y * xv1;
      aa1[q4*4+2] += va.z * xv1; aa1[q4*4+3] += va.w * xv1;
      ac1[q4*4+0] += vc.x * xv1; ac1[q4*4+1] += vc.y * xv1;
      ac1[q4*4+2] += vc.z * xv1; ac1[q4*4+3] += vc.w * xv1;
    }
  }
  size_t ga0 = (size_t)(g0 + nl) * ODIM + og * 16;
  size_t ga1 = (size_t)(g0 + 64 + nl) * ODIM + og * 16;
  #pragma unroll
  for (int q4 = 0; q4 < 4; ++q4) {
    *(float4*)&a [ga0 + q4 * 4] = *(float4*)&aa0[q4 * 4];
    *(float4*)&cc[ga0 + q4 * 4] = *(float4*)&ac0[q4 * 4];
    *(float4*)&a [ga1 + q4 * 4] = *(float4*)&aa1[q4 * 4];
    *(float4*)&cc[ga1 + q4 * 4] = *(float4*)&ac1[q4 * 4];
  }
}

// ---------------------------------------------------------------------------
// out[b][o][n] = relu(inv[o] * max_k(a[b][n][o] + cc[b][knn[n][k]][o]) + bias[o])
// ---------------------------------------------------------------------------
__global__ __launch_bounds__(256) void out_kernel(const float* __restrict__ a,
                                                  const float* __restrict__ cc,
                                                  const int* __restrict__ knn,
                                                  const float* __restrict__ gamma,
                                                  const float* __restrict__ beta,
                                                  const float* __restrict__ mean,
                                                  const float* __restrict__ var,
                                                  float* __restrict__ out) {
  __shared__ float tile[64][65];
  const int tid = threadIdx.x, lane = tid & 63, wv = tid >> 6;
  const int b = blockIdx.y;
  const int n0 = blockIdx.x * 64;
  float inv  = gamma[lane] / sqrtf(var[lane] + 1e-5f);
  float bias = beta[lane] - mean[lane] * inv;
  for (int t = 0; t < 16; ++t) {
    int nl = wv * 16 + t;
    size_t base = (size_t)b * NPTS + (n0 + nl);
    float av = a[base * ODIM + lane];
    const int* kr = knn + base * KNN;
    float m = -INFINITY;
    #pragma unroll
    for (int k = 0; k < KNN; ++k) {
      int j = kr[k];
      float cv = cc[((size_t)b * NPTS + j) * ODIM + lane];
      m = fmaxf(m, av + cv);
    }
    float v = m * inv + bias;
    tile[nl][lane] = v > 0.f ? v : 0.f;
  }
  __syncthreads();
  for (int t = 0; t < 16; ++t) {
    int o = wv * 16 + t;
    out[((size_t)b * ODIM + o) * NPTS + n0 + lane] = tile[lane][o];
  }
}

// ---------------------------------------------------------------------------
extern "C" void kernel_launch(void* const* d_in, const int* in_sizes, int n_in,
                              void* d_out, int out_size, void* d_ws, size_t ws_size,
                              hipStream_t stream) {
  const float* x     = (const float*)d_in[0];
  const float* w     = (const float*)d_in[1];
  const float* gamma = (const float*)d_in[2];
  const float* beta  = (const float*)d_in[3];
  const float* mean  = (const float*)d_in[4];
  const float* var   = (const float*)d_in[5];
  float* out = (float*)d_out;

  char* wsb = (char*)d_ws;
  size_t off = 0;
  int*   knn   = (int*)(wsb + off);   off += (size_t)BDIM * NPTS * KNN * 4;   // 2.62 MB
  int*   flags = (int*)(wsb + off);   off += (size_t)BDIM * NPTS * 4;         // 0.13 MB
  int*   list  = (int*)(wsb + off);   off += (size_t)BDIM * NPTS * 4;         // 0.13 MB
  int*   cnt   = (int*)(wsb + off);   off += 256;
  float* sqw   = (float*)(wsb + off); off += (size_t)BDIM * NPTS * 4;         // 0.13 MB
  float* a     = (float*)(wsb + off); off += (size_t)BDIM * NPTS * ODIM * 4;  // 8 MB
  float* cc    = (float*)(wsb + off); off += (size_t)BDIM * NPTS * ODIM * 4;  // 8 MB
  char*  img   = wsb + off;           off += (size_t)BDIM * NT128 * 32768;    // 8 MB
  (void)ws_size;

  prep_kernel   <<<BDIM * NT128, 256, 0, stream>>>(x, img);
  sq_kernel     <<<BDIM * NPTS / 256, 256, 0, stream>>>(x, sqw, cnt);
  proj_kernel   <<<BDIM * NPTS / 128, 256, 0, stream>>>(x, w, a, cc);
  fused_knn     <<<512, 256, 0, stream>>>(img, sqw, knn, flags);
  compact_kernel<<<BDIM * NPTS / 256, 256, 0, stream>>>(flags, list, cnt);
  fallback_knn  <<<1024, 256, 0, stream>>>(x, sqw, cnt, list, knn);
  out_kernel    <<<dim3(NPTS / 64, BDIM), 256, 0, stream>>>(a, cc, knn, gamma, beta,
                                                            mean, var, out);
}

// Round 8
// 341.367 us; speedup vs baseline: 3.8715x; 1.1753x over previous
//
#include <hip/hip_runtime.h>
#include <cstdint>
#include <cstddef>

#define NPTS 4096
#define CDIM 64
#define BDIM 8
#define KNN  20
#define ODIM 64
#define NT128 32          // 128-col tile images per batch (prep layout)
#define NT64  64          // 64-col compute tiles per batch (fused)

typedef unsigned long long u64;
typedef unsigned int u32;
typedef _Float16 f16;
using f16x8 = __attribute__((ext_vector_type(8))) _Float16;
using f32x4 = __attribute__((ext_vector_type(4))) float;
#define SENT   (~0ull)
#define SENT32 0xFFFFFFFFu
#define FINF (__builtin_inff())

__device__ __forceinline__ int swz(int r) { return (r & 7) ^ ((r >> 3) & 7); }

// order-preserving float->u32 flip (ascending float == ascending u32)
__device__ __forceinline__ unsigned flip_f32(float d) {
  unsigned bits = __float_as_uint(d);
  return bits ^ (unsigned)(((int)bits >> 31) | 0x80000000u);
}

// wave64 all-reduce min (DPP), uniform via readlane 63  (R3-validated)
__device__ __forceinline__ unsigned wave_min_u32(unsigned v) {
  unsigned t;
  t = (unsigned)__builtin_amdgcn_update_dpp((int)v, (int)v, 0x111, 0xF, 0xF, false); v = t < v ? t : v;
  t = (unsigned)__builtin_amdgcn_update_dpp((int)v, (int)v, 0x112, 0xF, 0xF, false); v = t < v ? t : v;
  t = (unsigned)__builtin_amdgcn_update_dpp((int)v, (int)v, 0x114, 0xF, 0xF, false); v = t < v ? t : v;
  t = (unsigned)__builtin_amdgcn_update_dpp((int)v, (int)v, 0x118, 0xF, 0xF, false); v = t < v ? t : v;
  t = (unsigned)__builtin_amdgcn_update_dpp((int)v, (int)v, 0x142, 0xA, 0xF, false); v = t < v ? t : v;
  t = (unsigned)__builtin_amdgcn_update_dpp((int)v, (int)v, 0x143, 0xC, 0xF, false); v = t < v ? t : v;
  return (unsigned)__builtin_amdgcn_readlane((int)v, 63);
}

// 16-lane all-reduce min (quad xor1, xor2, row_ror4, row_ror8) — R5-R7 validated
__device__ __forceinline__ u32 rmin16u(u32 v) {
  int t;
  t = __builtin_amdgcn_update_dpp((int)v, (int)v, 0xB1,  0xF, 0xF, false); v = ((u32)t < v) ? (u32)t : v;
  t = __builtin_amdgcn_update_dpp((int)v, (int)v, 0x4E,  0xF, 0xF, false); v = ((u32)t < v) ? (u32)t : v;
  t = __builtin_amdgcn_update_dpp((int)v, (int)v, 0x124, 0xF, 0xF, false); v = ((u32)t < v) ? (u32)t : v;
  t = __builtin_amdgcn_update_dpp((int)v, (int)v, 0x128, 0xF, 0xF, false); v = ((u32)t < v) ? (u32)t : v;
  return v;
}

// branchless insert into ascending sorted-8 of u64 keys (bubble, drops max)
__device__ __forceinline__ void ins8u(u64 (&L)[8], u64 v) {
  u64 c = v;
  #pragma unroll
  for (int j = 0; j < 8; ++j) {
    u64 lo = c < L[j] ? c : L[j];
    u64 hi = c < L[j] ? L[j] : c;
    L[j] = lo; c = hi;
  }
}

// async global->LDS, 16B per lane; LDS dest is wave-uniform base + lane*16
__device__ __forceinline__ void gl16(const char* g, char* l) {
  __builtin_amdgcn_global_load_lds(
      (const __attribute__((address_space(1))) unsigned int*)g,
      (__attribute__((address_space(3))) unsigned int*)l, 16, 0, 0);
}
// stage one 64-col tile (hi 8KB + lo 8KB) into a 16KB LDS buffer
__device__ __forceinline__ void stage64(const char* src_hi, char* dst, int tid) {
  const int w = tid >> 6, lane = tid & 63;
  const int off = w * 2048 + (lane << 4);
  gl16(src_hi + off,                 dst + w * 2048);
  gl16(src_hi + off + 1024,          dst + w * 2048 + 1024);
  gl16(src_hi + 16384 + off,         dst + 8192 + w * 2048);
  gl16(src_hi + 16384 + off + 1024,  dst + 8192 + w * 2048 + 1024);
}

// ---------------------------------------------------------------------------
// sq[b][n] = sum_c x[b][c][n]^2   (ascending c — BIT-IDENTICAL to R3-R7;
// sq numerics feed dist boundaries, do not touch). Also zeroes cnt.
// ---------------------------------------------------------------------------
__global__ __launch_bounds__(256) void sq_kernel(const float* __restrict__ x,
                                                 float* __restrict__ sq,
                                                 int* __restrict__ cnt) {
  if (blockIdx.x == 0 && threadIdx.x == 0) *cnt = 0;
  int g = blockIdx.x * 256 + threadIdx.x;
  int b = g >> 12, n = g & (NPTS - 1);
  const float* xb = x + (size_t)b * CDIM * NPTS + n;
  float s = 0.f;
  #pragma unroll
  for (int c = 0; c < CDIM; ++c) { float v = xb[(size_t)c * NPTS]; s += v * v; }
  sq[g] = s;
}

// ---------------------------------------------------------------------------
// prep: per-(b,128-tile) fp16 hi/lo images, exact swizzled layout
// byte(n',c) = (n'*128 + 2c) ^ (swz(n')<<4); hi at +0, lo at +16384.
// Rewritten with 16B LDS writes (8 x ds_write_b128/thread, 2-way = free)
// instead of 64 scalar b16 writes (8-way conflicts). Bytes identical.
// ---------------------------------------------------------------------------
__global__ __launch_bounds__(256) void prep_kernel(const float* __restrict__ x,
                                                   char* __restrict__ img) {
  __shared__ char limg[32768];
  const int tid = threadIdx.x;
  const int b = blockIdx.x >> 5;
  const int t = blockIdx.x & 31;
  const int np = tid & 127;
  const int half = tid >> 7;
  const float* xb = x + (size_t)b * CDIM * NPTS + t * 128 + np;
  const int sw = swz(np) << 4;
  #pragma unroll
  for (int oct = 0; oct < 4; ++oct) {
    const int cb = half * 32 + oct * 8;
    f16x8 hv, lv;
    #pragma unroll
    for (int j = 0; j < 8; ++j) {
      float v = xb[(size_t)(cb + j) * NPTS];
      f16 h = (f16)v;
      hv[j] = h;
      lv[j] = (f16)(v - (float)h);
    }
    int byt = (np * 128 + cb * 2) ^ sw;
    *(f16x8*)(limg + byt) = hv;
    *(f16x8*)(limg + 16384 + byt) = lv;
  }
  __syncthreads();
  char* dst = img + (size_t)blockIdx.x * 32768;
  #pragma unroll
  for (int i = 0; i < 8; ++i)
    *(float4*)(dst + i * 4096 + tid * 16) = *(const float4*)(limg + i * 4096 + tid * 16);
}

// ---------------------------------------------------------------------------
// Fused dist+top20. MFMA fp16x3 (hh,hl,lh; ks ascending — BIT-IDENTICAL dists
// to R4-R7). Selection: u32 keys (flip(d)&0xFFFFFF00)|(mcol>>4) — low 4 bits
// of a lane's column are its own s, so 8 index bits suffice. Sorted-8 bubble
// insert (16 VALU). 21 pop rounds of rmin16u; winner lane via ballot.
// Flag (-> exact fallback) iff: lane drained, OR 24-bit dist-prefix tie at
// the 20/21 boundary, OR multi-owner pop. Provably catches any set error.
// ---------------------------------------------------------------------------
__global__ __launch_bounds__(256) void fused_knn(const char* __restrict__ img,
                                                 const float* __restrict__ sq,
                                                 int* __restrict__ knn,
                                                 int* __restrict__ flags) {
  __shared__ char XB[2][16384];

  const int tid = threadIdx.x;
  const int lane = tid & 63;
  const int w = tid >> 6;
  const int q = lane >> 4;
  const int s = lane & 15;

  const int blk = blockIdx.x;
  const int b  = blk >> 6;
  const int r0 = (blk & 63) * 64;
  const char* imgb = img + (size_t)b * (NT128 * 32768);
  const float* sqb = sq + (size_t)b * NPTS;

  stage64(imgb, XB[0], tid);      // tile 0

  // A fragments straight from global img (L2/L3-resident), same byte layout
  f16x8 Ah[2], Al[2];
  {
    const int grow = r0 + w * 16 + s;
    const char* at = imgb + (size_t)(grow >> 7) * 32768;
    const int nn = grow & 127;
    const int swn = swz(nn) << 4;
    #pragma unroll
    for (int ks = 0; ks < 2; ++ks) {
      int byt = (nn * 128 + (ks * 32 + q * 8) * 2) ^ swn;
      Ah[ks] = *(const f16x8*)(at + byt);
      Al[ks] = *(const f16x8*)(at + 16384 + byt);
    }
  }

  float sqr[4];
  #pragma unroll
  for (int reg = 0; reg < 4; ++reg) sqr[reg] = sqb[r0 + w * 16 + q * 4 + reg];

  u32 L[4][8];
  #pragma unroll
  for (int reg = 0; reg < 4; ++reg)
    #pragma unroll
    for (int j = 0; j < 8; ++j) L[reg][j] = SENT32;

  __syncthreads();                 // tile-0 staging drained

  for (int t = 0; t < NT64; ++t) {
    if (t + 1 < NT64)
      stage64(imgb + (size_t)((t + 1) >> 1) * 32768 + (size_t)((t + 1) & 1) * 8192,
              XB[(t + 1) & 1], tid);
    const char* XBc = XB[t & 1];
    #pragma unroll
    for (int e = 0; e < 4; ++e) {
      const int j = e * 16 + s;
      const int swj = swz(j) << 4;
      f32x4 acc = {0.f, 0.f, 0.f, 0.f};
      #pragma unroll
      for (int ks = 0; ks < 2; ++ks) {
        int byt = (j * 128 + (ks * 32 + q * 8) * 2) ^ swj;
        f16x8 Bh = *(const f16x8*)(XBc + byt);
        f16x8 Bl = *(const f16x8*)(XBc + 8192 + byt);
        acc = __builtin_amdgcn_mfma_f32_16x16x32_f16(Ah[ks], Bh, acc, 0, 0, 0);
        acc = __builtin_amdgcn_mfma_f32_16x16x32_f16(Ah[ks], Bl, acc, 0, 0, 0);
        acc = __builtin_amdgcn_mfma_f32_16x16x32_f16(Al[ks], Bh, acc, 0, 0, 0);
      }
      const int mcol = t * 64 + e * 16 + s;
      const float sm = sqb[mcol];
      const u32 klo = (u32)(t * 4 + e);       // = mcol >> 4, wave-uniform
      #pragma unroll
      for (int reg = 0; reg < 4; ++reg) {
        float v = (sqr[reg] + sm) - 2.0f * acc[reg];
        u32 key = (flip_f32(v) & 0xFFFFFF00u) | klo;
        if (__any(key < L[reg][7])) {
          u32 c = key;
          #pragma unroll
          for (int jj = 0; jj < 8; ++jj) {
            u32 lo = c < L[reg][jj] ? c : L[reg][jj];
            u32 hi = c < L[reg][jj] ? L[reg][jj] : c;
            L[reg][jj] = lo; c = hi;
          }
        }
      }
    }
    __syncthreads();   // reads of XB[t&1] done; next-tile staging drained
  }

  // pops: 21 rounds per row (20 results + boundary probe); 4 quarters
  // resolve 4 rows concurrently.
  #pragma unroll
  for (int reg = 0; reg < 4; ++reg) {
    bool flg = false;
    int iA = 0, iB = 0;
    u32 k20 = 0, k21 = 0;
    for (int r = 0; r < KNN + 1; ++r) {
      u32 head = L[reg][0];
      u32 wkey = rmin16u(head);
      unsigned long long bal = __ballot(head == wkey);
      unsigned qm = (unsigned)((bal >> (q * 16)) & 0xFFFFull);
      int swin = __ffs((int)qm) - 1;
      flg = flg || ((qm & (qm - 1u)) != 0u);          // multi-owner key tie
      int idx = (int)(((wkey & 0xFFu) << 4) | (u32)swin);
      if (r < 16) { if (s == r) iA = idx; }
      else if (r < KNN) { if (s == r - 16) iB = idx; }
      if (r == KNN - 1) k20 = wkey;
      if (r == KNN)     k21 = wkey;
      bool own = (head == wkey) && (s == swin);
      #pragma unroll
      for (int jj = 0; jj < 7; ++jj) L[reg][jj] = own ? L[reg][jj + 1] : L[reg][jj];
      L[reg][7] = own ? SENT32 : L[reg][7];
    }
    flg = flg || ((k20 >> 8) == (k21 >> 8));          // boundary prefix tie
    u32 alive = (L[reg][0] == SENT32) ? 0u : 1u;      // drained lane
    flg = flg || (rmin16u(alive) == 0u);
    size_t grow = (size_t)b * NPTS + r0 + w * 16 + q * 4 + reg;
    knn[grow * KNN + s] = iA;
    if (s < 4) knn[grow * KNN + 16 + s] = iB;
    if (s == 0) flags[grow] = flg ? 1 : 0;
  }
}

// ---------------------------------------------------------------------------
// compact: gather flagged row ids into list[].
// ---------------------------------------------------------------------------
__global__ __launch_bounds__(256) void compact_kernel(const int* __restrict__ flags,
                                                      int* __restrict__ list,
                                                      int* __restrict__ cnt) {
  int g = blockIdx.x * 256 + threadIdx.x;
  if (flags[g]) {
    int p = atomicAdd(cnt, 1);
    list[p] = g;
  }
}

// ---------------------------------------------------------------------------
// Exact fp32 brute-force for flagged rows (R7-validated). One BLOCK per row,
// grid-strided over compacted list. (d,m)-lexicographic u64 keys.
// ---------------------------------------------------------------------------
__global__ __launch_bounds__(256) void fallback_knn(const float* __restrict__ x,
                                                    const float* __restrict__ sq,
                                                    const int* __restrict__ cnt,
                                                    const int* __restrict__ list,
                                                    int* __restrict__ knn) {
  __shared__ float xrl[CDIM];
  __shared__ u64 cand[4 * KNN];
  const int tid = threadIdx.x, lane = tid & 63, wv = tid >> 6;
  const int count = *cnt;

  for (int it = blockIdx.x; it < count; it += gridDim.x) {
    const int g = list[it];
    const int b = g >> 12, r = g & (NPTS - 1);
    const float* xb  = x  + (size_t)b * CDIM * NPTS;
    const float* sqb = sq + (size_t)b * NPTS;
    if (tid < CDIM) xrl[tid] = xb[(size_t)tid * NPTS + r];
    __syncthreads();
    const float sqr = sqb[r];

    u64 L[8];
    #pragma unroll
    for (int j = 0; j < 8; ++j) L[j] = SENT;
    #pragma unroll
    for (int ii = 0; ii < 4; ++ii) {
      const int i = wv * 4 + ii;
      float a0 = 0.f, a1 = 0.f, a2 = 0.f, a3 = 0.f;
      const float* xp = xb + i * 256 + lane * 4;
      #pragma unroll
      for (int c4 = 0; c4 < 16; ++c4) {
        float4 xr4 = *(const float4*)&xrl[c4 * 4];
        #pragma unroll
        for (int j = 0; j < 4; ++j) {
          float4 xv = *(const float4*)(xp + (size_t)(c4 * 4 + j) * NPTS);
          float xr = (&xr4.x)[j];
          a0 += xr * xv.x; a1 += xr * xv.y; a2 += xr * xv.z; a3 += xr * xv.w;
        }
      }
      int mb = i * 256 + lane * 4;
      float4 sv = *(const float4*)(sqb + mb);
      ins8u(L, ((u64)flip_f32(sqr + sv.x - 2.0f * a0) << 12) | (unsigned)mb);
      ins8u(L, ((u64)flip_f32(sqr + sv.y - 2.0f * a1) << 12) | (unsigned)(mb + 1));
      ins8u(L, ((u64)flip_f32(sqr + sv.z - 2.0f * a2) << 12) | (unsigned)(mb + 2));
      ins8u(L, ((u64)flip_f32(sqr + sv.w - 2.0f * a3) << 12) | (unsigned)(mb + 3));
    }

    u64 last = 0; bool done = false;
    for (int rr = 0; rr < KNN; ++rr) {
      bool need = (L[0] == SENT) && !done;
      if (__any(need)) {
        if (need) {                                  // never fires in practice
          #pragma unroll
          for (int j = 0; j < 8; ++j) L[j] = SENT;
          for (int ii = 0; ii < 4; ++ii) {
            const int i = wv * 4 + ii;
            float a0 = 0.f, a1 = 0.f, a2 = 0.f, a3 = 0.f;
            const float* xp = xb + i * 256 + lane * 4;
            #pragma unroll
            for (int c4 = 0; c4 < 16; ++c4) {
              float4 xr4 = *(const float4*)&xrl[c4 * 4];
              #pragma unroll
              for (int j = 0; j < 4; ++j) {
                float4 xv = *(const float4*)(xp + (size_t)(c4 * 4 + j) * NPTS);
                float xr = (&xr4.x)[j];
                a0 += xr * xv.x; a1 += xr * xv.y; a2 += xr * xv.z; a3 += xr * xv.w;
              }
            }
            int mb = i * 256 + lane * 4;
            float4 sv = *(const float4*)(sqb + mb);
            u64 v;
            v = ((u64)flip_f32(sqr + sv.x - 2.0f * a0) << 12) | (unsigned)mb;       ins8u(L, v > last ? v : SENT);
            v = ((u64)flip_f32(sqr + sv.y - 2.0f * a1) << 12) | (unsigned)(mb + 1); ins8u(L, v > last ? v : SENT);
            v = ((u64)flip_f32(sqr + sv.z - 2.0f * a2) << 12) | (unsigned)(mb + 2); ins8u(L, v > last ? v : SENT);
            v = ((u64)flip_f32(sqr + sv.w - 2.0f * a3) << 12) | (unsigned)(mb + 3); ins8u(L, v > last ? v : SENT);
          }
          if (L[0] == SENT) done = true;
        }
      }
      unsigned keyH = (unsigned)(L[0] >> 12);
      unsigned wkey = wave_min_u32(keyH);
      unsigned mc   = (keyH == wkey) ? (unsigned)(L[0] & 0xFFF) : 0xFFFFFFFFu;
      unsigned wm   = wave_min_u32(mc);
      u64 wsel = ((u64)wkey << 12) | wm;
      if (lane == rr) cand[wv * KNN + rr] = wsel;
      bool win = (L[0] == wsel);
      #pragma unroll
      for (int j = 0; j < 7; ++j) L[j] = win ? L[j + 1] : L[j];
      L[7] = win ? SENT : L[7];
      last = wsel;
    }
    __syncthreads();

    if (wv == 0) {                       // merge 80 candidates -> top 20
      u64 c0 = cand[lane < 4 * KNN ? lane : 0];
      if (lane >= 4 * KNN) c0 = SENT;
      u64 c1 = (lane < 4 * KNN - 64) ? cand[64 + lane] : SENT;
      int myidx = 0;
      for (int rr = 0; rr < KNN; ++rr) {
        u64 mn = c0 < c1 ? c0 : c1;
        unsigned keyH = (unsigned)(mn >> 12);
        unsigned wkey = wave_min_u32(keyH);
        unsigned mc   = (keyH == wkey) ? (unsigned)(mn & 0xFFF) : 0xFFFFFFFFu;
        unsigned wm   = wave_min_u32(mc);
        u64 wsel = ((u64)wkey << 12) | wm;
        if (lane == rr) myidx = (int)wm;
        if (c0 == wsel)      { c0 = c1; c1 = SENT; }
        else if (c1 == wsel) { c1 = SENT; }
      }
      if (lane < KNN) knn[(size_t)g * KNN + lane] = myidx;
    }
    __syncthreads();
  }
}

// ---------------------------------------------------------------------------
// a[b][n][o]  = sum_c (W[o][c]-W[o][c+64]) * x[b][c][n]
// cc[b][n][o] = sum_c  W[o][c+64]          * x[b][c][n]
// ---------------------------------------------------------------------------
__global__ __launch_bounds__(256) void proj_kernel(const float* __restrict__ x,
                                                   const float* __restrict__ w,
                                                   float* __restrict__ a,
                                                   float* __restrict__ cc) {
  __shared__ float wa[CDIM][ODIM];
  __shared__ float wc[CDIM][ODIM];
  const int tid = threadIdx.x;
  #pragma unroll
  for (int p = 0; p < 16; ++p) {
    int idx = p * 256 + tid;
    int o = idx & 63, c = idx >> 6;
    float w1 = w[o * 128 + c], w2 = w[o * 128 + 64 + c];
    wa[c][o] = w1 - w2;
    wc[c][o] = w2;
  }
  __syncthreads();

  const int og = tid >> 6;
  const int nl = tid & 63;
  const int g0 = blockIdx.x * 128;
  const int b  = g0 >> 12;
  const int n0 = g0 & (NPTS - 1);
  const float* xB = x + (size_t)b * CDIM * NPTS;

  float aa0[16], ac0[16], aa1[16], ac1[16];
  #pragma unroll
  for (int qq = 0; qq < 16; ++qq) { aa0[qq] = ac0[qq] = aa1[qq] = ac1[qq] = 0.f; }

  #pragma unroll 4
  for (int c = 0; c < CDIM; ++c) {
    float xv0 = xB[(size_t)c * NPTS + n0 + nl];
    float xv1 = xB[(size_t)c * NPTS + n0 + 64 + nl];
    #pragma unroll
    for (int q4 = 0; q4 < 4; ++q4) {
      float4 va = *(const float4*)&wa[c][og * 16 + q4 * 4];
      float4 vc = *(const float4*)&wc[c][og * 16 + q4 * 4];
      aa0[q4*4+0] += va.x * xv0; aa0[q4*4+1] += va.y * xv0;
      aa0[q4*4+2] += va.z * xv0; aa0[q4*4+3] += va.w * xv0;
      ac0[q4*4+0] += vc.x * xv0; ac0[q4*4+1] += vc.y * xv0;
      ac0[q4*4+2] += vc.z * xv0; ac0[q4*4+3] += vc.w * xv0;
      aa1[q4*4+0] += va.x * xv1; aa1[q4*4+1] += va.y * xv1;
      aa1[q4*4+2] += va.z * xv1; aa1[q4*4+3] += va.w * xv1;
      ac1[q4*4+0] += vc.x * xv1; ac1[q4*4+1] += vc.y * xv1;
      ac1[q4*4+2] += vc.z * xv1; ac1[q4*4+3] += vc.w * xv1;
    }
  }
  size_t ga0 = (size_t)(g0 + nl) * ODIM + og * 16;
  size_t ga1 = (size_t)(g0 + 64 + nl) * ODIM + og * 16;
  #pragma unroll
  for (int q4 = 0; q4 < 4; ++q4) {
    *(float4*)&a [ga0 + q4 * 4] = *(float4*)&aa0[q4 * 4];
    *(float4*)&cc[ga0 + q4 * 4] = *(float4*)&ac0[q4 * 4];
    *(float4*)&a [ga1 + q4 * 4] = *(float4*)&aa1[q4 * 4];
    *(float4*)&cc[ga1 + q4 * 4] = *(float4*)&ac1[q4 * 4];
  }
}

// ---------------------------------------------------------------------------
// out[b][o][n] = relu(inv[o] * max_k(a[b][n][o] + cc[b][knn[n][k]][o]) + bias[o])
// ---------------------------------------------------------------------------
__global__ __launch_bounds__(256) void out_kernel(const float* __restrict__ a,
                                                  const float* __restrict__ cc,
                                                  const int* __restrict__ knn,
                                                  const float* __restrict__ gamma,
                                                  const float* __restrict__ beta,
                                                  const float* __restrict__ mean,
                                                  const float* __restrict__ var,
                                                  float* __restrict__ out) {
  __shared__ float tile[64][65];
  const int tid = threadIdx.x, lane = tid & 63, wv = tid >> 6;
  const int b = blockIdx.y;
  const int n0 = blockIdx.x * 64;
  float inv  = gamma[lane] / sqrtf(var[lane] + 1e-5f);
  float bias = beta[lane] - mean[lane] * inv;
  for (int t = 0; t < 16; ++t) {
    int nl = wv * 16 + t;
    size_t base = (size_t)b * NPTS + (n0 + nl);
    float av = a[base * ODIM + lane];
    const int* kr = knn + base * KNN;
    float m = -INFINITY;
    #pragma unroll
    for (int k = 0; k < KNN; ++k) {
      int j = kr[k];
      float cv = cc[((size_t)b * NPTS + j) * ODIM + lane];
      m = fmaxf(m, av + cv);
    }
    float v = m * inv + bias;
    tile[nl][lane] = v > 0.f ? v : 0.f;
  }
  __syncthreads();
  for (int t = 0; t < 16; ++t) {
    int o = wv * 16 + t;
    out[((size_t)b * ODIM + o) * NPTS + n0 + lane] = tile[lane][o];
  }
}

// ---------------------------------------------------------------------------
extern "C" void kernel_launch(void* const* d_in, const int* in_sizes, int n_in,
                              void* d_out, int out_size, void* d_ws, size_t ws_size,
                              hipStream_t stream) {
  const float* x     = (const float*)d_in[0];
  const float* w     = (const float*)d_in[1];
  const float* gamma = (const float*)d_in[2];
  const float* beta  = (const float*)d_in[3];
  const float* mean  = (const float*)d_in[4];
  const float* var   = (const float*)d_in[5];
  float* out = (float*)d_out;

  char* wsb = (char*)d_ws;
  size_t off = 0;
  int*   knn   = (int*)(wsb + off);   off += (size_t)BDIM * NPTS * KNN * 4;   // 2.62 MB
  int*   flags = (int*)(wsb + off);   off += (size_t)BDIM * NPTS * 4;         // 0.13 MB
  int*   list  = (int*)(wsb + off);   off += (size_t)BDIM * NPTS * 4;         // 0.13 MB
  int*   cnt   = (int*)(wsb + off);   off += 256;
  float* sqw   = (float*)(wsb + off); off += (size_t)BDIM * NPTS * 4;         // 0.13 MB
  float* a     = (float*)(wsb + off); off += (size_t)BDIM * NPTS * ODIM * 4;  // 8 MB
  float* cc    = (float*)(wsb + off); off += (size_t)BDIM * NPTS * ODIM * 4;  // 8 MB
  char*  img   = wsb + off;           off += (size_t)BDIM * NT128 * 32768;    // 8 MB
  (void)ws_size;

  prep_kernel   <<<BDIM * NT128, 256, 0, stream>>>(x, img);
  sq_kernel     <<<BDIM * NPTS / 256, 256, 0, stream>>>(x, sqw, cnt);
  proj_kernel   <<<BDIM * NPTS / 128, 256, 0, stream>>>(x, w, a, cc);
  fused_knn     <<<512, 256, 0, stream>>>(img, sqw, knn, flags);
  compact_kernel<<<BDIM * NPTS / 256, 256, 0, stream>>>(flags, list, cnt);
  fallback_knn  <<<2048, 256, 0, stream>>>(x, sqw, cnt, list, knn);
  out_kernel    <<<dim3(NPTS / 64, BDIM), 256, 0, stream>>>(a, cc, knn, gamma, beta,
                                                            mean, var, out);
}

// Round 9
// 325.448 us; speedup vs baseline: 4.0609x; 1.0489x over previous
//
#include <hip/hip_runtime.h>
#include <cstdint>
#include <cstddef>

#define NPTS 4096
#define CDIM 64
#define BDIM 8
#define KNN  20
#define ODIM 64
#define NT128 32          // 128-col tile images per batch (prep layout)
#define NT64  64          // 64-col compute tiles per batch (fused)

typedef unsigned long long u64;
typedef unsigned int u32;
typedef _Float16 f16;
using f16x8 = __attribute__((ext_vector_type(8))) _Float16;
using f32x4 = __attribute__((ext_vector_type(4))) float;
#define SENT   (~0ull)
#define SENT32 0xFFFFFFFFu
#define FINF (__builtin_inff())

__device__ __forceinline__ int swz(int r) { return (r & 7) ^ ((r >> 3) & 7); }

// order-preserving float->u32 flip (ascending float == ascending u32)
__device__ __forceinline__ unsigned flip_f32(float d) {
  unsigned bits = __float_as_uint(d);
  return bits ^ (unsigned)(((int)bits >> 31) | 0x80000000u);
}

// wave64 all-reduce min (DPP), uniform via readlane 63  (R3-validated)
__device__ __forceinline__ unsigned wave_min_u32(unsigned v) {
  unsigned t;
  t = (unsigned)__builtin_amdgcn_update_dpp((int)v, (int)v, 0x111, 0xF, 0xF, false); v = t < v ? t : v;
  t = (unsigned)__builtin_amdgcn_update_dpp((int)v, (int)v, 0x112, 0xF, 0xF, false); v = t < v ? t : v;
  t = (unsigned)__builtin_amdgcn_update_dpp((int)v, (int)v, 0x114, 0xF, 0xF, false); v = t < v ? t : v;
  t = (unsigned)__builtin_amdgcn_update_dpp((int)v, (int)v, 0x118, 0xF, 0xF, false); v = t < v ? t : v;
  t = (unsigned)__builtin_amdgcn_update_dpp((int)v, (int)v, 0x142, 0xA, 0xF, false); v = t < v ? t : v;
  t = (unsigned)__builtin_amdgcn_update_dpp((int)v, (int)v, 0x143, 0xC, 0xF, false); v = t < v ? t : v;
  return (unsigned)__builtin_amdgcn_readlane((int)v, 63);
}

// 16-lane all-reduce min (quad xor1, xor2, row_ror4, row_ror8) — R5-R8 validated
__device__ __forceinline__ u32 rmin16u(u32 v) {
  int t;
  t = __builtin_amdgcn_update_dpp((int)v, (int)v, 0xB1,  0xF, 0xF, false); v = ((u32)t < v) ? (u32)t : v;
  t = __builtin_amdgcn_update_dpp((int)v, (int)v, 0x4E,  0xF, 0xF, false); v = ((u32)t < v) ? (u32)t : v;
  t = __builtin_amdgcn_update_dpp((int)v, (int)v, 0x124, 0xF, 0xF, false); v = ((u32)t < v) ? (u32)t : v;
  t = __builtin_amdgcn_update_dpp((int)v, (int)v, 0x128, 0xF, 0xF, false); v = ((u32)t < v) ? (u32)t : v;
  return v;
}

// branchless insert into ascending sorted-8 of u64 keys (bubble, drops max)
__device__ __forceinline__ void ins8u(u64 (&L)[8], u64 v) {
  u64 c = v;
  #pragma unroll
  for (int j = 0; j < 8; ++j) {
    u64 lo = c < L[j] ? c : L[j];
    u64 hi = c < L[j] ? L[j] : c;
    L[j] = lo; c = hi;
  }
}

// async global->LDS, 16B per lane; LDS dest is wave-uniform base + lane*16
__device__ __forceinline__ void gl16(const char* g, char* l) {
  __builtin_amdgcn_global_load_lds(
      (const __attribute__((address_space(1))) unsigned int*)g,
      (__attribute__((address_space(3))) unsigned int*)l, 16, 0, 0);
}
// stage one 64-col tile (hi 8KB + lo 8KB) into a 16KB LDS buffer
__device__ __forceinline__ void stage64(const char* src_hi, char* dst, int tid) {
  const int w = tid >> 6, lane = tid & 63;
  const int off = w * 2048 + (lane << 4);
  gl16(src_hi + off,                 dst + w * 2048);
  gl16(src_hi + off + 1024,          dst + w * 2048 + 1024);
  gl16(src_hi + 16384 + off,         dst + 8192 + w * 2048);
  gl16(src_hi + 16384 + off + 1024,  dst + 8192 + w * 2048 + 1024);
}

// ---------------------------------------------------------------------------
// sq[b][n] = sum_c x[b][c][n]^2   (ascending c — BIT-IDENTICAL to R3-R8).
// Also writes sqp: permuted copy sqp[((b*64+t)*16+s)*4+e] = sq[b][t*64+e*16+s]
// so fused_knn loads one float4 per (lane,tile). Also zeroes cnt.
// ---------------------------------------------------------------------------
__global__ __launch_bounds__(256) void sq_kernel(const float* __restrict__ x,
                                                 float* __restrict__ sq,
                                                 float* __restrict__ sqp,
                                                 int* __restrict__ cnt) {
  if (blockIdx.x == 0 && threadIdx.x == 0) *cnt = 0;
  int g = blockIdx.x * 256 + threadIdx.x;
  int b = g >> 12, n = g & (NPTS - 1);
  const float* xb = x + (size_t)b * CDIM * NPTS + n;
  float s = 0.f;
  #pragma unroll
  for (int c = 0; c < CDIM; ++c) { float v = xb[(size_t)c * NPTS]; s += v * v; }
  sq[g] = s;
  int t = n >> 6, j0 = n & 63;
  int sl = j0 & 15, e = j0 >> 4;
  sqp[(((size_t)b * NT64 + t) * 16 + sl) * 4 + e] = s;
}

// ---------------------------------------------------------------------------
// prep: per-(b,128-tile) fp16 hi/lo images, exact swizzled layout
// byte(n',c) = (n'*128 + 2c) ^ (swz(n')<<4); hi at +0, lo at +16384.
// ---------------------------------------------------------------------------
__global__ __launch_bounds__(256) void prep_kernel(const float* __restrict__ x,
                                                   char* __restrict__ img) {
  __shared__ char limg[32768];
  const int tid = threadIdx.x;
  const int b = blockIdx.x >> 5;
  const int t = blockIdx.x & 31;
  const int np = tid & 127;
  const int half = tid >> 7;
  const float* xb = x + (size_t)b * CDIM * NPTS + t * 128 + np;
  const int sw = swz(np) << 4;
  #pragma unroll
  for (int oct = 0; oct < 4; ++oct) {
    const int cb = half * 32 + oct * 8;
    f16x8 hv, lv;
    #pragma unroll
    for (int j = 0; j < 8; ++j) {
      float v = xb[(size_t)(cb + j) * NPTS];
      f16 h = (f16)v;
      hv[j] = h;
      lv[j] = (f16)(v - (float)h);
    }
    int byt = (np * 128 + cb * 2) ^ sw;
    *(f16x8*)(limg + byt) = hv;
    *(f16x8*)(limg + 16384 + byt) = lv;
  }
  __syncthreads();
  char* dst = img + (size_t)blockIdx.x * 32768;
  #pragma unroll
  for (int i = 0; i < 8; ++i)
    *(float4*)(dst + i * 4096 + tid * 16) = *(const float4*)(limg + i * 4096 + tid * 16);
}

// ---------------------------------------------------------------------------
// Fused dist+top20 (numerics/certificate IDENTICAL to R8). Changes:
//  * __launch_bounds__(256, 2): grid is 2 blocks/CU (grid-limited), so allow
//    ~128 VGPRs — keeps L[] in arch VGPRs instead of AGPR spill moves.
//  * sq per-tile loads from permuted sqp (1 float4/tile vs 4 scalar loads).
//  * flagged rows appended to list[] directly (compact kernel removed).
// ---------------------------------------------------------------------------
__global__ __launch_bounds__(256, 2) void fused_knn(const char* __restrict__ img,
                                                    const float* __restrict__ sq,
                                                    const float* __restrict__ sqp,
                                                    int* __restrict__ knn,
                                                    int* __restrict__ list,
                                                    int* __restrict__ cnt) {
  __shared__ char XB[2][16384];

  const int tid = threadIdx.x;
  const int lane = tid & 63;
  const int w = tid >> 6;
  const int q = lane >> 4;
  const int s = lane & 15;

  const int blk = blockIdx.x;
  const int b  = blk >> 6;
  const int r0 = (blk & 63) * 64;
  const char* imgb = img + (size_t)b * (NT128 * 32768);
  const float* sqb = sq + (size_t)b * NPTS;
  const float4* sqp4 = (const float4*)(sqp + (size_t)b * NT64 * 64);

  stage64(imgb, XB[0], tid);      // tile 0

  // A fragments straight from global img (L2/L3-resident), same byte layout
  f16x8 Ah[2], Al[2];
  {
    const int grow = r0 + w * 16 + s;
    const char* at = imgb + (size_t)(grow >> 7) * 32768;
    const int nn = grow & 127;
    const int swn = swz(nn) << 4;
    #pragma unroll
    for (int ks = 0; ks < 2; ++ks) {
      int byt = (nn * 128 + (ks * 32 + q * 8) * 2) ^ swn;
      Ah[ks] = *(const f16x8*)(at + byt);
      Al[ks] = *(const f16x8*)(at + 16384 + byt);
    }
  }

  float sqr[4];
  #pragma unroll
  for (int reg = 0; reg < 4; ++reg) sqr[reg] = sqb[r0 + w * 16 + q * 4 + reg];

  u32 L[4][8];
  #pragma unroll
  for (int reg = 0; reg < 4; ++reg)
    #pragma unroll
    for (int j = 0; j < 8; ++j) L[reg][j] = SENT32;

  __syncthreads();                 // tile-0 staging drained

  for (int t = 0; t < NT64; ++t) {
    if (t + 1 < NT64)
      stage64(imgb + (size_t)((t + 1) >> 1) * 32768 + (size_t)((t + 1) & 1) * 8192,
              XB[(t + 1) & 1], tid);
    const char* XBc = XB[t & 1];
    const float4 sm4 = sqp4[t * 16 + s];     // sq[t*64 + e*16 + s], e=0..3
    #pragma unroll
    for (int e = 0; e < 4; ++e) {
      const int j = e * 16 + s;
      const int swj = swz(j) << 4;
      f32x4 acc = {0.f, 0.f, 0.f, 0.f};
      #pragma unroll
      for (int ks = 0; ks < 2; ++ks) {
        int byt = (j * 128 + (ks * 32 + q * 8) * 2) ^ swj;
        f16x8 Bh = *(const f16x8*)(XBc + byt);
        f16x8 Bl = *(const f16x8*)(XBc + 8192 + byt);
        acc = __builtin_amdgcn_mfma_f32_16x16x32_f16(Ah[ks], Bh, acc, 0, 0, 0);
        acc = __builtin_amdgcn_mfma_f32_16x16x32_f16(Ah[ks], Bl, acc, 0, 0, 0);
        acc = __builtin_amdgcn_mfma_f32_16x16x32_f16(Al[ks], Bh, acc, 0, 0, 0);
      }
      const float sm = (&sm4.x)[e];
      const u32 klo = (u32)(t * 4 + e);       // = mcol >> 4, wave-uniform
      #pragma unroll
      for (int reg = 0; reg < 4; ++reg) {
        float v = (sqr[reg] + sm) - 2.0f * acc[reg];
        u32 key = (flip_f32(v) & 0xFFFFFF00u) | klo;
        if (__any(key < L[reg][7])) {
          u32 c = key;
          #pragma unroll
          for (int jj = 0; jj < 8; ++jj) {
            u32 lo = c < L[reg][jj] ? c : L[reg][jj];
            u32 hi = c < L[reg][jj] ? L[reg][jj] : c;
            L[reg][jj] = lo; c = hi;
          }
        }
      }
    }
    __syncthreads();   // reads of XB[t&1] done; next-tile staging drained
  }

  // pops: 21 rounds per row (20 results + boundary probe); 4 quarters
  // resolve 4 rows concurrently.
  #pragma unroll
  for (int reg = 0; reg < 4; ++reg) {
    bool flg = false;
    int iA = 0, iB = 0;
    u32 k20 = 0, k21 = 0;
    for (int r = 0; r < KNN + 1; ++r) {
      u32 head = L[reg][0];
      u32 wkey = rmin16u(head);
      unsigned long long bal = __ballot(head == wkey);
      unsigned qm = (unsigned)((bal >> (q * 16)) & 0xFFFFull);
      int swin = __ffs((int)qm) - 1;
      flg = flg || ((qm & (qm - 1u)) != 0u);          // multi-owner key tie
      int idx = (int)(((wkey & 0xFFu) << 4) | (u32)swin);
      if (r < 16) { if (s == r) iA = idx; }
      else if (r < KNN) { if (s == r - 16) iB = idx; }
      if (r == KNN - 1) k20 = wkey;
      if (r == KNN)     k21 = wkey;
      bool own = (head == wkey) && (s == swin);
      #pragma unroll
      for (int jj = 0; jj < 7; ++jj) L[reg][jj] = own ? L[reg][jj + 1] : L[reg][jj];
      L[reg][7] = own ? SENT32 : L[reg][7];
    }
    flg = flg || ((k20 >> 8) == (k21 >> 8));          // boundary prefix tie
    u32 alive = (L[reg][0] == SENT32) ? 0u : 1u;      // drained lane
    flg = flg || (rmin16u(alive) == 0u);
    size_t grow = (size_t)b * NPTS + r0 + w * 16 + q * 4 + reg;
    knn[grow * KNN + s] = iA;
    if (s < 4) knn[grow * KNN + 16 + s] = iB;
    if (s == 0 && flg) { int p = atomicAdd(cnt, 1); list[p] = (int)grow; }
  }
}

// ---------------------------------------------------------------------------
// Exact fp32 brute-force for flagged rows (R7/R8-validated). One BLOCK per
// row, grid-strided over compacted list. (d,m)-lexicographic u64 keys.
// ---------------------------------------------------------------------------
__global__ __launch_bounds__(256) void fallback_knn(const float* __restrict__ x,
                                                    const float* __restrict__ sq,
                                                    const int* __restrict__ cnt,
                                                    const int* __restrict__ list,
                                                    int* __restrict__ knn) {
  __shared__ float xrl[CDIM];
  __shared__ u64 cand[4 * KNN];
  const int tid = threadIdx.x, lane = tid & 63, wv = tid >> 6;
  const int count = *cnt;

  for (int it = blockIdx.x; it < count; it += gridDim.x) {
    const int g = list[it];
    const int b = g >> 12, r = g & (NPTS - 1);
    const float* xb  = x  + (size_t)b * CDIM * NPTS;
    const float* sqb = sq + (size_t)b * NPTS;
    if (tid < CDIM) xrl[tid] = xb[(size_t)tid * NPTS + r];
    __syncthreads();
    const float sqr = sqb[r];

    u64 L[8];
    #pragma unroll
    for (int j = 0; j < 8; ++j) L[j] = SENT;
    #pragma unroll
    for (int ii = 0; ii < 4; ++ii) {
      const int i = wv * 4 + ii;
      float a0 = 0.f, a1 = 0.f, a2 = 0.f, a3 = 0.f;
      const float* xp = xb + i * 256 + lane * 4;
      #pragma unroll
      for (int c4 = 0; c4 < 16; ++c4) {
        float4 xr4 = *(const float4*)&xrl[c4 * 4];
        #pragma unroll
        for (int j = 0; j < 4; ++j) {
          float4 xv = *(const float4*)(xp + (size_t)(c4 * 4 + j) * NPTS);
          float xr = (&xr4.x)[j];
          a0 += xr * xv.x; a1 += xr * xv.y; a2 += xr * xv.z; a3 += xr * xv.w;
        }
      }
      int mb = i * 256 + lane * 4;
      float4 sv = *(const float4*)(sqb + mb);
      ins8u(L, ((u64)flip_f32(sqr + sv.x - 2.0f * a0) << 12) | (unsigned)mb);
      ins8u(L, ((u64)flip_f32(sqr + sv.y - 2.0f * a1) << 12) | (unsigned)(mb + 1));
      ins8u(L, ((u64)flip_f32(sqr + sv.z - 2.0f * a2) << 12) | (unsigned)(mb + 2));
      ins8u(L, ((u64)flip_f32(sqr + sv.w - 2.0f * a3) << 12) | (unsigned)(mb + 3));
    }

    u64 last = 0; bool done = false;
    for (int rr = 0; rr < KNN; ++rr) {
      bool need = (L[0] == SENT) && !done;
      if (__any(need)) {
        if (need) {                                  // never fires in practice
          #pragma unroll
          for (int j = 0; j < 8; ++j) L[j] = SENT;
          for (int ii = 0; ii < 4; ++ii) {
            const int i = wv * 4 + ii;
            float a0 = 0.f, a1 = 0.f, a2 = 0.f, a3 = 0.f;
            const float* xp = xb + i * 256 + lane * 4;
            #pragma unroll
            for (int c4 = 0; c4 < 16; ++c4) {
              float4 xr4 = *(const float4*)&xrl[c4 * 4];
              #pragma unroll
              for (int j = 0; j < 4; ++j) {
                float4 xv = *(const float4*)(xp + (size_t)(c4 * 4 + j) * NPTS);
                float xr = (&xr4.x)[j];
                a0 += xr * xv.x; a1 += xr * xv.y; a2 += xr * xv.z; a3 += xr * xv.w;
              }
            }
            int mb = i * 256 + lane * 4;
            float4 sv = *(const float4*)(sqb + mb);
            u64 v;
            v = ((u64)flip_f32(sqr + sv.x - 2.0f * a0) << 12) | (unsigned)mb;       ins8u(L, v > last ? v : SENT);
            v = ((u64)flip_f32(sqr + sv.y - 2.0f * a1) << 12) | (unsigned)(mb + 1); ins8u(L, v > last ? v : SENT);
            v = ((u64)flip_f32(sqr + sv.z - 2.0f * a2) << 12) | (unsigned)(mb + 2); ins8u(L, v > last ? v : SENT);
            v = ((u64)flip_f32(sqr + sv.w - 2.0f * a3) << 12) | (unsigned)(mb + 3); ins8u(L, v > last ? v : SENT);
          }
          if (L[0] == SENT) done = true;
        }
      }
      unsigned keyH = (unsigned)(L[0] >> 12);
      unsigned wkey = wave_min_u32(keyH);
      unsigned mc   = (keyH == wkey) ? (unsigned)(L[0] & 0xFFF) : 0xFFFFFFFFu;
      unsigned wm   = wave_min_u32(mc);
      u64 wsel = ((u64)wkey << 12) | wm;
      if (lane == rr) cand[wv * KNN + rr] = wsel;
      bool win = (L[0] == wsel);
      #pragma unroll
      for (int j = 0; j < 7; ++j) L[j] = win ? L[j + 1] : L[j];
      L[7] = win ? SENT : L[7];
      last = wsel;
    }
    __syncthreads();

    if (wv == 0) {                       // merge 80 candidates -> top 20
      u64 c0 = cand[lane < 4 * KNN ? lane : 0];
      if (lane >= 4 * KNN) c0 = SENT;
      u64 c1 = (lane < 4 * KNN - 64) ? cand[64 + lane] : SENT;
      int myidx = 0;
      for (int rr = 0; rr < KNN; ++rr) {
        u64 mn = c0 < c1 ? c0 : c1;
        unsigned keyH = (unsigned)(mn >> 12);
        unsigned wkey = wave_min_u32(keyH);
        unsigned mc   = (keyH == wkey) ? (unsigned)(mn & 0xFFF) : 0xFFFFFFFFu;
        unsigned wm   = wave_min_u32(mc);
        u64 wsel = ((u64)wkey << 12) | wm;
        if (lane == rr) myidx = (int)wm;
        if (c0 == wsel)      { c0 = c1; c1 = SENT; }
        else if (c1 == wsel) { c1 = SENT; }
      }
      if (lane < KNN) knn[(size_t)g * KNN + lane] = myidx;
    }
    __syncthreads();
  }
}

// ---------------------------------------------------------------------------
// a[b][n][o]  = sum_c (W[o][c]-W[o][c+64]) * x[b][c][n]
// cc[b][n][o] = sum_c  W[o][c+64]          * x[b][c][n]
// ---------------------------------------------------------------------------
__global__ __launch_bounds__(256) void proj_kernel(const float* __restrict__ x,
                                                   const float* __restrict__ w,
                                                   float* __restrict__ a,
                                                   float* __restrict__ cc) {
  __shared__ float wa[CDIM][ODIM];
  __shared__ float wc[CDIM][ODIM];
  const int tid = threadIdx.x;
  #pragma unroll
  for (int p = 0; p < 16; ++p) {
    int idx = p * 256 + tid;
    int o = idx & 63, c = idx >> 6;
    float w1 = w[o * 128 + c], w2 = w[o * 128 + 64 + c];
    wa[c][o] = w1 - w2;
    wc[c][o] = w2;
  }
  __syncthreads();

  const int og = tid >> 6;
  const int nl = tid & 63;
  const int g0 = blockIdx.x * 128;
  const int b  = g0 >> 12;
  const int n0 = g0 & (NPTS - 1);
  const float* xB = x + (size_t)b * CDIM * NPTS;

  float aa0[16], ac0[16], aa1[16], ac1[16];
  #pragma unroll
  for (int qq = 0; qq < 16; ++qq) { aa0[qq] = ac0[qq] = aa1[qq] = ac1[qq] = 0.f; }

  #pragma unroll 4
  for (int c = 0; c < CDIM; ++c) {
    float xv0 = xB[(size_t)c * NPTS + n0 + nl];
    float xv1 = xB[(size_t)c * NPTS + n0 + 64 + nl];
    #pragma unroll
    for (int q4 = 0; q4 < 4; ++q4) {
      float4 va = *(const float4*)&wa[c][og * 16 + q4 * 4];
      float4 vc = *(const float4*)&wc[c][og * 16 + q4 * 4];
      aa0[q4*4+0] += va.x * xv0; aa0[q4*4+1] += va.y * xv0;
      aa0[q4*4+2] += va.z * xv0; aa0[q4*4+3] += va.w * xv0;
      ac0[q4*4+0] += vc.x * xv0; ac0[q4*4+1] += vc.y * xv0;
      ac0[q4*4+2] += vc.z * xv0; ac0[q4*4+3] += vc.w * xv0;
      aa1[q4*4+0] += va.x * xv1; aa1[q4*4+1] += va.y * xv1;
      aa1[q4*4+2] += va.z * xv1; aa1[q4*4+3] += va.w * xv1;
      ac1[q4*4+0] += vc.x * xv1; ac1[q4*4+1] += vc.y * xv1;
      ac1[q4*4+2] += vc.z * xv1; ac1[q4*4+3] += vc.w * xv1;
    }
  }
  size_t ga0 = (size_t)(g0 + nl) * ODIM + og * 16;
  size_t ga1 = (size_t)(g0 + 64 + nl) * ODIM + og * 16;
  #pragma unroll
  for (int q4 = 0; q4 < 4; ++q4) {
    *(float4*)&a [ga0 + q4 * 4] = *(float4*)&aa0[q4 * 4];
    *(float4*)&cc[ga0 + q4 * 4] = *(float4*)&ac0[q4 * 4];
    *(float4*)&a [ga1 + q4 * 4] = *(float4*)&aa1[q4 * 4];
    *(float4*)&cc[ga1 + q4 * 4] = *(float4*)&ac1[q4 * 4];
  }
}

// ---------------------------------------------------------------------------
// out[b][o][n] = relu(inv[o] * max_k(a[b][n][o] + cc[b][knn[n][k]][o]) + bias[o])
// ---------------------------------------------------------------------------
__global__ __launch_bounds__(256) void out_kernel(const float* __restrict__ a,
                                                  const float* __restrict__ cc,
                                                  const int* __restrict__ knn,
                                                  const float* __restrict__ gamma,
                                                  const float* __restrict__ beta,
                                                  const float* __restrict__ mean,
                                                  const float* __restrict__ var,
                                                  float* __restrict__ out) {
  __shared__ float tile[64][65];
  const int tid = threadIdx.x, lane = tid & 63, wv = tid >> 6;
  const int b = blockIdx.y;
  const int n0 = blockIdx.x * 64;
  float inv  = gamma[lane] / sqrtf(var[lane] + 1e-5f);
  float bias = beta[lane] - mean[lane] * inv;
  for (int t = 0; t < 16; ++t) {
    int nl = wv * 16 + t;
    size_t base = (size_t)b * NPTS + (n0 + nl);
    float av = a[base * ODIM + lane];
    const int* kr = knn + base * KNN;
    float m = -INFINITY;
    #pragma unroll
    for (int k = 0; k < KNN; ++k) {
      int j = kr[k];
      float cv = cc[((size_t)b * NPTS + j) * ODIM + lane];
      m = fmaxf(m, av + cv);
    }
    float v = m * inv + bias;
    tile[nl][lane] = v > 0.f ? v : 0.f;
  }
  __syncthreads();
  for (int t = 0; t < 16; ++t) {
    int o = wv * 16 + t;
    out[((size_t)b * ODIM + o) * NPTS + n0 + lane] = tile[lane][o];
  }
}

// ---------------------------------------------------------------------------
extern "C" void kernel_launch(void* const* d_in, const int* in_sizes, int n_in,
                              void* d_out, int out_size, void* d_ws, size_t ws_size,
                              hipStream_t stream) {
  const float* x     = (const float*)d_in[0];
  const float* w     = (const float*)d_in[1];
  const float* gamma = (const float*)d_in[2];
  const float* beta  = (const float*)d_in[3];
  const float* mean  = (const float*)d_in[4];
  const float* var   = (const float*)d_in[5];
  float* out = (float*)d_out;

  char* wsb = (char*)d_ws;
  size_t off = 0;
  int*   knn   = (int*)(wsb + off);   off += (size_t)BDIM * NPTS * KNN * 4;   // 2.62 MB
  int*   list  = (int*)(wsb + off);   off += (size_t)BDIM * NPTS * 4;         // 0.13 MB
  int*   cnt   = (int*)(wsb + off);   off += 256;
  float* sqw   = (float*)(wsb + off); off += (size_t)BDIM * NPTS * 4;         // 0.13 MB
  float* sqp   = (float*)(wsb + off); off += (size_t)BDIM * NPTS * 4;         // 0.13 MB
  float* a     = (float*)(wsb + off); off += (size_t)BDIM * NPTS * ODIM * 4;  // 8 MB
  float* cc    = (float*)(wsb + off); off += (size_t)BDIM * NPTS * ODIM * 4;  // 8 MB
  char*  img   = wsb + off;           off += (size_t)BDIM * NT128 * 32768;    // 8 MB
  (void)ws_size;

  prep_kernel <<<BDIM * NT128, 256, 0, stream>>>(x, img);
  sq_kernel   <<<BDIM * NPTS / 256, 256, 0, stream>>>(x, sqw, sqp, cnt);
  proj_kernel <<<BDIM * NPTS / 128, 256, 0, stream>>>(x, w, a, cc);
  fused_knn   <<<512, 256, 0, stream>>>(img, sqw, sqp, knn, list, cnt);
  fallback_knn<<<2048, 256, 0, stream>>>(x, sqw, cnt, list, knn);
  out_kernel  <<<dim3(NPTS / 64, BDIM), 256, 0, stream>>>(a, cc, knn, gamma, beta,
                                                          mean, var, out);
}

// Round 10
// 301.580 us; speedup vs baseline: 4.3823x; 1.0791x over previous
//
#include <hip/hip_runtime.h>
#include <cstdint>
#include <cstddef>

#define NPTS 4096
#define CDIM 64
#define BDIM 8
#define KNN  20
#define ODIM 64
#define NT128 32          // 128-col tile images per batch (prep layout)
#define NT64  64          // 64-col compute tiles per batch (fused)

typedef unsigned long long u64;
typedef unsigned int u32;
typedef _Float16 f16;
using f16x8 = __attribute__((ext_vector_type(8))) _Float16;
using f32x4 = __attribute__((ext_vector_type(4))) float;
#define SENT   (~0ull)
#define FINF (__builtin_inff())

__device__ __forceinline__ int swz(int r) { return (r & 7) ^ ((r >> 3) & 7); }

// order-preserving float->u32 flip (ascending float == ascending u32)
__device__ __forceinline__ unsigned flip_f32(float d) {
  unsigned bits = __float_as_uint(d);
  return bits ^ (unsigned)(((int)bits >> 31) | 0x80000000u);
}

// wave64 all-reduce min (DPP), uniform via readlane 63  (R3-validated)
__device__ __forceinline__ unsigned wave_min_u32(unsigned v) {
  unsigned t;
  t = (unsigned)__builtin_amdgcn_update_dpp((int)v, (int)v, 0x111, 0xF, 0xF, false); v = t < v ? t : v;
  t = (unsigned)__builtin_amdgcn_update_dpp((int)v, (int)v, 0x112, 0xF, 0xF, false); v = t < v ? t : v;
  t = (unsigned)__builtin_amdgcn_update_dpp((int)v, (int)v, 0x114, 0xF, 0xF, false); v = t < v ? t : v;
  t = (unsigned)__builtin_amdgcn_update_dpp((int)v, (int)v, 0x118, 0xF, 0xF, false); v = t < v ? t : v;
  t = (unsigned)__builtin_amdgcn_update_dpp((int)v, (int)v, 0x142, 0xA, 0xF, false); v = t < v ? t : v;
  t = (unsigned)__builtin_amdgcn_update_dpp((int)v, (int)v, 0x143, 0xC, 0xF, false); v = t < v ? t : v;
  return (unsigned)__builtin_amdgcn_readlane((int)v, 63);
}

// 16-lane all-reduce min, float (quad xor1, xor2, row_ror4, row_ror8)
__device__ __forceinline__ float rmin16f(float v) {
  int t;
  t = __builtin_amdgcn_update_dpp(__float_as_int(v), __float_as_int(v), 0xB1,  0xF, 0xF, false);
  v = fminf(v, __int_as_float(t));
  t = __builtin_amdgcn_update_dpp(__float_as_int(v), __float_as_int(v), 0x4E,  0xF, 0xF, false);
  v = fminf(v, __int_as_float(t));
  t = __builtin_amdgcn_update_dpp(__float_as_int(v), __float_as_int(v), 0x124, 0xF, 0xF, false);
  v = fminf(v, __int_as_float(t));
  t = __builtin_amdgcn_update_dpp(__float_as_int(v), __float_as_int(v), 0x128, 0xF, 0xF, false);
  v = fminf(v, __int_as_float(t));
  return v;
}
__device__ __forceinline__ u32 rmin16u(u32 v) {
  int t;
  t = __builtin_amdgcn_update_dpp((int)v, (int)v, 0xB1,  0xF, 0xF, false); v = ((u32)t < v) ? (u32)t : v;
  t = __builtin_amdgcn_update_dpp((int)v, (int)v, 0x4E,  0xF, 0xF, false); v = ((u32)t < v) ? (u32)t : v;
  t = __builtin_amdgcn_update_dpp((int)v, (int)v, 0x124, 0xF, 0xF, false); v = ((u32)t < v) ? (u32)t : v;
  t = __builtin_amdgcn_update_dpp((int)v, (int)v, 0x128, 0xF, 0xF, false); v = ((u32)t < v) ? (u32)t : v;
  return v;
}

// branchless insert into ascending sorted-8 of u64 keys (bubble, drops max)
__device__ __forceinline__ void ins8u(u64 (&L)[8], u64 v) {
  u64 c = v;
  #pragma unroll
  for (int j = 0; j < 8; ++j) {
    u64 lo = c < L[j] ? c : L[j];
    u64 hi = c < L[j] ? L[j] : c;
    L[j] = lo; c = hi;
  }
}

// async global->LDS, 16B per lane; LDS dest is wave-uniform base + lane*16
__device__ __forceinline__ void gl16(const char* g, char* l) {
  __builtin_amdgcn_global_load_lds(
      (const __attribute__((address_space(1))) unsigned int*)g,
      (__attribute__((address_space(3))) unsigned int*)l, 16, 0, 0);
}
// stage one 64-col tile (hi 8KB + lo 8KB) into a 16KB LDS buffer
__device__ __forceinline__ void stage64(const char* src_hi, char* dst, int tid) {
  const int w = tid >> 6, lane = tid & 63;
  const int off = w * 2048 + (lane << 4);
  gl16(src_hi + off,                 dst + w * 2048);
  gl16(src_hi + off + 1024,          dst + w * 2048 + 1024);
  gl16(src_hi + 16384 + off,         dst + 8192 + w * 2048);
  gl16(src_hi + 16384 + off + 1024,  dst + 8192 + w * 2048 + 1024);
}

// ---------------------------------------------------------------------------
// sq[b][n] = sum_c x[b][c][n]^2   (ascending c — BIT-IDENTICAL to R3-R9).
// Also writes permuted sqp; zeroes cnt.
// ---------------------------------------------------------------------------
__global__ __launch_bounds__(256) void sq_kernel(const float* __restrict__ x,
                                                 float* __restrict__ sq,
                                                 float* __restrict__ sqp,
                                                 int* __restrict__ cnt) {
  if (blockIdx.x == 0 && threadIdx.x == 0) *cnt = 0;
  int g = blockIdx.x * 256 + threadIdx.x;
  int b = g >> 12, n = g & (NPTS - 1);
  const float* xb = x + (size_t)b * CDIM * NPTS + n;
  float s = 0.f;
  #pragma unroll
  for (int c = 0; c < CDIM; ++c) { float v = xb[(size_t)c * NPTS]; s += v * v; }
  sq[g] = s;
  int t = n >> 6, j0 = n & 63;
  int sl = j0 & 15, e = j0 >> 4;
  sqp[(((size_t)b * NT64 + t) * 16 + sl) * 4 + e] = s;
}

// ---------------------------------------------------------------------------
// prep: per-(b,128-tile) fp16 hi/lo images, exact swizzled layout
// byte(n',c) = (n'*128 + 2c) ^ (swz(n')<<4); hi at +0, lo at +16384.
// ---------------------------------------------------------------------------
__global__ __launch_bounds__(256) void prep_kernel(const float* __restrict__ x,
                                                   char* __restrict__ img) {
  __shared__ char limg[32768];
  const int tid = threadIdx.x;
  const int b = blockIdx.x >> 5;
  const int t = blockIdx.x & 31;
  const int np = tid & 127;
  const int half = tid >> 7;
  const float* xb = x + (size_t)b * CDIM * NPTS + t * 128 + np;
  const int sw = swz(np) << 4;
  #pragma unroll
  for (int oct = 0; oct < 4; ++oct) {
    const int cb = half * 32 + oct * 8;
    f16x8 hv, lv;
    #pragma unroll
    for (int j = 0; j < 8; ++j) {
      float v = xb[(size_t)(cb + j) * NPTS];
      f16 h = (f16)v;
      hv[j] = h;
      lv[j] = (f16)(v - (float)h);
    }
    int byt = (np * 128 + cb * 2) ^ sw;
    *(f16x8*)(limg + byt) = hv;
    *(f16x8*)(limg + 16384 + byt) = lv;
  }
  __syncthreads();
  char* dst = img + (size_t)blockIdx.x * 32768;
  #pragma unroll
  for (int i = 0; i < 8; ++i)
    *(float4*)(dst + i * 4096 + tid * 16) = *(const float4*)(limg + i * 4096 + tid * 16);
}

// ---------------------------------------------------------------------------
// Fused dist+top20. Dist numerics (MFMA fp16x3 hh,hl,lh; ks ascending) are
// BIT-IDENTICAL to R4-R9. Selection now in FLOAT domain:
//   key = as_float((bits(d) & 0xFFFFFF00) | klo), klo = mcol>>4 (8 bits).
// Set-selection only (downstream is a max over the neighbor set), so pop
// order is irrelevant; any boundary/tie ambiguity is flagged -> exact
// fallback. asm "+v" pins L[] and acc in arch VGPRs (defeats AGPR offload
// moves — R9's VGPR_Count=44 despite ~90 live values).
// ---------------------------------------------------------------------------
__global__ __launch_bounds__(256, 2) void fused_knn(const char* __restrict__ img,
                                                    const float* __restrict__ sq,
                                                    const float* __restrict__ sqp,
                                                    int* __restrict__ knn,
                                                    int* __restrict__ list,
                                                    int* __restrict__ cnt) {
  __shared__ char XB[2][16384];

  const int tid = threadIdx.x;
  const int lane = tid & 63;
  const int w = tid >> 6;
  const int q = lane >> 4;
  const int s = lane & 15;

  const int blk = blockIdx.x;
  const int b  = blk >> 6;
  const int r0 = (blk & 63) * 64;
  const char* imgb = img + (size_t)b * (NT128 * 32768);
  const float* sqb = sq + (size_t)b * NPTS;
  const float4* sqp4 = (const float4*)(sqp + (size_t)b * NT64 * 64);

  stage64(imgb, XB[0], tid);      // tile 0

  // A fragments straight from global img (L2/L3-resident), same byte layout
  f16x8 Ah[2], Al[2];
  {
    const int grow = r0 + w * 16 + s;
    const char* at = imgb + (size_t)(grow >> 7) * 32768;
    const int nn = grow & 127;
    const int swn = swz(nn) << 4;
    #pragma unroll
    for (int ks = 0; ks < 2; ++ks) {
      int byt = (nn * 128 + (ks * 32 + q * 8) * 2) ^ swn;
      Ah[ks] = *(const f16x8*)(at + byt);
      Al[ks] = *(const f16x8*)(at + 16384 + byt);
    }
  }

  float sqr[4];
  #pragma unroll
  for (int reg = 0; reg < 4; ++reg) sqr[reg] = sqb[r0 + w * 16 + q * 4 + reg];

  float L[4][8];
  #pragma unroll
  for (int reg = 0; reg < 4; ++reg)
    #pragma unroll
    for (int j = 0; j < 8; ++j) L[reg][j] = FINF;

  __syncthreads();                 // tile-0 staging drained

  for (int t = 0; t < NT64; ++t) {
    // pin the top-8 lists into arch VGPRs (no-op if honored)
    #pragma unroll
    for (int reg = 0; reg < 4; ++reg)
      #pragma unroll
      for (int jj = 0; jj < 8; ++jj)
        asm volatile("" : "+v"(L[reg][jj]));

    if (t + 1 < NT64)
      stage64(imgb + (size_t)((t + 1) >> 1) * 32768 + (size_t)((t + 1) & 1) * 8192,
              XB[(t + 1) & 1], tid);
    const char* XBc = XB[t & 1];
    const float4 sm4 = sqp4[t * 16 + s];     // sq[t*64 + e*16 + s], e=0..3
    #pragma unroll
    for (int e = 0; e < 4; ++e) {
      const int j = e * 16 + s;
      const int swj = swz(j) << 4;
      f32x4 acc = {0.f, 0.f, 0.f, 0.f};
      #pragma unroll
      for (int ks = 0; ks < 2; ++ks) {
        int byt = (j * 128 + (ks * 32 + q * 8) * 2) ^ swj;
        f16x8 Bh = *(const f16x8*)(XBc + byt);
        f16x8 Bl = *(const f16x8*)(XBc + 8192 + byt);
        acc = __builtin_amdgcn_mfma_f32_16x16x32_f16(Ah[ks], Bh, acc, 0, 0, 0);
        acc = __builtin_amdgcn_mfma_f32_16x16x32_f16(Ah[ks], Bl, acc, 0, 0, 0);
        acc = __builtin_amdgcn_mfma_f32_16x16x32_f16(Al[ks], Bh, acc, 0, 0, 0);
      }
      asm volatile("" : "+v"(acc));          // acc reads happen from VGPRs
      const float sm = (&sm4.x)[e];
      const u32 klo = (u32)(t * 4 + e);      // = mcol >> 4, wave-uniform
      #pragma unroll
      for (int reg = 0; reg < 4; ++reg) {
        float v = (sqr[reg] + sm) - 2.0f * acc[reg];   // same expr as R4-R9
        float key = __uint_as_float((__float_as_uint(v) & 0xFFFFFF00u) | klo);
        float c = key;
        #pragma unroll
        for (int jj = 0; jj < 8; ++jj) {
          float lo = fminf(c, L[reg][jj]);
          float hi = fmaxf(c, L[reg][jj]);
          L[reg][jj] = lo; c = hi;
        }
      }
    }
    __syncthreads();   // reads of XB[t&1] done; next-tile staging drained
  }

  // pops: 21 rounds per row (20 results + boundary probe); 4 quarters
  // resolve 4 rows concurrently. Float-domain min; bit-prefix certificates.
  #pragma unroll
  for (int reg = 0; reg < 4; ++reg) {
    bool flg = false;
    int iA = 0, iB = 0;
    u32 k20 = 0, k21 = 0;
    for (int r = 0; r < KNN + 1; ++r) {
      float head = L[reg][0];
      float wkey = rmin16f(head);
      unsigned long long bal = __ballot(head == wkey);
      unsigned qm = (unsigned)((bal >> (q * 16)) & 0xFFFFull);
      int swin = __ffs((int)qm) - 1;
      flg = flg || ((qm & (qm - 1u)) != 0u);          // multi-owner tie
      u32 kb = __float_as_uint(wkey);
      int idx = (int)(((kb & 0xFFu) << 4) | (u32)swin);
      if (r < 16) { if (s == r) iA = idx; }
      else if (r < KNN) { if (s == r - 16) iB = idx; }
      if (r == KNN - 1) k20 = kb;
      if (r == KNN)     k21 = kb;
      bool own = (head == wkey) && (s == swin);
      #pragma unroll
      for (int jj = 0; jj < 7; ++jj) L[reg][jj] = own ? L[reg][jj + 1] : L[reg][jj];
      L[reg][7] = own ? FINF : L[reg][7];
    }
    flg = flg || ((k20 >> 8) == (k21 >> 8));          // boundary prefix tie
    u32 alive = (__float_as_uint(L[reg][0]) == __float_as_uint(FINF)) ? 0u : 1u;
    flg = flg || (rmin16u(alive) == 0u);              // drained lane
    size_t grow = (size_t)b * NPTS + r0 + w * 16 + q * 4 + reg;
    knn[grow * KNN + s] = iA;
    if (s < 4) knn[grow * KNN + 16 + s] = iB;
    if (s == 0 && flg) { int p = atomicAdd(cnt, 1); list[p] = (int)grow; }
  }
}

// ---------------------------------------------------------------------------
// Exact fp32 brute-force for flagged rows (R7-R9-validated, unchanged).
// ---------------------------------------------------------------------------
__global__ __launch_bounds__(256) void fallback_knn(const float* __restrict__ x,
                                                    const float* __restrict__ sq,
                                                    const int* __restrict__ cnt,
                                                    const int* __restrict__ list,
                                                    int* __restrict__ knn) {
  __shared__ float xrl[CDIM];
  __shared__ u64 cand[4 * KNN];
  const int tid = threadIdx.x, lane = tid & 63, wv = tid >> 6;
  const int count = *cnt;

  for (int it = blockIdx.x; it < count; it += gridDim.x) {
    const int g = list[it];
    const int b = g >> 12, r = g & (NPTS - 1);
    const float* xb  = x  + (size_t)b * CDIM * NPTS;
    const float* sqb = sq + (size_t)b * NPTS;
    if (tid < CDIM) xrl[tid] = xb[(size_t)tid * NPTS + r];
    __syncthreads();
    const float sqr = sqb[r];

    u64 L[8];
    #pragma unroll
    for (int j = 0; j < 8; ++j) L[j] = SENT;
    #pragma unroll
    for (int ii = 0; ii < 4; ++ii) {
      const int i = wv * 4 + ii;
      float a0 = 0.f, a1 = 0.f, a2 = 0.f, a3 = 0.f;
      const float* xp = xb + i * 256 + lane * 4;
      #pragma unroll
      for (int c4 = 0; c4 < 16; ++c4) {
        float4 xr4 = *(const float4*)&xrl[c4 * 4];
        #pragma unroll
        for (int j = 0; j < 4; ++j) {
          float4 xv = *(const float4*)(xp + (size_t)(c4 * 4 + j) * NPTS);
          float xr = (&xr4.x)[j];
          a0 += xr * xv.x; a1 += xr * xv.y; a2 += xr * xv.z; a3 += xr * xv.w;
        }
      }
      int mb = i * 256 + lane * 4;
      float4 sv = *(const float4*)(sqb + mb);
      ins8u(L, ((u64)flip_f32(sqr + sv.x - 2.0f * a0) << 12) | (unsigned)mb);
      ins8u(L, ((u64)flip_f32(sqr + sv.y - 2.0f * a1) << 12) | (unsigned)(mb + 1));
      ins8u(L, ((u64)flip_f32(sqr + sv.z - 2.0f * a2) << 12) | (unsigned)(mb + 2));
      ins8u(L, ((u64)flip_f32(sqr + sv.w - 2.0f * a3) << 12) | (unsigned)(mb + 3));
    }

    u64 last = 0; bool done = false;
    for (int rr = 0; rr < KNN; ++rr) {
      bool need = (L[0] == SENT) && !done;
      if (__any(need)) {
        if (need) {                                  // never fires in practice
          #pragma unroll
          for (int j = 0; j < 8; ++j) L[j] = SENT;
          for (int ii = 0; ii < 4; ++ii) {
            const int i = wv * 4 + ii;
            float a0 = 0.f, a1 = 0.f, a2 = 0.f, a3 = 0.f;
            const float* xp = xb + i * 256 + lane * 4;
            #pragma unroll
            for (int c4 = 0; c4 < 16; ++c4) {
              float4 xr4 = *(const float4*)&xrl[c4 * 4];
              #pragma unroll
              for (int j = 0; j < 4; ++j) {
                float4 xv = *(const float4*)(xp + (size_t)(c4 * 4 + j) * NPTS);
                float xr = (&xr4.x)[j];
                a0 += xr * xv.x; a1 += xr * xv.y; a2 += xr * xv.z; a3 += xr * xv.w;
              }
            }
            int mb = i * 256 + lane * 4;
            float4 sv = *(const float4*)(sqb + mb);
            u64 v;
            v = ((u64)flip_f32(sqr + sv.x - 2.0f * a0) << 12) | (unsigned)mb;       ins8u(L, v > last ? v : SENT);
            v = ((u64)flip_f32(sqr + sv.y - 2.0f * a1) << 12) | (unsigned)(mb + 1); ins8u(L, v > last ? v : SENT);
            v = ((u64)flip_f32(sqr + sv.z - 2.0f * a2) << 12) | (unsigned)(mb + 2); ins8u(L, v > last ? v : SENT);
            v = ((u64)flip_f32(sqr + sv.w - 2.0f * a3) << 12) | (unsigned)(mb + 3); ins8u(L, v > last ? v : SENT);
          }
          if (L[0] == SENT) done = true;
        }
      }
      unsigned keyH = (unsigned)(L[0] >> 12);
      unsigned wkey = wave_min_u32(keyH);
      unsigned mc   = (keyH == wkey) ? (unsigned)(L[0] & 0xFFF) : 0xFFFFFFFFu;
      unsigned wm   = wave_min_u32(mc);
      u64 wsel = ((u64)wkey << 12) | wm;
      if (lane == rr) cand[wv * KNN + rr] = wsel;
      bool win = (L[0] == wsel);
      #pragma unroll
      for (int j = 0; j < 7; ++j) L[j] = win ? L[j + 1] : L[j];
      L[7] = win ? SENT : L[7];
      last = wsel;
    }
    __syncthreads();

    if (wv == 0) {                       // merge 80 candidates -> top 20
      u64 c0 = cand[lane < 4 * KNN ? lane : 0];
      if (lane >= 4 * KNN) c0 = SENT;
      u64 c1 = (lane < 4 * KNN - 64) ? cand[64 + lane] : SENT;
      int myidx = 0;
      for (int rr = 0; rr < KNN; ++rr) {
        u64 mn = c0 < c1 ? c0 : c1;
        unsigned keyH = (unsigned)(mn >> 12);
        unsigned wkey = wave_min_u32(keyH);
        unsigned mc   = (keyH == wkey) ? (unsigned)(mn & 0xFFF) : 0xFFFFFFFFu;
        unsigned wm   = wave_min_u32(mc);
        u64 wsel = ((u64)wkey << 12) | wm;
        if (lane == rr) myidx = (int)wm;
        if (c0 == wsel)      { c0 = c1; c1 = SENT; }
        else if (c1 == wsel) { c1 = SENT; }
      }
      if (lane < KNN) knn[(size_t)g * KNN + lane] = myidx;
    }
    __syncthreads();
  }
}

// ---------------------------------------------------------------------------
// a[b][n][o]  = sum_c (W[o][c]-W[o][c+64]) * x[b][c][n]
// cc[b][n][o] = sum_c  W[o][c+64]          * x[b][c][n]
// ---------------------------------------------------------------------------
__global__ __launch_bounds__(256) void proj_kernel(const float* __restrict__ x,
                                                   const float* __restrict__ w,
                                                   float* __restrict__ a,
                                                   float* __restrict__ cc) {
  __shared__ float wa[CDIM][ODIM];
  __shared__ float wc[CDIM][ODIM];
  const int tid = threadIdx.x;
  #pragma unroll
  for (int p = 0; p < 16; ++p) {
    int idx = p * 256 + tid;
    int o = idx & 63, c = idx >> 6;
    float w1 = w[o * 128 + c], w2 = w[o * 128 + 64 + c];
    wa[c][o] = w1 - w2;
    wc[c][o] = w2;
  }
  __syncthreads();

  const int og = tid >> 6;
  const int nl = tid & 63;
  const int g0 = blockIdx.x * 128;
  const int b  = g0 >> 12;
  const int n0 = g0 & (NPTS - 1);
  const float* xB = x + (size_t)b * CDIM * NPTS;

  float aa0[16], ac0[16], aa1[16], ac1[16];
  #pragma unroll
  for (int qq = 0; qq < 16; ++qq) { aa0[qq] = ac0[qq] = aa1[qq] = ac1[qq] = 0.f; }

  #pragma unroll 4
  for (int c = 0; c < CDIM; ++c) {
    float xv0 = xB[(size_t)c * NPTS + n0 + nl];
    float xv1 = xB[(size_t)c * NPTS + n0 + 64 + nl];
    #pragma unroll
    for (int q4 = 0; q4 < 4; ++q4) {
      float4 va = *(const float4*)&wa[c][og * 16 + q4 * 4];
      float4 vc = *(const float4*)&wc[c][og * 16 + q4 * 4];
      aa0[q4*4+0] += va.x * xv0; aa0[q4*4+1] += va.y * xv0;
      aa0[q4*4+2] += va.z * xv0; aa0[q4*4+3] += va.w * xv0;
      ac0[q4*4+0] += vc.x * xv0; ac0[q4*4+1] += vc.y * xv0;
      ac0[q4*4+2] += vc.z * xv0; ac0[q4*4+3] += vc.w * xv0;
      aa1[q4*4+0] += va.x * xv1; aa1[q4*4+1] += va.y * xv1;
      aa1[q4*4+2] += va.z * xv1; aa1[q4*4+3] += va.w * xv1;
      ac1[q4*4+0] += vc.x * xv1; ac1[q4*4+1] += vc.y * xv1;
      ac1[q4*4+2] += vc.z * xv1; ac1[q4*4+3] += vc.w * xv1;
    }
  }
  size_t ga0 = (size_t)(g0 + nl) * ODIM + og * 16;
  size_t ga1 = (size_t)(g0 + 64 + nl) * ODIM + og * 16;
  #pragma unroll
  for (int q4 = 0; q4 < 4; ++q4) {
    *(float4*)&a [ga0 + q4 * 4] = *(float4*)&aa0[q4 * 4];
    *(float4*)&cc[ga0 + q4 * 4] = *(float4*)&ac0[q4 * 4];
    *(float4*)&a [ga1 + q4 * 4] = *(float4*)&aa1[q4 * 4];
    *(float4*)&cc[ga1 + q4 * 4] = *(float4*)&ac1[q4 * 4];
  }
}

// ---------------------------------------------------------------------------
// out[b][o][n] = relu(inv[o] * max_k(a[b][n][o] + cc[b][knn[n][k]][o]) + bias[o])
// ---------------------------------------------------------------------------
__global__ __launch_bounds__(256) void out_kernel(const float* __restrict__ a,
                                                  const float* __restrict__ cc,
                                                  const int* __restrict__ knn,
                                                  const float* __restrict__ gamma,
                                                  const float* __restrict__ beta,
                                                  const float* __restrict__ mean,
                                                  const float* __restrict__ var,
                                                  float* __restrict__ out) {
  __shared__ float tile[64][65];
  const int tid = threadIdx.x, lane = tid & 63, wv = tid >> 6;
  const int b = blockIdx.y;
  const int n0 = blockIdx.x * 64;
  float inv  = gamma[lane] / sqrtf(var[lane] + 1e-5f);
  float bias = beta[lane] - mean[lane] * inv;
  for (int t = 0; t < 16; ++t) {
    int nl = wv * 16 + t;
    size_t base = (size_t)b * NPTS + (n0 + nl);
    float av = a[base * ODIM + lane];
    const int* kr = knn + base * KNN;
    float m = -INFINITY;
    #pragma unroll
    for (int k = 0; k < KNN; ++k) {
      int j = kr[k];
      float cv = cc[((size_t)b * NPTS + j) * ODIM + lane];
      m = fmaxf(m, av + cv);
    }
    float v = m * inv + bias;
    tile[nl][lane] = v > 0.f ? v : 0.f;
  }
  __syncthreads();
  for (int t = 0; t < 16; ++t) {
    int o = wv * 16 + t;
    out[((size_t)b * ODIM + o) * NPTS + n0 + lane] = tile[lane][o];
  }
}

// ---------------------------------------------------------------------------
extern "C" void kernel_launch(void* const* d_in, const int* in_sizes, int n_in,
                              void* d_out, int out_size, void* d_ws, size_t ws_size,
                              hipStream_t stream) {
  const float* x     = (const float*)d_in[0];
  const float* w     = (const float*)d_in[1];
  const float* gamma = (const float*)d_in[2];
  const float* beta  = (const float*)d_in[3];
  const float* mean  = (const float*)d_in[4];
  const float* var   = (const float*)d_in[5];
  float* out = (float*)d_out;

  char* wsb = (char*)d_ws;
  size_t off = 0;
  int*   knn   = (int*)(wsb + off);   off += (size_t)BDIM * NPTS * KNN * 4;   // 2.62 MB
  int*   list  = (int*)(wsb + off);   off += (size_t)BDIM * NPTS * 4;         // 0.13 MB
  int*   cnt   = (int*)(wsb + off);   off += 256;
  float* sqw   = (float*)(wsb + off); off += (size_t)BDIM * NPTS * 4;         // 0.13 MB
  float* sqp   = (float*)(wsb + off); off += (size_t)BDIM * NPTS * 4;         // 0.13 MB
  float* a     = (float*)(wsb + off); off += (size_t)BDIM * NPTS * ODIM * 4;  // 8 MB
  float* cc    = (float*)(wsb + off); off += (size_t)BDIM * NPTS * ODIM * 4;  // 8 MB
  char*  img   = wsb + off;           off += (size_t)BDIM * NT128 * 32768;    // 8 MB
  (void)ws_size;

  prep_kernel <<<BDIM * NT128, 256, 0, stream>>>(x, img);
  sq_kernel   <<<BDIM * NPTS / 256, 256, 0, stream>>>(x, sqw, sqp, cnt);
  proj_kernel <<<BDIM * NPTS / 128, 256, 0, stream>>>(x, w, a, cc);
  fused_knn   <<<512, 256, 0, stream>>>(img, sqw, sqp, knn, list, cnt);
  fallback_knn<<<2048, 256, 0, stream>>>(x, sqw, cnt, list, knn);
  out_kernel  <<<dim3(NPTS / 64, BDIM), 256, 0, stream>>>(a, cc, knn, gamma, beta,
                                                          mean, var, out);
}

// Round 11
// 280.373 us; speedup vs baseline: 4.7137x; 1.0756x over previous
//
#include <hip/hip_runtime.h>
#include <cstdint>
#include <cstddef>

#define NPTS 4096
#define CDIM 64
#define BDIM 8
#define KNN  20
#define ODIM 64
#define NT128 32          // 128-col tile images per batch (prep layout)
#define NT64  64          // 64-col compute tiles per batch (fused)

typedef unsigned long long u64;
typedef unsigned int u32;
typedef _Float16 f16;
using f16x8 = __attribute__((ext_vector_type(8))) _Float16;
using f32x4 = __attribute__((ext_vector_type(4))) float;
#define SENT   (~0ull)
#define FINF (__builtin_inff())

__device__ __forceinline__ int swz(int r) { return (r & 7) ^ ((r >> 3) & 7); }

// order-preserving float->u32 flip (ascending float == ascending u32)
__device__ __forceinline__ unsigned flip_f32(float d) {
  unsigned bits = __float_as_uint(d);
  return bits ^ (unsigned)(((int)bits >> 31) | 0x80000000u);
}

// wave64 all-reduce min (DPP), uniform via readlane 63  (R3-validated)
__device__ __forceinline__ unsigned wave_min_u32(unsigned v) {
  unsigned t;
  t = (unsigned)__builtin_amdgcn_update_dpp((int)v, (int)v, 0x111, 0xF, 0xF, false); v = t < v ? t : v;
  t = (unsigned)__builtin_amdgcn_update_dpp((int)v, (int)v, 0x112, 0xF, 0xF, false); v = t < v ? t : v;
  t = (unsigned)__builtin_amdgcn_update_dpp((int)v, (int)v, 0x114, 0xF, 0xF, false); v = t < v ? t : v;
  t = (unsigned)__builtin_amdgcn_update_dpp((int)v, (int)v, 0x118, 0xF, 0xF, false); v = t < v ? t : v;
  t = (unsigned)__builtin_amdgcn_update_dpp((int)v, (int)v, 0x142, 0xA, 0xF, false); v = t < v ? t : v;
  t = (unsigned)__builtin_amdgcn_update_dpp((int)v, (int)v, 0x143, 0xC, 0xF, false); v = t < v ? t : v;
  return (unsigned)__builtin_amdgcn_readlane((int)v, 63);
}

// 16-lane all-reduce min, float (quad xor1, xor2, row_ror4, row_ror8)
__device__ __forceinline__ float rmin16f(float v) {
  int t;
  t = __builtin_amdgcn_update_dpp(__float_as_int(v), __float_as_int(v), 0xB1,  0xF, 0xF, false);
  v = fminf(v, __int_as_float(t));
  t = __builtin_amdgcn_update_dpp(__float_as_int(v), __float_as_int(v), 0x4E,  0xF, 0xF, false);
  v = fminf(v, __int_as_float(t));
  t = __builtin_amdgcn_update_dpp(__float_as_int(v), __float_as_int(v), 0x124, 0xF, 0xF, false);
  v = fminf(v, __int_as_float(t));
  t = __builtin_amdgcn_update_dpp(__float_as_int(v), __float_as_int(v), 0x128, 0xF, 0xF, false);
  v = fminf(v, __int_as_float(t));
  return v;
}
__device__ __forceinline__ u32 rmin16u(u32 v) {
  int t;
  t = __builtin_amdgcn_update_dpp((int)v, (int)v, 0xB1,  0xF, 0xF, false); v = ((u32)t < v) ? (u32)t : v;
  t = __builtin_amdgcn_update_dpp((int)v, (int)v, 0x4E,  0xF, 0xF, false); v = ((u32)t < v) ? (u32)t : v;
  t = __builtin_amdgcn_update_dpp((int)v, (int)v, 0x124, 0xF, 0xF, false); v = ((u32)t < v) ? (u32)t : v;
  t = __builtin_amdgcn_update_dpp((int)v, (int)v, 0x128, 0xF, 0xF, false); v = ((u32)t < v) ? (u32)t : v;
  return v;
}

// branchless insert into ascending sorted-8 of u64 keys (bubble, drops max)
__device__ __forceinline__ void ins8u(u64 (&L)[8], u64 v) {
  u64 c = v;
  #pragma unroll
  for (int j = 0; j < 8; ++j) {
    u64 lo = c < L[j] ? c : L[j];
    u64 hi = c < L[j] ? L[j] : c;
    L[j] = lo; c = hi;
  }
}

// async global->LDS, 16B per lane; LDS dest is wave-uniform base + lane*16
__device__ __forceinline__ void gl16(const char* g, char* l) {
  __builtin_amdgcn_global_load_lds(
      (const __attribute__((address_space(1))) unsigned int*)g,
      (__attribute__((address_space(3))) unsigned int*)l, 16, 0, 0);
}
// stage one 64-col tile (hi 8KB + lo 8KB) into a 16KB LDS buffer
__device__ __forceinline__ void stage64(const char* src_hi, char* dst, int tid) {
  const int w = tid >> 6, lane = tid & 63;
  const int off = w * 2048 + (lane << 4);
  gl16(src_hi + off,                 dst + w * 2048);
  gl16(src_hi + off + 1024,          dst + w * 2048 + 1024);
  gl16(src_hi + 16384 + off,         dst + 8192 + w * 2048);
  gl16(src_hi + 16384 + off + 1024,  dst + 8192 + w * 2048 + 1024);
}

// ---------------------------------------------------------------------------
// sq[b][n] = sum_c x[b][c][n]^2   (ascending c — BIT-IDENTICAL to R3-R10).
// Also writes permuted sqp; zeroes cnt.
// ---------------------------------------------------------------------------
__global__ __launch_bounds__(256) void sq_kernel(const float* __restrict__ x,
                                                 float* __restrict__ sq,
                                                 float* __restrict__ sqp,
                                                 int* __restrict__ cnt) {
  if (blockIdx.x == 0 && threadIdx.x == 0) *cnt = 0;
  int g = blockIdx.x * 256 + threadIdx.x;
  int b = g >> 12, n = g & (NPTS - 1);
  const float* xb = x + (size_t)b * CDIM * NPTS + n;
  float s = 0.f;
  #pragma unroll
  for (int c = 0; c < CDIM; ++c) { float v = xb[(size_t)c * NPTS]; s += v * v; }
  sq[g] = s;
  int t = n >> 6, j0 = n & 63;
  int sl = j0 & 15, e = j0 >> 4;
  sqp[(((size_t)b * NT64 + t) * 16 + sl) * 4 + e] = s;
}

// ---------------------------------------------------------------------------
// prep: per-(b,128-tile) fp16 hi/lo images, exact swizzled layout
// byte(n',c) = (n'*128 + 2c) ^ (swz(n')<<4); hi at +0, lo at +16384.
// ---------------------------------------------------------------------------
__global__ __launch_bounds__(256) void prep_kernel(const float* __restrict__ x,
                                                   char* __restrict__ img) {
  __shared__ char limg[32768];
  const int tid = threadIdx.x;
  const int b = blockIdx.x >> 5;
  const int t = blockIdx.x & 31;
  const int np = tid & 127;
  const int half = tid >> 7;
  const float* xb = x + (size_t)b * CDIM * NPTS + t * 128 + np;
  const int sw = swz(np) << 4;
  #pragma unroll
  for (int oct = 0; oct < 4; ++oct) {
    const int cb = half * 32 + oct * 8;
    f16x8 hv, lv;
    #pragma unroll
    for (int j = 0; j < 8; ++j) {
      float v = xb[(size_t)(cb + j) * NPTS];
      f16 h = (f16)v;
      hv[j] = h;
      lv[j] = (f16)(v - (float)h);
    }
    int byt = (np * 128 + cb * 2) ^ sw;
    *(f16x8*)(limg + byt) = hv;
    *(f16x8*)(limg + 16384 + byt) = lv;
  }
  __syncthreads();
  char* dst = img + (size_t)blockIdx.x * 32768;
  #pragma unroll
  for (int i = 0; i < 8; ++i)
    *(float4*)(dst + i * 4096 + tid * 16) = *(const float4*)(limg + i * 4096 + tid * 16);
}

// ---------------------------------------------------------------------------
// Fused dist+top20. Dist numerics (MFMA fp16x3 hh,hl,lh; ks ascending) are
// BIT-IDENTICAL to R4-R10. Float-domain keys as R10. NEW: med3 insertion —
// for ascending sorted-8 L and value v:
//   L'[0] = min(v,L[0]);  L'[j] = med3(v, L[j-1], L[j])  (j=1..7)
// 8 independent single-cycle ops (vs 16 chained min/max). Result list is
// mathematically identical to the bubble insert; set/flags unchanged.
// ---------------------------------------------------------------------------
__global__ __launch_bounds__(256, 2) void fused_knn(const char* __restrict__ img,
                                                    const float* __restrict__ sq,
                                                    const float* __restrict__ sqp,
                                                    int* __restrict__ knn,
                                                    int* __restrict__ list,
                                                    int* __restrict__ cnt) {
  __shared__ char XB[2][16384];

  const int tid = threadIdx.x;
  const int lane = tid & 63;
  const int w = tid >> 6;
  const int q = lane >> 4;
  const int s = lane & 15;

  const int blk = blockIdx.x;
  const int b  = blk >> 6;
  const int r0 = (blk & 63) * 64;
  const char* imgb = img + (size_t)b * (NT128 * 32768);
  const float* sqb = sq + (size_t)b * NPTS;
  const float4* sqp4 = (const float4*)(sqp + (size_t)b * NT64 * 64);

  stage64(imgb, XB[0], tid);      // tile 0

  // A fragments straight from global img (L2/L3-resident), same byte layout
  f16x8 Ah[2], Al[2];
  {
    const int grow = r0 + w * 16 + s;
    const char* at = imgb + (size_t)(grow >> 7) * 32768;
    const int nn = grow & 127;
    const int swn = swz(nn) << 4;
    #pragma unroll
    for (int ks = 0; ks < 2; ++ks) {
      int byt = (nn * 128 + (ks * 32 + q * 8) * 2) ^ swn;
      Ah[ks] = *(const f16x8*)(at + byt);
      Al[ks] = *(const f16x8*)(at + 16384 + byt);
    }
  }

  float sqr[4];
  #pragma unroll
  for (int reg = 0; reg < 4; ++reg) sqr[reg] = sqb[r0 + w * 16 + q * 4 + reg];

  float L[4][8];
  #pragma unroll
  for (int reg = 0; reg < 4; ++reg)
    #pragma unroll
    for (int j = 0; j < 8; ++j) L[reg][j] = FINF;

  __syncthreads();                 // tile-0 staging drained

  for (int t = 0; t < NT64; ++t) {
    // pin the top-8 lists into arch VGPRs (no-op if honored)
    #pragma unroll
    for (int reg = 0; reg < 4; ++reg)
      #pragma unroll
      for (int jj = 0; jj < 8; ++jj)
        asm volatile("" : "+v"(L[reg][jj]));

    if (t + 1 < NT64)
      stage64(imgb + (size_t)((t + 1) >> 1) * 32768 + (size_t)((t + 1) & 1) * 8192,
              XB[(t + 1) & 1], tid);
    const char* XBc = XB[t & 1];
    const float4 sm4 = sqp4[t * 16 + s];     // sq[t*64 + e*16 + s], e=0..3
    #pragma unroll
    for (int e = 0; e < 4; ++e) {
      const int j = e * 16 + s;
      const int swj = swz(j) << 4;
      f32x4 acc = {0.f, 0.f, 0.f, 0.f};
      #pragma unroll
      for (int ks = 0; ks < 2; ++ks) {
        int byt = (j * 128 + (ks * 32 + q * 8) * 2) ^ swj;
        f16x8 Bh = *(const f16x8*)(XBc + byt);
        f16x8 Bl = *(const f16x8*)(XBc + 8192 + byt);
        acc = __builtin_amdgcn_mfma_f32_16x16x32_f16(Ah[ks], Bh, acc, 0, 0, 0);
        acc = __builtin_amdgcn_mfma_f32_16x16x32_f16(Ah[ks], Bl, acc, 0, 0, 0);
        acc = __builtin_amdgcn_mfma_f32_16x16x32_f16(Al[ks], Bh, acc, 0, 0, 0);
      }
      asm volatile("" : "+v"(acc));          // acc reads happen from VGPRs
      const float sm = (&sm4.x)[e];
      const u32 klo = (u32)(t * 4 + e);      // = mcol >> 4, wave-uniform
      #pragma unroll
      for (int reg = 0; reg < 4; ++reg) {
        float v = (sqr[reg] + sm) - 2.0f * acc[reg];   // same expr as R4-R10
        float key = __uint_as_float((__float_as_uint(v) & 0xFFFFFF00u) | klo);
        // med3 insertion network (independent ops, drops current max)
        float n0 = fminf(key, L[reg][0]);
        float n1 = __builtin_amdgcn_fmed3f(key, L[reg][0], L[reg][1]);
        float n2 = __builtin_amdgcn_fmed3f(key, L[reg][1], L[reg][2]);
        float n3 = __builtin_amdgcn_fmed3f(key, L[reg][2], L[reg][3]);
        float n4 = __builtin_amdgcn_fmed3f(key, L[reg][3], L[reg][4]);
        float n5 = __builtin_amdgcn_fmed3f(key, L[reg][4], L[reg][5]);
        float n6 = __builtin_amdgcn_fmed3f(key, L[reg][5], L[reg][6]);
        float n7 = __builtin_amdgcn_fmed3f(key, L[reg][6], L[reg][7]);
        L[reg][0] = n0; L[reg][1] = n1; L[reg][2] = n2; L[reg][3] = n3;
        L[reg][4] = n4; L[reg][5] = n5; L[reg][6] = n6; L[reg][7] = n7;
      }
    }
    __syncthreads();   // reads of XB[t&1] done; next-tile staging drained
  }

  // pops: 21 rounds per row (20 results + boundary probe); 4 quarters
  // resolve 4 rows concurrently. Float-domain min; bit-prefix certificates.
  #pragma unroll
  for (int reg = 0; reg < 4; ++reg) {
    bool flg = false;
    int iA = 0, iB = 0;
    u32 k20 = 0, k21 = 0;
    for (int r = 0; r < KNN + 1; ++r) {
      float head = L[reg][0];
      float wkey = rmin16f(head);
      unsigned long long bal = __ballot(head == wkey);
      unsigned qm = (unsigned)((bal >> (q * 16)) & 0xFFFFull);
      int swin = __ffs((int)qm) - 1;
      flg = flg || ((qm & (qm - 1u)) != 0u);          // multi-owner tie
      u32 kb = __float_as_uint(wkey);
      int idx = (int)(((kb & 0xFFu) << 4) | (u32)swin);
      if (r < 16) { if (s == r) iA = idx; }
      else if (r < KNN) { if (s == r - 16) iB = idx; }
      if (r == KNN - 1) k20 = kb;
      if (r == KNN)     k21 = kb;
      bool own = (head == wkey) && (s == swin);
      #pragma unroll
      for (int jj = 0; jj < 7; ++jj) L[reg][jj] = own ? L[reg][jj + 1] : L[reg][jj];
      L[reg][7] = own ? FINF : L[reg][7];
    }
    flg = flg || ((k20 >> 8) == (k21 >> 8));          // boundary prefix tie
    u32 alive = (__float_as_uint(L[reg][0]) == __float_as_uint(FINF)) ? 0u : 1u;
    flg = flg || (rmin16u(alive) == 0u);              // drained lane
    size_t grow = (size_t)b * NPTS + r0 + w * 16 + q * 4 + reg;
    knn[grow * KNN + s] = iA;
    if (s < 4) knn[grow * KNN + 16 + s] = iB;
    if (s == 0 && flg) { int p = atomicAdd(cnt, 1); list[p] = (int)grow; }
  }
}

// ---------------------------------------------------------------------------
// Exact fp32 brute-force for flagged rows (R7-R10-validated, unchanged).
// ---------------------------------------------------------------------------
__global__ __launch_bounds__(256) void fallback_knn(const float* __restrict__ x,
                                                    const float* __restrict__ sq,
                                                    const int* __restrict__ cnt,
                                                    const int* __restrict__ list,
                                                    int* __restrict__ knn) {
  __shared__ float xrl[CDIM];
  __shared__ u64 cand[4 * KNN];
  const int tid = threadIdx.x, lane = tid & 63, wv = tid >> 6;
  const int count = *cnt;

  for (int it = blockIdx.x; it < count; it += gridDim.x) {
    const int g = list[it];
    const int b = g >> 12, r = g & (NPTS - 1);
    const float* xb  = x  + (size_t)b * CDIM * NPTS;
    const float* sqb = sq + (size_t)b * NPTS;
    if (tid < CDIM) xrl[tid] = xb[(size_t)tid * NPTS + r];
    __syncthreads();
    const float sqr = sqb[r];

    u64 L[8];
    #pragma unroll
    for (int j = 0; j < 8; ++j) L[j] = SENT;
    #pragma unroll
    for (int ii = 0; ii < 4; ++ii) {
      const int i = wv * 4 + ii;
      float a0 = 0.f, a1 = 0.f, a2 = 0.f, a3 = 0.f;
      const float* xp = xb + i * 256 + lane * 4;
      #pragma unroll
      for (int c4 = 0; c4 < 16; ++c4) {
        float4 xr4 = *(const float4*)&xrl[c4 * 4];
        #pragma unroll
        for (int j = 0; j < 4; ++j) {
          float4 xv = *(const float4*)(xp + (size_t)(c4 * 4 + j) * NPTS);
          float xr = (&xr4.x)[j];
          a0 += xr * xv.x; a1 += xr * xv.y; a2 += xr * xv.z; a3 += xr * xv.w;
        }
      }
      int mb = i * 256 + lane * 4;
      float4 sv = *(const float4*)(sqb + mb);
      ins8u(L, ((u64)flip_f32(sqr + sv.x - 2.0f * a0) << 12) | (unsigned)mb);
      ins8u(L, ((u64)flip_f32(sqr + sv.y - 2.0f * a1) << 12) | (unsigned)(mb + 1));
      ins8u(L, ((u64)flip_f32(sqr + sv.z - 2.0f * a2) << 12) | (unsigned)(mb + 2));
      ins8u(L, ((u64)flip_f32(sqr + sv.w - 2.0f * a3) << 12) | (unsigned)(mb + 3));
    }

    u64 last = 0; bool done = false;
    for (int rr = 0; rr < KNN; ++rr) {
      bool need = (L[0] == SENT) && !done;
      if (__any(need)) {
        if (need) {                                  // never fires in practice
          #pragma unroll
          for (int j = 0; j < 8; ++j) L[j] = SENT;
          for (int ii = 0; ii < 4; ++ii) {
            const int i = wv * 4 + ii;
            float a0 = 0.f, a1 = 0.f, a2 = 0.f, a3 = 0.f;
            const float* xp = xb + i * 256 + lane * 4;
            #pragma unroll
            for (int c4 = 0; c4 < 16; ++c4) {
              float4 xr4 = *(const float4*)&xrl[c4 * 4];
              #pragma unroll
              for (int j = 0; j < 4; ++j) {
                float4 xv = *(const float4*)(xp + (size_t)(c4 * 4 + j) * NPTS);
                float xr = (&xr4.x)[j];
                a0 += xr * xv.x; a1 += xr * xv.y; a2 += xr * xv.z; a3 += xr * xv.w;
              }
            }
            int mb = i * 256 + lane * 4;
            float4 sv = *(const float4*)(sqb + mb);
            u64 v;
            v = ((u64)flip_f32(sqr + sv.x - 2.0f * a0) << 12) | (unsigned)mb;       ins8u(L, v > last ? v : SENT);
            v = ((u64)flip_f32(sqr + sv.y - 2.0f * a1) << 12) | (unsigned)(mb + 1); ins8u(L, v > last ? v : SENT);
            v = ((u64)flip_f32(sqr + sv.z - 2.0f * a2) << 12) | (unsigned)(mb + 2); ins8u(L, v > last ? v : SENT);
            v = ((u64)flip_f32(sqr + sv.w - 2.0f * a3) << 12) | (unsigned)(mb + 3); ins8u(L, v > last ? v : SENT);
          }
          if (L[0] == SENT) done = true;
        }
      }
      unsigned keyH = (unsigned)(L[0] >> 12);
      unsigned wkey = wave_min_u32(keyH);
      unsigned mc   = (keyH == wkey) ? (unsigned)(L[0] & 0xFFF) : 0xFFFFFFFFu;
      unsigned wm   = wave_min_u32(mc);
      u64 wsel = ((u64)wkey << 12) | wm;
      if (lane == rr) cand[wv * KNN + rr] = wsel;
      bool win = (L[0] == wsel);
      #pragma unroll
      for (int j = 0; j < 7; ++j) L[j] = win ? L[j + 1] : L[j];
      L[7] = win ? SENT : L[7];
      last = wsel;
    }
    __syncthreads();

    if (wv == 0) {                       // merge 80 candidates -> top 20
      u64 c0 = cand[lane < 4 * KNN ? lane : 0];
      if (lane >= 4 * KNN) c0 = SENT;
      u64 c1 = (lane < 4 * KNN - 64) ? cand[64 + lane] : SENT;
      int myidx = 0;
      for (int rr = 0; rr < KNN; ++rr) {
        u64 mn = c0 < c1 ? c0 : c1;
        unsigned keyH = (unsigned)(mn >> 12);
        unsigned wkey = wave_min_u32(keyH);
        unsigned mc   = (keyH == wkey) ? (unsigned)(mn & 0xFFF) : 0xFFFFFFFFu;
        unsigned wm   = wave_min_u32(mc);
        u64 wsel = ((u64)wkey << 12) | wm;
        if (lane == rr) myidx = (int)wm;
        if (c0 == wsel)      { c0 = c1; c1 = SENT; }
        else if (c1 == wsel) { c1 = SENT; }
      }
      if (lane < KNN) knn[(size_t)g * KNN + lane] = myidx;
    }
    __syncthreads();
  }
}

// ---------------------------------------------------------------------------
// a[b][n][o]  = sum_c (W[o][c]-W[o][c+64]) * x[b][c][n]
// cc[b][n][o] = sum_c  W[o][c+64]          * x[b][c][n]
// ---------------------------------------------------------------------------
__global__ __launch_bounds__(256) void proj_kernel(const float* __restrict__ x,
                                                   const float* __restrict__ w,
                                                   float* __restrict__ a,
                                                   float* __restrict__ cc) {
  __shared__ float wa[CDIM][ODIM];
  __shared__ float wc[CDIM][ODIM];
  const int tid = threadIdx.x;
  #pragma unroll
  for (int p = 0; p < 16; ++p) {
    int idx = p * 256 + tid;
    int o = idx & 63, c = idx >> 6;
    float w1 = w[o * 128 + c], w2 = w[o * 128 + 64 + c];
    wa[c][o] = w1 - w2;
    wc[c][o] = w2;
  }
  __syncthreads();

  const int og = tid >> 6;
  const int nl = tid & 63;
  const int g0 = blockIdx.x * 128;
  const int b  = g0 >> 12;
  const int n0 = g0 & (NPTS - 1);
  const float* xB = x + (size_t)b * CDIM * NPTS;

  float aa0[16], ac0[16], aa1[16], ac1[16];
  #pragma unroll
  for (int qq = 0; qq < 16; ++qq) { aa0[qq] = ac0[qq] = aa1[qq] = ac1[qq] = 0.f; }

  #pragma unroll 4
  for (int c = 0; c < CDIM; ++c) {
    float xv0 = xB[(size_t)c * NPTS + n0 + nl];
    float xv1 = xB[(size_t)c * NPTS + n0 + 64 + nl];
    #pragma unroll
    for (int q4 = 0; q4 < 4; ++q4) {
      float4 va = *(const float4*)&wa[c][og * 16 + q4 * 4];
      float4 vc = *(const float4*)&wc[c][og * 16 + q4 * 4];
      aa0[q4*4+0] += va.x * xv0; aa0[q4*4+1] += va.y * xv0;
      aa0[q4*4+2] += va.z * xv0; aa0[q4*4+3] += va.w * xv0;
      ac0[q4*4+0] += vc.x * xv0; ac0[q4*4+1] += vc.y * xv0;
      ac0[q4*4+2] += vc.z * xv0; ac0[q4*4+3] += vc.w * xv0;
      aa1[q4*4+0] += va.x * xv1; aa1[q4*4+1] += va.y * xv1;
      aa1[q4*4+2] += va.z * xv1; aa1[q4*4+3] += va.w * xv1;
      ac1[q4*4+0] += vc.x * xv1; ac1[q4*4+1] += vc.y * xv1;
      ac1[q4*4+2] += vc.z * xv1; ac1[q4*4+3] += vc.w * xv1;
    }
  }
  size_t ga0 = (size_t)(g0 + nl) * ODIM + og * 16;
  size_t ga1 = (size_t)(g0 + 64 + nl) * ODIM + og * 16;
  #pragma unroll
  for (int q4 = 0; q4 < 4; ++q4) {
    *(float4*)&a [ga0 + q4 * 4] = *(float4*)&aa0[q4 * 4];
    *(float4*)&cc[ga0 + q4 * 4] = *(float4*)&ac0[q4 * 4];
    *(float4*)&a [ga1 + q4 * 4] = *(float4*)&aa1[q4 * 4];
    *(float4*)&cc[ga1 + q4 * 4] = *(float4*)&ac1[q4 * 4];
  }
}

// ---------------------------------------------------------------------------
// out[b][o][n] = relu(inv[o] * max_k(a[b][n][o] + cc[b][knn[n][k]][o]) + bias[o])
// ---------------------------------------------------------------------------
__global__ __launch_bounds__(256) void out_kernel(const float* __restrict__ a,
                                                  const float* __restrict__ cc,
                                                  const int* __restrict__ knn,
                                                  const float* __restrict__ gamma,
                                                  const float* __restrict__ beta,
                                                  const float* __restrict__ mean,
                                                  const float* __restrict__ var,
                                                  float* __restrict__ out) {
  __shared__ float tile[64][65];
  const int tid = threadIdx.x, lane = tid & 63, wv = tid >> 6;
  const int b = blockIdx.y;
  const int n0 = blockIdx.x * 64;
  float inv  = gamma[lane] / sqrtf(var[lane] + 1e-5f);
  float bias = beta[lane] - mean[lane] * inv;
  for (int t = 0; t < 16; ++t) {
    int nl = wv * 16 + t;
    size_t base = (size_t)b * NPTS + (n0 + nl);
    float av = a[base * ODIM + lane];
    const int* kr = knn + base * KNN;
    float m = -INFINITY;
    #pragma unroll
    for (int k = 0; k < KNN; ++k) {
      int j = kr[k];
      float cv = cc[((size_t)b * NPTS + j) * ODIM + lane];
      m = fmaxf(m, av + cv);
    }
    float v = m * inv + bias;
    tile[nl][lane] = v > 0.f ? v : 0.f;
  }
  __syncthreads();
  for (int t = 0; t < 16; ++t) {
    int o = wv * 16 + t;
    out[((size_t)b * ODIM + o) * NPTS + n0 + lane] = tile[lane][o];
  }
}

// ---------------------------------------------------------------------------
extern "C" void kernel_launch(void* const* d_in, const int* in_sizes, int n_in,
                              void* d_out, int out_size, void* d_ws, size_t ws_size,
                              hipStream_t stream) {
  const float* x     = (const float*)d_in[0];
  const float* w     = (const float*)d_in[1];
  const float* gamma = (const float*)d_in[2];
  const float* beta  = (const float*)d_in[3];
  const float* mean  = (const float*)d_in[4];
  const float* var   = (const float*)d_in[5];
  float* out = (float*)d_out;

  char* wsb = (char*)d_ws;
  size_t off = 0;
  int*   knn   = (int*)(wsb + off);   off += (size_t)BDIM * NPTS * KNN * 4;   // 2.62 MB
  int*   list  = (int*)(wsb + off);   off += (size_t)BDIM * NPTS * 4;         // 0.13 MB
  int*   cnt   = (int*)(wsb + off);   off += 256;
  float* sqw   = (float*)(wsb + off); off += (size_t)BDIM * NPTS * 4;         // 0.13 MB
  float* sqp   = (float*)(wsb + off); off += (size_t)BDIM * NPTS * 4;         // 0.13 MB
  float* a     = (float*)(wsb + off); off += (size_t)BDIM * NPTS * ODIM * 4;  // 8 MB
  float* cc    = (float*)(wsb + off); off += (size_t)BDIM * NPTS * ODIM * 4;  // 8 MB
  char*  img   = wsb + off;           off += (size_t)BDIM * NT128 * 32768;    // 8 MB
  (void)ws_size;

  prep_kernel <<<BDIM * NT128, 256, 0, stream>>>(x, img);
  sq_kernel   <<<BDIM * NPTS / 256, 256, 0, stream>>>(x, sqw, sqp, cnt);
  proj_kernel <<<BDIM * NPTS / 128, 256, 0, stream>>>(x, w, a, cc);
  fused_knn   <<<512, 256, 0, stream>>>(img, sqw, sqp, knn, list, cnt);
  fallback_knn<<<2048, 256, 0, stream>>>(x, sqw, cnt, list, knn);
  out_kernel  <<<dim3(NPTS / 64, BDIM), 256, 0, stream>>>(a, cc, knn, gamma, beta,
                                                          mean, var, out);
}

// Round 12
// 266.399 us; speedup vs baseline: 4.9610x; 1.0525x over previous
//
#include <hip/hip_runtime.h>
#include <cstdint>
#include <cstddef>

#define NPTS 4096
#define CDIM 64
#define BDIM 8
#define KNN  20
#define ODIM 64
#define NT128 32          // 128-col tile images per batch (prep layout)
#define NT64  64          // 64-col compute tiles per batch (fused)

typedef unsigned long long u64;
typedef unsigned int u32;
typedef _Float16 f16;
using f16x8 = __attribute__((ext_vector_type(8))) _Float16;
using f32x4 = __attribute__((ext_vector_type(4))) float;
#define SENT   (~0ull)
#define FINF (__builtin_inff())

__device__ __forceinline__ int swz(int r) { return (r & 7) ^ ((r >> 3) & 7); }

// order-preserving float->u32 flip (ascending float == ascending u32)
__device__ __forceinline__ unsigned flip_f32(float d) {
  unsigned bits = __float_as_uint(d);
  return bits ^ (unsigned)(((int)bits >> 31) | 0x80000000u);
}

// wave64 all-reduce min (DPP), uniform via readlane 63  (R3-validated)
__device__ __forceinline__ unsigned wave_min_u32(unsigned v) {
  unsigned t;
  t = (unsigned)__builtin_amdgcn_update_dpp((int)v, (int)v, 0x111, 0xF, 0xF, false); v = t < v ? t : v;
  t = (unsigned)__builtin_amdgcn_update_dpp((int)v, (int)v, 0x112, 0xF, 0xF, false); v = t < v ? t : v;
  t = (unsigned)__builtin_amdgcn_update_dpp((int)v, (int)v, 0x114, 0xF, 0xF, false); v = t < v ? t : v;
  t = (unsigned)__builtin_amdgcn_update_dpp((int)v, (int)v, 0x118, 0xF, 0xF, false); v = t < v ? t : v;
  t = (unsigned)__builtin_amdgcn_update_dpp((int)v, (int)v, 0x142, 0xA, 0xF, false); v = t < v ? t : v;
  t = (unsigned)__builtin_amdgcn_update_dpp((int)v, (int)v, 0x143, 0xC, 0xF, false); v = t < v ? t : v;
  return (unsigned)__builtin_amdgcn_readlane((int)v, 63);
}

// 16-lane all-reduce min, float (quad xor1, xor2, row_ror4, row_ror8)
__device__ __forceinline__ float rmin16f(float v) {
  int t;
  t = __builtin_amdgcn_update_dpp(__float_as_int(v), __float_as_int(v), 0xB1,  0xF, 0xF, false);
  v = fminf(v, __int_as_float(t));
  t = __builtin_amdgcn_update_dpp(__float_as_int(v), __float_as_int(v), 0x4E,  0xF, 0xF, false);
  v = fminf(v, __int_as_float(t));
  t = __builtin_amdgcn_update_dpp(__float_as_int(v), __float_as_int(v), 0x124, 0xF, 0xF, false);
  v = fminf(v, __int_as_float(t));
  t = __builtin_amdgcn_update_dpp(__float_as_int(v), __float_as_int(v), 0x128, 0xF, 0xF, false);
  v = fminf(v, __int_as_float(t));
  return v;
}
__device__ __forceinline__ u32 rmin16u(u32 v) {
  int t;
  t = __builtin_amdgcn_update_dpp((int)v, (int)v, 0xB1,  0xF, 0xF, false); v = ((u32)t < v) ? (u32)t : v;
  t = __builtin_amdgcn_update_dpp((int)v, (int)v, 0x4E,  0xF, 0xF, false); v = ((u32)t < v) ? (u32)t : v;
  t = __builtin_amdgcn_update_dpp((int)v, (int)v, 0x124, 0xF, 0xF, false); v = ((u32)t < v) ? (u32)t : v;
  t = __builtin_amdgcn_update_dpp((int)v, (int)v, 0x128, 0xF, 0xF, false); v = ((u32)t < v) ? (u32)t : v;
  return v;
}

// med3 insertion into ascending sorted-8 (descending in-place, 8 independent ops)
__device__ __forceinline__ void insert_med3(float (&Lr)[8], float key) {
  Lr[7] = __builtin_amdgcn_fmed3f(key, Lr[6], Lr[7]);
  Lr[6] = __builtin_amdgcn_fmed3f(key, Lr[5], Lr[6]);
  Lr[5] = __builtin_amdgcn_fmed3f(key, Lr[4], Lr[5]);
  Lr[4] = __builtin_amdgcn_fmed3f(key, Lr[3], Lr[4]);
  Lr[3] = __builtin_amdgcn_fmed3f(key, Lr[2], Lr[3]);
  Lr[2] = __builtin_amdgcn_fmed3f(key, Lr[1], Lr[2]);
  Lr[1] = __builtin_amdgcn_fmed3f(key, Lr[0], Lr[1]);
  Lr[0] = fminf(key, Lr[0]);
}

// branchless insert into ascending sorted-8 of u64 keys (bubble, drops max)
__device__ __forceinline__ void ins8u(u64 (&L)[8], u64 v) {
  u64 c = v;
  #pragma unroll
  for (int j = 0; j < 8; ++j) {
    u64 lo = c < L[j] ? c : L[j];
    u64 hi = c < L[j] ? L[j] : c;
    L[j] = lo; c = hi;
  }
}

// async global->LDS, 16B per lane; LDS dest is wave-uniform base + lane*16
__device__ __forceinline__ void gl16(const char* g, char* l) {
  __builtin_amdgcn_global_load_lds(
      (const __attribute__((address_space(1))) unsigned int*)g,
      (__attribute__((address_space(3))) unsigned int*)l, 16, 0, 0);
}
// stage one 64-col tile (hi 8KB + lo 8KB) into a 16KB LDS buffer (256 thr)
__device__ __forceinline__ void stage64(const char* src_hi, char* dst, int t256) {
  const int w = t256 >> 6, lane = t256 & 63;
  const int off = w * 2048 + (lane << 4);
  gl16(src_hi + off,                 dst + w * 2048);
  gl16(src_hi + off + 1024,          dst + w * 2048 + 1024);
  gl16(src_hi + 16384 + off,         dst + 8192 + w * 2048);
  gl16(src_hi + 16384 + off + 1024,  dst + 8192 + w * 2048 + 1024);
}

// ---------------------------------------------------------------------------
// sq[b][n] = sum_c x[b][c][n]^2   (ascending c — BIT-IDENTICAL to R3-R11).
// Also writes permuted sqp; zeroes cnt.
// ---------------------------------------------------------------------------
__global__ __launch_bounds__(256) void sq_kernel(const float* __restrict__ x,
                                                 float* __restrict__ sq,
                                                 float* __restrict__ sqp,
                                                 int* __restrict__ cnt) {
  if (blockIdx.x == 0 && threadIdx.x == 0) *cnt = 0;
  int g = blockIdx.x * 256 + threadIdx.x;
  int b = g >> 12, n = g & (NPTS - 1);
  const float* xb = x + (size_t)b * CDIM * NPTS + n;
  float s = 0.f;
  #pragma unroll
  for (int c = 0; c < CDIM; ++c) { float v = xb[(size_t)c * NPTS]; s += v * v; }
  sq[g] = s;
  int t = n >> 6, j0 = n & 63;
  int sl = j0 & 15, e = j0 >> 4;
  sqp[(((size_t)b * NT64 + t) * 16 + sl) * 4 + e] = s;
}

// ---------------------------------------------------------------------------
// prep: per-(b,128-tile) fp16 hi/lo images, exact swizzled layout
// byte(n',c) = (n'*128 + 2c) ^ (swz(n')<<4); hi at +0, lo at +16384.
// ---------------------------------------------------------------------------
__global__ __launch_bounds__(256) void prep_kernel(const float* __restrict__ x,
                                                   char* __restrict__ img) {
  __shared__ char limg[32768];
  const int tid = threadIdx.x;
  const int b = blockIdx.x >> 5;
  const int t = blockIdx.x & 31;
  const int np = tid & 127;
  const int half = tid >> 7;
  const float* xb = x + (size_t)b * CDIM * NPTS + t * 128 + np;
  const int sw = swz(np) << 4;
  #pragma unroll
  for (int oct = 0; oct < 4; ++oct) {
    const int cb = half * 32 + oct * 8;
    f16x8 hv, lv;
    #pragma unroll
    for (int j = 0; j < 8; ++j) {
      float v = xb[(size_t)(cb + j) * NPTS];
      f16 h = (f16)v;
      hv[j] = h;
      lv[j] = (f16)(v - (float)h);
    }
    int byt = (np * 128 + cb * 2) ^ sw;
    *(f16x8*)(limg + byt) = hv;
    *(f16x8*)(limg + 16384 + byt) = lv;
  }
  __syncthreads();
  char* dst = img + (size_t)blockIdx.x * 32768;
  #pragma unroll
  for (int i = 0; i < 8; ++i)
    *(float4*)(dst + i * 4096 + tid * 16) = *(const float4*)(limg + i * 4096 + tid * 16);
}

// ---------------------------------------------------------------------------
// Fused dist+top20, 8-wave column-split. Waves 0-3 sweep tiles 0-31, waves
// 4-7 sweep tiles 32-63 (own double-buffered XB each; 64KB LDS). End: group-1
// dumps sorted-8 lists to LDS (lane-contiguous), group-0 merges via 8 more
// med3 inserts -> exact top-8 of the SAME 256-col sample as R11 => output
// bit-identical to R11. 2 blocks/CU x 8 waves = 4 waves/SIMD (2x latency
// hiding vs R11's 2). Dist numerics / certificate / pops unchanged.
// ---------------------------------------------------------------------------
__global__ __launch_bounds__(512, 2) void fused_knn(const char* __restrict__ img,
                                                    const float* __restrict__ sq,
                                                    const float* __restrict__ sqp,
                                                    int* __restrict__ knn,
                                                    int* __restrict__ list,
                                                    int* __restrict__ cnt) {
  __shared__ char XB[2][2][16384];     // [grp][dbuf] — 64 KB

  const int tid  = threadIdx.x;
  const int grp  = tid >> 8;           // 0: tiles 0-31, 1: tiles 32-63
  const int t256 = tid & 255;
  const int lane = tid & 63;
  const int w4   = t256 >> 6;          // wave within group (0..3)
  const int q = lane >> 4;
  const int s = lane & 15;

  const int blk = blockIdx.x;
  const int b  = blk >> 6;
  const int r0 = (blk & 63) * 64;
  const char* imgb = img + (size_t)b * (NT128 * 32768);
  const float* sqb = sq + (size_t)b * NPTS;
  const float4* sqp4 = (const float4*)(sqp + (size_t)b * NT64 * 64);

  const int tb = grp * 32;             // group tile base
  // tile -> src byte offset within batch image
  #define TSRC(tile) (imgb + (size_t)((tile) >> 1) * 32768 + (size_t)((tile) & 1) * 8192)

  stage64(TSRC(tb), XB[grp][0], t256);   // group's tile 0

  // A fragments straight from global img (L2/L3-resident), same byte layout
  f16x8 Ah[2], Al[2];
  {
    const int grow = r0 + w4 * 16 + s;
    const char* at = imgb + (size_t)(grow >> 7) * 32768;
    const int nn = grow & 127;
    const int swn = swz(nn) << 4;
    #pragma unroll
    for (int ks = 0; ks < 2; ++ks) {
      int byt = (nn * 128 + (ks * 32 + q * 8) * 2) ^ swn;
      Ah[ks] = *(const f16x8*)(at + byt);
      Al[ks] = *(const f16x8*)(at + 16384 + byt);
    }
  }

  float sqr[4];
  #pragma unroll
  for (int reg = 0; reg < 4; ++reg) sqr[reg] = sqb[r0 + w4 * 16 + q * 4 + reg];

  float L[4][8];
  #pragma unroll
  for (int reg = 0; reg < 4; ++reg)
    #pragma unroll
    for (int j = 0; j < 8; ++j) L[reg][j] = FINF;

  __syncthreads();                 // tile-0 staging drained (both groups)

  for (int t = 0; t < 32; ++t) {
    #pragma unroll
    for (int reg = 0; reg < 4; ++reg)
      #pragma unroll
      for (int jj = 0; jj < 8; ++jj)
        asm volatile("" : "+v"(L[reg][jj]));

    if (t + 1 < 32)
      stage64(TSRC(tb + t + 1), XB[grp][(t + 1) & 1], t256);
    const char* XBc = XB[grp][t & 1];
    const int tile = tb + t;
    const float4 sm4 = sqp4[tile * 16 + s];   // sq[tile*64 + e*16 + s]
    #pragma unroll
    for (int e = 0; e < 4; ++e) {
      const int j = e * 16 + s;
      const int swj = swz(j) << 4;
      f32x4 acc = {0.f, 0.f, 0.f, 0.f};
      #pragma unroll
      for (int ks = 0; ks < 2; ++ks) {
        int byt = (j * 128 + (ks * 32 + q * 8) * 2) ^ swj;
        f16x8 Bh = *(const f16x8*)(XBc + byt);
        f16x8 Bl = *(const f16x8*)(XBc + 8192 + byt);
        acc = __builtin_amdgcn_mfma_f32_16x16x32_f16(Ah[ks], Bh, acc, 0, 0, 0);
        acc = __builtin_amdgcn_mfma_f32_16x16x32_f16(Ah[ks], Bl, acc, 0, 0, 0);
        acc = __builtin_amdgcn_mfma_f32_16x16x32_f16(Al[ks], Bh, acc, 0, 0, 0);
      }
      asm volatile("" : "+v"(acc));
      const float sm = (&sm4.x)[e];
      const u32 klo = (u32)(tile * 4 + e);    // = mcol >> 4, wave-uniform
      #pragma unroll
      for (int reg = 0; reg < 4; ++reg) {
        float v = (sqr[reg] + sm) - 2.0f * acc[reg];   // same expr as R4-R11
        float key = __uint_as_float((__float_as_uint(v) & 0xFFFFFF00u) | klo);
        insert_med3(L[reg], key);
      }
    }
    __syncthreads();   // reads of XB[grp][t&1] done; next staging drained
  }

  // merge: group-1 dumps lists (lane-contiguous layout, conflict-free)
  float* mbuf = (float*)XB;            // reuse 64KB (needs 32KB)
  if (grp == 1) {
    #pragma unroll
    for (int reg = 0; reg < 4; ++reg)
      #pragma unroll
      for (int j = 0; j < 8; ++j)
        mbuf[((reg * 8 + j) * 4 + w4) * 64 + lane] = L[reg][j];
  }
  __syncthreads();

  if (grp == 1) return;                // no barriers below

  #pragma unroll
  for (int reg = 0; reg < 4; ++reg)
    #pragma unroll
    for (int j = 0; j < 8; ++j)
      insert_med3(L[reg], mbuf[((reg * 8 + j) * 4 + w4) * 64 + lane]);

  // pops: 21 rounds per row (20 results + boundary probe); 4 quarters
  // resolve 4 rows concurrently. Float-domain min; bit-prefix certificates.
  #pragma unroll
  for (int reg = 0; reg < 4; ++reg) {
    bool flg = false;
    int iA = 0, iB = 0;
    u32 k20 = 0, k21 = 0;
    for (int r = 0; r < KNN + 1; ++r) {
      float head = L[reg][0];
      float wkey = rmin16f(head);
      unsigned long long bal = __ballot(head == wkey);
      unsigned qm = (unsigned)((bal >> (q * 16)) & 0xFFFFull);
      int swin = __ffs((int)qm) - 1;
      flg = flg || ((qm & (qm - 1u)) != 0u);          // multi-owner tie
      u32 kb = __float_as_uint(wkey);
      int idx = (int)(((kb & 0xFFu) << 4) | (u32)swin);
      if (r < 16) { if (s == r) iA = idx; }
      else if (r < KNN) { if (s == r - 16) iB = idx; }
      if (r == KNN - 1) k20 = kb;
      if (r == KNN)     k21 = kb;
      bool own = (head == wkey) && (s == swin);
      #pragma unroll
      for (int jj = 0; jj < 7; ++jj) L[reg][jj] = own ? L[reg][jj + 1] : L[reg][jj];
      L[reg][7] = own ? FINF : L[reg][7];
    }
    flg = flg || ((k20 >> 8) == (k21 >> 8));          // boundary prefix tie
    u32 alive = (__float_as_uint(L[reg][0]) == __float_as_uint(FINF)) ? 0u : 1u;
    flg = flg || (rmin16u(alive) == 0u);              // drained lane
    size_t grow = (size_t)b * NPTS + r0 + w4 * 16 + q * 4 + reg;
    knn[grow * KNN + s] = iA;
    if (s < 4) knn[grow * KNN + 16 + s] = iB;
    if (s == 0 && flg) { int p = atomicAdd(cnt, 1); list[p] = (int)grow; }
  }
  #undef TSRC
}

// ---------------------------------------------------------------------------
// Exact fp32 brute-force for flagged rows (R7-R11-validated, unchanged).
// ---------------------------------------------------------------------------
__global__ __launch_bounds__(256) void fallback_knn(const float* __restrict__ x,
                                                    const float* __restrict__ sq,
                                                    const int* __restrict__ cnt,
                                                    const int* __restrict__ list,
                                                    int* __restrict__ knn) {
  __shared__ float xrl[CDIM];
  __shared__ u64 cand[4 * KNN];
  const int tid = threadIdx.x, lane = tid & 63, wv = tid >> 6;
  const int count = *cnt;

  for (int it = blockIdx.x; it < count; it += gridDim.x) {
    const int g = list[it];
    const int b = g >> 12, r = g & (NPTS - 1);
    const float* xb  = x  + (size_t)b * CDIM * NPTS;
    const float* sqb = sq + (size_t)b * NPTS;
    if (tid < CDIM) xrl[tid] = xb[(size_t)tid * NPTS + r];
    __syncthreads();
    const float sqr = sqb[r];

    u64 L[8];
    #pragma unroll
    for (int j = 0; j < 8; ++j) L[j] = SENT;
    #pragma unroll
    for (int ii = 0; ii < 4; ++ii) {
      const int i = wv * 4 + ii;
      float a0 = 0.f, a1 = 0.f, a2 = 0.f, a3 = 0.f;
      const float* xp = xb + i * 256 + lane * 4;
      #pragma unroll
      for (int c4 = 0; c4 < 16; ++c4) {
        float4 xr4 = *(const float4*)&xrl[c4 * 4];
        #pragma unroll
        for (int j = 0; j < 4; ++j) {
          float4 xv = *(const float4*)(xp + (size_t)(c4 * 4 + j) * NPTS);
          float xr = (&xr4.x)[j];
          a0 += xr * xv.x; a1 += xr * xv.y; a2 += xr * xv.z; a3 += xr * xv.w;
        }
      }
      int mb = i * 256 + lane * 4;
      float4 sv = *(const float4*)(sqb + mb);
      ins8u(L, ((u64)flip_f32(sqr + sv.x - 2.0f * a0) << 12) | (unsigned)mb);
      ins8u(L, ((u64)flip_f32(sqr + sv.y - 2.0f * a1) << 12) | (unsigned)(mb + 1));
      ins8u(L, ((u64)flip_f32(sqr + sv.z - 2.0f * a2) << 12) | (unsigned)(mb + 2));
      ins8u(L, ((u64)flip_f32(sqr + sv.w - 2.0f * a3) << 12) | (unsigned)(mb + 3));
    }

    u64 last = 0; bool done = false;
    for (int rr = 0; rr < KNN; ++rr) {
      bool need = (L[0] == SENT) && !done;
      if (__any(need)) {
        if (need) {                                  // never fires in practice
          #pragma unroll
          for (int j = 0; j < 8; ++j) L[j] = SENT;
          for (int ii = 0; ii < 4; ++ii) {
            const int i = wv * 4 + ii;
            float a0 = 0.f, a1 = 0.f, a2 = 0.f, a3 = 0.f;
            const float* xp = xb + i * 256 + lane * 4;
            #pragma unroll
            for (int c4 = 0; c4 < 16; ++c4) {
              float4 xr4 = *(const float4*)&xrl[c4 * 4];
              #pragma unroll
              for (int j = 0; j < 4; ++j) {
                float4 xv = *(const float4*)(xp + (size_t)(c4 * 4 + j) * NPTS);
                float xr = (&xr4.x)[j];
                a0 += xr * xv.x; a1 += xr * xv.y; a2 += xr * xv.z; a3 += xr * xv.w;
              }
            }
            int mb = i * 256 + lane * 4;
            float4 sv = *(const float4*)(sqb + mb);
            u64 v;
            v = ((u64)flip_f32(sqr + sv.x - 2.0f * a0) << 12) | (unsigned)mb;       ins8u(L, v > last ? v : SENT);
            v = ((u64)flip_f32(sqr + sv.y - 2.0f * a1) << 12) | (unsigned)(mb + 1); ins8u(L, v > last ? v : SENT);
            v = ((u64)flip_f32(sqr + sv.z - 2.0f * a2) << 12) | (unsigned)(mb + 2); ins8u(L, v > last ? v : SENT);
            v = ((u64)flip_f32(sqr + sv.w - 2.0f * a3) << 12) | (unsigned)(mb + 3); ins8u(L, v > last ? v : SENT);
          }
          if (L[0] == SENT) done = true;
        }
      }
      unsigned keyH = (unsigned)(L[0] >> 12);
      unsigned wkey = wave_min_u32(keyH);
      unsigned mc   = (keyH == wkey) ? (unsigned)(L[0] & 0xFFF) : 0xFFFFFFFFu;
      unsigned wm   = wave_min_u32(mc);
      u64 wsel = ((u64)wkey << 12) | wm;
      if (lane == rr) cand[wv * KNN + rr] = wsel;
      bool win = (L[0] == wsel);
      #pragma unroll
      for (int j = 0; j < 7; ++j) L[j] = win ? L[j + 1] : L[j];
      L[7] = win ? SENT : L[7];
      last = wsel;
    }
    __syncthreads();

    if (wv == 0) {                       // merge 80 candidates -> top 20
      u64 c0 = cand[lane < 4 * KNN ? lane : 0];
      if (lane >= 4 * KNN) c0 = SENT;
      u64 c1 = (lane < 4 * KNN - 64) ? cand[64 + lane] : SENT;
      int myidx = 0;
      for (int rr = 0; rr < KNN; ++rr) {
        u64 mn = c0 < c1 ? c0 : c1;
        unsigned keyH = (unsigned)(mn >> 12);
        unsigned wkey = wave_min_u32(keyH);
        unsigned mc   = (keyH == wkey) ? (unsigned)(mn & 0xFFF) : 0xFFFFFFFFu;
        unsigned wm   = wave_min_u32(mc);
        u64 wsel = ((u64)wkey << 12) | wm;
        if (lane == rr) myidx = (int)wm;
        if (c0 == wsel)      { c0 = c1; c1 = SENT; }
        else if (c1 == wsel) { c1 = SENT; }
      }
      if (lane < KNN) knn[(size_t)g * KNN + lane] = myidx;
    }
    __syncthreads();
  }
}

// ---------------------------------------------------------------------------
// a[b][n][o]  = sum_c (W[o][c]-W[o][c+64]) * x[b][c][n]
// cc[b][n][o] = sum_c  W[o][c+64]          * x[b][c][n]
// ---------------------------------------------------------------------------
__global__ __launch_bounds__(256) void proj_kernel(const float* __restrict__ x,
                                                   const float* __restrict__ w,
                                                   float* __restrict__ a,
                                                   float* __restrict__ cc) {
  __shared__ float wa[CDIM][ODIM];
  __shared__ float wc[CDIM][ODIM];
  const int tid = threadIdx.x;
  #pragma unroll
  for (int p = 0; p < 16; ++p) {
    int idx = p * 256 + tid;
    int o = idx & 63, c = idx >> 6;
    float w1 = w[o * 128 + c], w2 = w[o * 128 + 64 + c];
    wa[c][o] = w1 - w2;
    wc[c][o] = w2;
  }
  __syncthreads();

  const int og = tid >> 6;
  const int nl = tid & 63;
  const int g0 = blockIdx.x * 128;
  const int b  = g0 >> 12;
  const int n0 = g0 & (NPTS - 1);
  const float* xB = x + (size_t)b * CDIM * NPTS;

  float aa0[16], ac0[16], aa1[16], ac1[16];
  #pragma unroll
  for (int qq = 0; qq < 16; ++qq) { aa0[qq] = ac0[qq] = aa1[qq] = ac1[qq] = 0.f; }

  #pragma unroll 4
  for (int c = 0; c < CDIM; ++c) {
    float xv0 = xB[(size_t)c * NPTS + n0 + nl];
    float xv1 = xB[(size_t)c * NPTS + n0 + 64 + nl];
    #pragma unroll
    for (int q4 = 0; q4 < 4; ++q4) {
      float4 va = *(const float4*)&wa[c][og * 16 + q4 * 4];
      float4 vc = *(const float4*)&wc[c][og * 16 + q4 * 4];
      aa0[q4*4+0] += va.x * xv0; aa0[q4*4+1] += va.y * xv0;
      aa0[q4*4+2] += va.z * xv0; aa0[q4*4+3] += va.w * xv0;
      ac0[q4*4+0] += vc.x * xv0; ac0[q4*4+1] += vc.y * xv0;
      ac0[q4*4+2] += vc.z * xv0; ac0[q4*4+3] += vc.w * xv0;
      aa1[q4*4+0] += va.x * xv1; aa1[q4*4+1] += va.y * xv1;
      aa1[q4*4+2] += va.z * xv1; aa1[q4*4+3] += va.w * xv1;
      ac1[q4*4+0] += vc.x * xv1; ac1[q4*4+1] += vc.y * xv1;
      ac1[q4*4+2] += vc.z * xv1; ac1[q4*4+3] += vc.w * xv1;
    }
  }
  size_t ga0 = (size_t)(g0 + nl) * ODIM + og * 16;
  size_t ga1 = (size_t)(g0 + 64 + nl) * ODIM + og * 16;
  #pragma unroll
  for (int q4 = 0; q4 < 4; ++q4) {
    *(float4*)&a [ga0 + q4 * 4] = *(float4*)&aa0[q4 * 4];
    *(float4*)&cc[ga0 + q4 * 4] = *(float4*)&ac0[q4 * 4];
    *(float4*)&a [ga1 + q4 * 4] = *(float4*)&aa1[q4 * 4];
    *(float4*)&cc[ga1 + q4 * 4] = *(float4*)&ac1[q4 * 4];
  }
}

// ---------------------------------------------------------------------------
// out[b][o][n] = relu(inv[o] * max_k(a[b][n][o] + cc[b][knn[n][k]][o]) + bias[o])
// ---------------------------------------------------------------------------
__global__ __launch_bounds__(256) void out_kernel(const float* __restrict__ a,
                                                  const float* __restrict__ cc,
                                                  const int* __restrict__ knn,
                                                  const float* __restrict__ gamma,
                                                  const float* __restrict__ beta,
                                                  const float* __restrict__ mean,
                                                  const float* __restrict__ var,
                                                  float* __restrict__ out) {
  __shared__ float tile[64][65];
  const int tid = threadIdx.x, lane = tid & 63, wv = tid >> 6;
  const int b = blockIdx.y;
  const int n0 = blockIdx.x * 64;
  float inv  = gamma[lane] / sqrtf(var[lane] + 1e-5f);
  float bias = beta[lane] - mean[lane] * inv;
  for (int t = 0; t < 16; ++t) {
    int nl = wv * 16 + t;
    size_t base = (size_t)b * NPTS + (n0 + nl);
    float av = a[base * ODIM + lane];
    const int* kr = knn + base * KNN;
    float m = -INFINITY;
    #pragma unroll
    for (int k = 0; k < KNN; ++k) {
      int j = kr[k];
      float cv = cc[((size_t)b * NPTS + j) * ODIM + lane];
      m = fmaxf(m, av + cv);
    }
    float v = m * inv + bias;
    tile[nl][lane] = v > 0.f ? v : 0.f;
  }
  __syncthreads();
  for (int t = 0; t < 16; ++t) {
    int o = wv * 16 + t;
    out[((size_t)b * ODIM + o) * NPTS + n0 + lane] = tile[lane][o];
  }
}

// ---------------------------------------------------------------------------
extern "C" void kernel_launch(void* const* d_in, const int* in_sizes, int n_in,
                              void* d_out, int out_size, void* d_ws, size_t ws_size,
                              hipStream_t stream) {
  const float* x     = (const float*)d_in[0];
  const float* w     = (const float*)d_in[1];
  const float* gamma = (const float*)d_in[2];
  const float* beta  = (const float*)d_in[3];
  const float* mean  = (const float*)d_in[4];
  const float* var   = (const float*)d_in[5];
  float* out = (float*)d_out;

  char* wsb = (char*)d_ws;
  size_t off = 0;
  int*   knn   = (int*)(wsb + off);   off += (size_t)BDIM * NPTS * KNN * 4;   // 2.62 MB
  int*   list  = (int*)(wsb + off);   off += (size_t)BDIM * NPTS * 4;         // 0.13 MB
  int*   cnt   = (int*)(wsb + off);   off += 256;
  float* sqw   = (float*)(wsb + off); off += (size_t)BDIM * NPTS * 4;         // 0.13 MB
  float* sqp   = (float*)(wsb + off); off += (size_t)BDIM * NPTS * 4;         // 0.13 MB
  float* a     = (float*)(wsb + off); off += (size_t)BDIM * NPTS * ODIM * 4;  // 8 MB
  float* cc    = (float*)(wsb + off); off += (size_t)BDIM * NPTS * ODIM * 4;  // 8 MB
  char*  img   = wsb + off;           off += (size_t)BDIM * NT128 * 32768;    // 8 MB
  (void)ws_size;

  prep_kernel <<<BDIM * NT128, 256, 0, stream>>>(x, img);
  sq_kernel   <<<BDIM * NPTS / 256, 256, 0, stream>>>(x, sqw, sqp, cnt);
  proj_kernel <<<BDIM * NPTS / 128, 256, 0, stream>>>(x, w, a, cc);
  fused_knn   <<<512, 512, 0, stream>>>(img, sqw, sqp, knn, list, cnt);
  fallback_knn<<<2048, 256, 0, stream>>>(x, sqw, cnt, list, knn);
  out_kernel  <<<dim3(NPTS / 64, BDIM), 256, 0, stream>>>(a, cc, knn, gamma, beta,
                                                          mean, var, out);
}

// Round 13
// 209.648 us; speedup vs baseline: 6.3039x; 1.2707x over previous
//
#include <hip/hip_runtime.h>
#include <cstdint>
#include <cstddef>

#define NPTS 4096
#define CDIM 64
#define BDIM 8
#define KNN  20
#define ODIM 64
#define NT128 32          // 128-col tile images per batch (img layout)
#define NT64  64          // 64-col compute tiles per batch (fused)

typedef unsigned long long u64;
typedef unsigned int u32;
typedef _Float16 f16;
using f16x8 = __attribute__((ext_vector_type(8))) _Float16;
using f32x4 = __attribute__((ext_vector_type(4))) float;
#define SENT   (~0ull)
#define FINF (__builtin_inff())

__device__ __forceinline__ int swz(int r) { return (r & 7) ^ ((r >> 3) & 7); }

// order-preserving float->u32 flip (ascending float == ascending u32)
__device__ __forceinline__ unsigned flip_f32(float d) {
  unsigned bits = __float_as_uint(d);
  return bits ^ (unsigned)(((int)bits >> 31) | 0x80000000u);
}

// wave64 all-reduce min (DPP), uniform via readlane 63  (R3-validated)
__device__ __forceinline__ unsigned wave_min_u32(unsigned v) {
  unsigned t;
  t = (unsigned)__builtin_amdgcn_update_dpp((int)v, (int)v, 0x111, 0xF, 0xF, false); v = t < v ? t : v;
  t = (unsigned)__builtin_amdgcn_update_dpp((int)v, (int)v, 0x112, 0xF, 0xF, false); v = t < v ? t : v;
  t = (unsigned)__builtin_amdgcn_update_dpp((int)v, (int)v, 0x114, 0xF, 0xF, false); v = t < v ? t : v;
  t = (unsigned)__builtin_amdgcn_update_dpp((int)v, (int)v, 0x118, 0xF, 0xF, false); v = t < v ? t : v;
  t = (unsigned)__builtin_amdgcn_update_dpp((int)v, (int)v, 0x142, 0xA, 0xF, false); v = t < v ? t : v;
  t = (unsigned)__builtin_amdgcn_update_dpp((int)v, (int)v, 0x143, 0xC, 0xF, false); v = t < v ? t : v;
  return (unsigned)__builtin_amdgcn_readlane((int)v, 63);
}

// 16-lane all-reduce min, float (quad xor1, xor2, row_ror4, row_ror8)
__device__ __forceinline__ float rmin16f(float v) {
  int t;
  t = __builtin_amdgcn_update_dpp(__float_as_int(v), __float_as_int(v), 0xB1,  0xF, 0xF, false);
  v = fminf(v, __int_as_float(t));
  t = __builtin_amdgcn_update_dpp(__float_as_int(v), __float_as_int(v), 0x4E,  0xF, 0xF, false);
  v = fminf(v, __int_as_float(t));
  t = __builtin_amdgcn_update_dpp(__float_as_int(v), __float_as_int(v), 0x124, 0xF, 0xF, false);
  v = fminf(v, __int_as_float(t));
  t = __builtin_amdgcn_update_dpp(__float_as_int(v), __float_as_int(v), 0x128, 0xF, 0xF, false);
  v = fminf(v, __int_as_float(t));
  return v;
}
__device__ __forceinline__ u32 rmin16u(u32 v) {
  int t;
  t = __builtin_amdgcn_update_dpp((int)v, (int)v, 0xB1,  0xF, 0xF, false); v = ((u32)t < v) ? (u32)t : v;
  t = __builtin_amdgcn_update_dpp((int)v, (int)v, 0x4E,  0xF, 0xF, false); v = ((u32)t < v) ? (u32)t : v;
  t = __builtin_amdgcn_update_dpp((int)v, (int)v, 0x124, 0xF, 0xF, false); v = ((u32)t < v) ? (u32)t : v;
  t = __builtin_amdgcn_update_dpp((int)v, (int)v, 0x128, 0xF, 0xF, false); v = ((u32)t < v) ? (u32)t : v;
  return v;
}

// med3 insertion into ascending sorted-8 (8 independent ops, drops max)
__device__ __forceinline__ void insert_med3(float (&Lr)[8], float key) {
  Lr[7] = __builtin_amdgcn_fmed3f(key, Lr[6], Lr[7]);
  Lr[6] = __builtin_amdgcn_fmed3f(key, Lr[5], Lr[6]);
  Lr[5] = __builtin_amdgcn_fmed3f(key, Lr[4], Lr[5]);
  Lr[4] = __builtin_amdgcn_fmed3f(key, Lr[3], Lr[4]);
  Lr[3] = __builtin_amdgcn_fmed3f(key, Lr[2], Lr[3]);
  Lr[2] = __builtin_amdgcn_fmed3f(key, Lr[1], Lr[2]);
  Lr[1] = __builtin_amdgcn_fmed3f(key, Lr[0], Lr[1]);
  Lr[0] = fminf(key, Lr[0]);
}

// branchless insert into ascending sorted-8 of u64 keys (bubble, drops max)
__device__ __forceinline__ void ins8u(u64 (&L)[8], u64 v) {
  u64 c = v;
  #pragma unroll
  for (int j = 0; j < 8; ++j) {
    u64 lo = c < L[j] ? c : L[j];
    u64 hi = c < L[j] ? L[j] : c;
    L[j] = lo; c = hi;
  }
}

// async global->LDS, 16B per lane; LDS dest is wave-uniform base + lane*16
__device__ __forceinline__ void gl16(const char* g, char* l) {
  __builtin_amdgcn_global_load_lds(
      (const __attribute__((address_space(1))) unsigned int*)g,
      (__attribute__((address_space(3))) unsigned int*)l, 16, 0, 0);
}
// stage one 64-col tile (hi 8KB + lo 8KB) into a 16KB LDS buffer (256 thr)
__device__ __forceinline__ void stage64(const char* src_hi, char* dst, int t256) {
  const int w = t256 >> 6, lane = t256 & 63;
  const int off = w * 2048 + (lane << 4);
  gl16(src_hi + off,                 dst + w * 2048);
  gl16(src_hi + off + 1024,          dst + w * 2048 + 1024);
  gl16(src_hi + 16384 + off,         dst + 8192 + w * 2048);
  gl16(src_hi + 16384 + off + 1024,  dst + 8192 + w * 2048 + 1024);
}

// ---------------------------------------------------------------------------
// pre: ONE pass over x per 64-n segment (512 blocks, 2/CU):
//  - sq (ascending-c, one thread per n — BIT-IDENTICAL to R3-R12) + sqp + cnt=0
//  - fp16 hi/lo img bytes (identical swizzled layout to prep_kernel)
//  - proj a/cc (identical fma order to proj_kernel)
// ---------------------------------------------------------------------------
__global__ __launch_bounds__(256) void pre_kernel(const float* __restrict__ x,
                                                  const float* __restrict__ w,
                                                  float* __restrict__ sq,
                                                  float* __restrict__ sqp,
                                                  float* __restrict__ a,
                                                  float* __restrict__ cc,
                                                  char* __restrict__ img,
                                                  int* __restrict__ cnt) {
  __shared__ float xs[CDIM][64];     // 16KB [c][n']
  __shared__ float wa[CDIM][ODIM];   // 16KB
  __shared__ float wc[CDIM][ODIM];   // 16KB
  __shared__ char  limg[16384];      // 16KB (hi 8K + lo 8K for these 64 n)

  const int tid = threadIdx.x;
  const int blk = blockIdx.x;
  const int b = blk >> 6, seg = blk & 63;
  const int n0 = seg * 64;
  if (blk == 0 && tid == 0) *cnt = 0;

  const float* xb = x + (size_t)b * CDIM * NPTS;
  #pragma unroll
  for (int p = 0; p < 16; ++p) {
    int idx = p * 256 + tid;                 // 0..4095
    int c = idx >> 6, n = idx & 63;
    xs[c][n] = xb[(size_t)c * NPTS + n0 + n];
  }
  #pragma unroll
  for (int p = 0; p < 16; ++p) {
    int idx = p * 256 + tid;
    int o = idx & 63, c = idx >> 6;
    float w1 = w[o * 128 + c], w2 = w[o * 128 + 64 + c];
    wa[c][o] = w1 - w2;
    wc[c][o] = w2;
  }
  __syncthreads();

  // sq: ascending c per n, single thread per n (bit-identical)
  if (tid < 64) {
    float s = 0.f;
    #pragma unroll
    for (int c = 0; c < CDIM; ++c) { float v = xs[c][tid]; s += v * v; }
    int n = n0 + tid;
    sq[b * NPTS + n] = s;
    int t = n >> 6, j0 = n & 63;
    sqp[(((size_t)b * NT64 + t) * 16 + (j0 & 15)) * 4 + (j0 >> 4)] = s;
  }

  // proj: identical per-o accumulation order as R12's proj_kernel
  {
    const int og = tid >> 6, nl = tid & 63;
    float aa[16], ac[16];
    #pragma unroll
    for (int qq = 0; qq < 16; ++qq) { aa[qq] = ac[qq] = 0.f; }
    #pragma unroll 4
    for (int c = 0; c < CDIM; ++c) {
      float xv = xs[c][nl];
      #pragma unroll
      for (int q4 = 0; q4 < 4; ++q4) {
        float4 va = *(const float4*)&wa[c][og * 16 + q4 * 4];
        float4 vc = *(const float4*)&wc[c][og * 16 + q4 * 4];
        aa[q4*4+0] += va.x * xv; aa[q4*4+1] += va.y * xv;
        aa[q4*4+2] += va.z * xv; aa[q4*4+3] += va.w * xv;
        ac[q4*4+0] += vc.x * xv; ac[q4*4+1] += vc.y * xv;
        ac[q4*4+2] += vc.z * xv; ac[q4*4+3] += vc.w * xv;
      }
    }
    size_t ga = (size_t)(b * NPTS + n0 + nl) * ODIM + og * 16;
    #pragma unroll
    for (int q4 = 0; q4 < 4; ++q4) {
      *(float4*)&a [ga + q4 * 4] = *(float4*)&aa[q4 * 4];
      *(float4*)&cc[ga + q4 * 4] = *(float4*)&ac[q4 * 4];
    }
  }

  // img: identical bytes/layout to R12 prep (np128 = (seg&1)*64 + npl)
  {
    const int npl = tid & 63;
    const int half = tid >> 6;                // c-base half*16
    const int np128 = (seg & 1) * 64 + npl;
    const int sw = swz(np128) << 4;
    #pragma unroll
    for (int oct = 0; oct < 2; ++oct) {
      const int cb = half * 16 + oct * 8;
      f16x8 hv, lv;
      #pragma unroll
      for (int j = 0; j < 8; ++j) {
        float v = xs[cb + j][npl];
        f16 h = (f16)v;
        hv[j] = h;
        lv[j] = (f16)(v - (float)h);
      }
      int byt = (npl * 128 + cb * 2) ^ sw;    // within this 8KB half
      *(f16x8*)(limg + byt) = hv;
      *(f16x8*)(limg + 8192 + byt) = lv;
    }
  }
  __syncthreads();
  {
    char* dstbase = img + ((size_t)b * NT128 + (seg >> 1)) * 32768
                        + (size_t)(seg & 1) * 8192;
    #pragma unroll
    for (int i = 0; i < 2; ++i) {
      *(float4*)(dstbase + i * 4096 + tid * 16) =
          *(const float4*)(limg + i * 4096 + tid * 16);
      *(float4*)(dstbase + 16384 + i * 4096 + tid * 16) =
          *(const float4*)(limg + 8192 + i * 4096 + tid * 16);
    }
  }
}

// ---------------------------------------------------------------------------
// Fused dist+top20+OUT. Sweep/selection/certificate BYTE-IDENTICAL to R12.
// New: knn also kept in LDS (kbuf); after pops all 8 waves compute the
// 64-row out tile (a + 20 cc-gathers + BN/ReLU, LDS transpose, coalesced
// writes). Flagged rows' out is preliminary; fallback rewrites it.
// ---------------------------------------------------------------------------
__global__ __launch_bounds__(512, 2) void fused_knn(const char* __restrict__ img,
                                                    const float* __restrict__ sq,
                                                    const float* __restrict__ sqp,
                                                    int* __restrict__ knn,
                                                    int* __restrict__ list,
                                                    int* __restrict__ cnt,
                                                    const float* __restrict__ pa,
                                                    const float* __restrict__ pcc,
                                                    const float* __restrict__ gamma,
                                                    const float* __restrict__ beta,
                                                    const float* __restrict__ mean,
                                                    const float* __restrict__ var,
                                                    float* __restrict__ pout) {
  __shared__ char XB[2][2][16384];     // [grp][dbuf] — 64 KB

  const int tid  = threadIdx.x;
  const int grp  = tid >> 8;           // 0: tiles 0-31, 1: tiles 32-63
  const int t256 = tid & 255;
  const int lane = tid & 63;
  const int w4   = t256 >> 6;          // wave within group (0..3)
  const int q = lane >> 4;
  const int s = lane & 15;

  const int blk = blockIdx.x;
  const int b  = blk >> 6;
  const int r0 = (blk & 63) * 64;
  const char* imgb = img + (size_t)b * (NT128 * 32768);
  const float* sqb = sq + (size_t)b * NPTS;
  const float4* sqp4 = (const float4*)(sqp + (size_t)b * NT64 * 64);

  const int tb = grp * 32;             // group tile base
  #define TSRC(tile) (imgb + (size_t)((tile) >> 1) * 32768 + (size_t)((tile) & 1) * 8192)

  stage64(TSRC(tb), XB[grp][0], t256);   // group's tile 0

  f16x8 Ah[2], Al[2];
  {
    const int grow = r0 + w4 * 16 + s;
    const char* at = imgb + (size_t)(grow >> 7) * 32768;
    const int nn = grow & 127;
    const int swn = swz(nn) << 4;
    #pragma unroll
    for (int ks = 0; ks < 2; ++ks) {
      int byt = (nn * 128 + (ks * 32 + q * 8) * 2) ^ swn;
      Ah[ks] = *(const f16x8*)(at + byt);
      Al[ks] = *(const f16x8*)(at + 16384 + byt);
    }
  }

  float sqr[4];
  #pragma unroll
  for (int reg = 0; reg < 4; ++reg) sqr[reg] = sqb[r0 + w4 * 16 + q * 4 + reg];

  float L[4][8];
  #pragma unroll
  for (int reg = 0; reg < 4; ++reg)
    #pragma unroll
    for (int j = 0; j < 8; ++j) L[reg][j] = FINF;

  __syncthreads();                 // tile-0 staging drained (both groups)

  for (int t = 0; t < 32; ++t) {
    #pragma unroll
    for (int reg = 0; reg < 4; ++reg)
      #pragma unroll
      for (int jj = 0; jj < 8; ++jj)
        asm volatile("" : "+v"(L[reg][jj]));

    if (t + 1 < 32)
      stage64(TSRC(tb + t + 1), XB[grp][(t + 1) & 1], t256);
    const char* XBc = XB[grp][t & 1];
    const int tile = tb + t;
    const float4 sm4 = sqp4[tile * 16 + s];   // sq[tile*64 + e*16 + s]
    #pragma unroll
    for (int e = 0; e < 4; ++e) {
      const int j = e * 16 + s;
      const int swj = swz(j) << 4;
      f32x4 acc = {0.f, 0.f, 0.f, 0.f};
      #pragma unroll
      for (int ks = 0; ks < 2; ++ks) {
        int byt = (j * 128 + (ks * 32 + q * 8) * 2) ^ swj;
        f16x8 Bh = *(const f16x8*)(XBc + byt);
        f16x8 Bl = *(const f16x8*)(XBc + 8192 + byt);
        acc = __builtin_amdgcn_mfma_f32_16x16x32_f16(Ah[ks], Bh, acc, 0, 0, 0);
        acc = __builtin_amdgcn_mfma_f32_16x16x32_f16(Ah[ks], Bl, acc, 0, 0, 0);
        acc = __builtin_amdgcn_mfma_f32_16x16x32_f16(Al[ks], Bh, acc, 0, 0, 0);
      }
      asm volatile("" : "+v"(acc));
      const float sm = (&sm4.x)[e];
      const u32 klo = (u32)(tile * 4 + e);    // = mcol >> 4
      #pragma unroll
      for (int reg = 0; reg < 4; ++reg) {
        float v = (sqr[reg] + sm) - 2.0f * acc[reg];   // same expr as R4-R12
        float key = __uint_as_float((__float_as_uint(v) & 0xFFFFFF00u) | klo);
        insert_med3(L[reg], key);
      }
    }
    __syncthreads();
  }

  // merge: group-1 dumps lists; group-0 merges (exact union top-8)
  float* mbuf = (float*)XB;              // [0, 32768)
  int*   kbuf = (int*)((char*)XB + 32768);          // 64 x 20 ints
  float* tile = (float*)((char*)XB + 40960);        // 64 x 65 floats
  if (grp == 1) {
    #pragma unroll
    for (int reg = 0; reg < 4; ++reg)
      #pragma unroll
      for (int j = 0; j < 8; ++j)
        mbuf[((reg * 8 + j) * 4 + w4) * 64 + lane] = L[reg][j];
  }
  __syncthreads();

  if (grp == 0) {
    #pragma unroll
    for (int reg = 0; reg < 4; ++reg)
      #pragma unroll
      for (int j = 0; j < 8; ++j)
        insert_med3(L[reg], mbuf[((reg * 8 + j) * 4 + w4) * 64 + lane]);

    // pops: 21 rounds per row; certificates identical to R12
    #pragma unroll
    for (int reg = 0; reg < 4; ++reg) {
      bool flg = false;
      int iA = 0, iB = 0;
      u32 k20 = 0, k21 = 0;
      for (int r = 0; r < KNN + 1; ++r) {
        float head = L[reg][0];
        float wkey = rmin16f(head);
        unsigned long long bal = __ballot(head == wkey);
        unsigned qm = (unsigned)((bal >> (q * 16)) & 0xFFFFull);
        int swin = __ffs((int)qm) - 1;
        flg = flg || ((qm & (qm - 1u)) != 0u);
        u32 kb = __float_as_uint(wkey);
        int idx = (int)(((kb & 0xFFu) << 4) | (u32)swin);
        if (r < 16) { if (s == r) iA = idx; }
        else if (r < KNN) { if (s == r - 16) iB = idx; }
        if (r == KNN - 1) k20 = kb;
        if (r == KNN)     k21 = kb;
        bool own = (head == wkey) && (s == swin);
        #pragma unroll
        for (int jj = 0; jj < 7; ++jj) L[reg][jj] = own ? L[reg][jj + 1] : L[reg][jj];
        L[reg][7] = own ? FINF : L[reg][7];
      }
      flg = flg || ((k20 >> 8) == (k21 >> 8));
      u32 alive = (__float_as_uint(L[reg][0]) == __float_as_uint(FINF)) ? 0u : 1u;
      flg = flg || (rmin16u(alive) == 0u);
      const int lrow = w4 * 16 + q * 4 + reg;
      size_t grow = (size_t)b * NPTS + r0 + lrow;
      knn[grow * KNN + s] = iA;
      kbuf[lrow * KNN + s] = iA;
      if (s < 4) { knn[grow * KNN + 16 + s] = iB; kbuf[lrow * KNN + 16 + s] = iB; }
      if (s == 0 && flg) { int p = atomicAdd(cnt, 1); list[p] = (int)grow; }
    }
  }
  __syncthreads();

  // inline out: all 8 waves, 8 rows each
  {
    const int wv8 = tid >> 6;
    float inv  = gamma[lane] / sqrtf(var[lane] + 1e-5f);
    float bias = beta[lane] - mean[lane] * inv;
    for (int rr = 0; rr < 8; ++rr) {
      int row = wv8 * 8 + rr;
      size_t base = (size_t)b * NPTS + r0 + row;
      float av = pa[base * ODIM + lane];
      const int* kr = kbuf + row * KNN;
      float m = -INFINITY;
      #pragma unroll
      for (int k = 0; k < KNN; ++k) {
        int jj = kr[k];
        m = fmaxf(m, av + pcc[((size_t)b * NPTS + jj) * ODIM + lane]);
      }
      float v = m * inv + bias;
      tile[row * 65 + lane] = v > 0.f ? v : 0.f;
    }
  }
  __syncthreads();
  #pragma unroll
  for (int t8 = 0; t8 < 8; ++t8) {
    int o = (tid >> 6) * 8 + t8;
    pout[((size_t)b * ODIM + o) * NPTS + r0 + lane] = tile[lane * 65 + o];
  }
  #undef TSRC
}

// ---------------------------------------------------------------------------
// Exact fp32 brute-force for flagged rows (R7-R12-validated) + out fixup.
// ---------------------------------------------------------------------------
__global__ __launch_bounds__(256) void fallback_knn(const float* __restrict__ x,
                                                    const float* __restrict__ sq,
                                                    const int* __restrict__ cnt,
                                                    const int* __restrict__ list,
                                                    int* __restrict__ knn,
                                                    const float* __restrict__ pa,
                                                    const float* __restrict__ pcc,
                                                    const float* __restrict__ gamma,
                                                    const float* __restrict__ beta,
                                                    const float* __restrict__ mean,
                                                    const float* __restrict__ var,
                                                    float* __restrict__ pout) {
  __shared__ float xrl[CDIM];
  __shared__ u64 cand[4 * KNN];
  __shared__ int kfix[KNN];
  const int tid = threadIdx.x, lane = tid & 63, wv = tid >> 6;
  const int count = *cnt;

  for (int it = blockIdx.x; it < count; it += gridDim.x) {
    const int g = list[it];
    const int b = g >> 12, r = g & (NPTS - 1);
    const float* xb  = x  + (size_t)b * CDIM * NPTS;
    const float* sqb = sq + (size_t)b * NPTS;
    if (tid < CDIM) xrl[tid] = xb[(size_t)tid * NPTS + r];
    __syncthreads();
    const float sqr = sqb[r];

    u64 L[8];
    #pragma unroll
    for (int j = 0; j < 8; ++j) L[j] = SENT;
    #pragma unroll
    for (int ii = 0; ii < 4; ++ii) {
      const int i = wv * 4 + ii;
      float a0 = 0.f, a1 = 0.f, a2 = 0.f, a3 = 0.f;
      const float* xp = xb + i * 256 + lane * 4;
      #pragma unroll
      for (int c4 = 0; c4 < 16; ++c4) {
        float4 xr4 = *(const float4*)&xrl[c4 * 4];
        #pragma unroll
        for (int j = 0; j < 4; ++j) {
          float4 xv = *(const float4*)(xp + (size_t)(c4 * 4 + j) * NPTS);
          float xr = (&xr4.x)[j];
          a0 += xr * xv.x; a1 += xr * xv.y; a2 += xr * xv.z; a3 += xr * xv.w;
        }
      }
      int mb = i * 256 + lane * 4;
      float4 sv = *(const float4*)(sqb + mb);
      ins8u(L, ((u64)flip_f32(sqr + sv.x - 2.0f * a0) << 12) | (unsigned)mb);
      ins8u(L, ((u64)flip_f32(sqr + sv.y - 2.0f * a1) << 12) | (unsigned)(mb + 1));
      ins8u(L, ((u64)flip_f32(sqr + sv.z - 2.0f * a2) << 12) | (unsigned)(mb + 2));
      ins8u(L, ((u64)flip_f32(sqr + sv.w - 2.0f * a3) << 12) | (unsigned)(mb + 3));
    }

    u64 last = 0; bool done = false;
    for (int rr = 0; rr < KNN; ++rr) {
      bool need = (L[0] == SENT) && !done;
      if (__any(need)) {
        if (need) {
          #pragma unroll
          for (int j = 0; j < 8; ++j) L[j] = SENT;
          for (int ii = 0; ii < 4; ++ii) {
            const int i = wv * 4 + ii;
            float a0 = 0.f, a1 = 0.f, a2 = 0.f, a3 = 0.f;
            const float* xp = xb + i * 256 + lane * 4;
            #pragma unroll
            for (int c4 = 0; c4 < 16; ++c4) {
              float4 xr4 = *(const float4*)&xrl[c4 * 4];
              #pragma unroll
              for (int j = 0; j < 4; ++j) {
                float4 xv = *(const float4*)(xp + (size_t)(c4 * 4 + j) * NPTS);
                float xr = (&xr4.x)[j];
                a0 += xr * xv.x; a1 += xr * xv.y; a2 += xr * xv.z; a3 += xr * xv.w;
              }
            }
            int mb = i * 256 + lane * 4;
            float4 sv = *(const float4*)(sqb + mb);
            u64 v;
            v = ((u64)flip_f32(sqr + sv.x - 2.0f * a0) << 12) | (unsigned)mb;       ins8u(L, v > last ? v : SENT);
            v = ((u64)flip_f32(sqr + sv.y - 2.0f * a1) << 12) | (unsigned)(mb + 1); ins8u(L, v > last ? v : SENT);
            v = ((u64)flip_f32(sqr + sv.z - 2.0f * a2) << 12) | (unsigned)(mb + 2); ins8u(L, v > last ? v : SENT);
            v = ((u64)flip_f32(sqr + sv.w - 2.0f * a3) << 12) | (unsigned)(mb + 3); ins8u(L, v > last ? v : SENT);
          }
          if (L[0] == SENT) done = true;
        }
      }
      unsigned keyH = (unsigned)(L[0] >> 12);
      unsigned wkey = wave_min_u32(keyH);
      unsigned mc   = (keyH == wkey) ? (unsigned)(L[0] & 0xFFF) : 0xFFFFFFFFu;
      unsigned wm   = wave_min_u32(mc);
      u64 wsel = ((u64)wkey << 12) | wm;
      if (lane == rr) cand[wv * KNN + rr] = wsel;
      bool win = (L[0] == wsel);
      #pragma unroll
      for (int j = 0; j < 7; ++j) L[j] = win ? L[j + 1] : L[j];
      L[7] = win ? SENT : L[7];
      last = wsel;
    }
    __syncthreads();

    if (wv == 0) {                       // merge 80 candidates -> top 20
      u64 c0 = cand[lane < 4 * KNN ? lane : 0];
      if (lane >= 4 * KNN) c0 = SENT;
      u64 c1 = (lane < 4 * KNN - 64) ? cand[64 + lane] : SENT;
      int myidx = 0;
      for (int rr = 0; rr < KNN; ++rr) {
        u64 mn = c0 < c1 ? c0 : c1;
        unsigned keyH = (unsigned)(mn >> 12);
        unsigned wkey = wave_min_u32(keyH);
        unsigned mc   = (keyH == wkey) ? (unsigned)(mn & 0xFFF) : 0xFFFFFFFFu;
        unsigned wm   = wave_min_u32(mc);
        u64 wsel = ((u64)wkey << 12) | wm;
        if (lane == rr) myidx = (int)wm;
        if (c0 == wsel)      { c0 = c1; c1 = SENT; }
        else if (c1 == wsel) { c1 = SENT; }
      }
      if (lane < KNN) {
        knn[(size_t)g * KNN + lane] = myidx;
        kfix[lane] = myidx;
      }
    }
    __syncthreads();

    if (wv == 0) {                       // out fixup for this row (lane = o)
      float inv  = gamma[lane] / sqrtf(var[lane] + 1e-5f);
      float bias = beta[lane] - mean[lane] * inv;
      float av = pa[(size_t)g * ODIM + lane];
      float m = -INFINITY;
      #pragma unroll
      for (int k = 0; k < KNN; ++k) {
        int jj = kfix[k];
        m = fmaxf(m, av + pcc[((size_t)b * NPTS + jj) * ODIM + lane]);
      }
      float v = m * inv + bias;
      pout[((size_t)b * ODIM + lane) * NPTS + r] = v > 0.f ? v : 0.f;
    }
    __syncthreads();
  }
}

// ---------------------------------------------------------------------------
extern "C" void kernel_launch(void* const* d_in, const int* in_sizes, int n_in,
                              void* d_out, int out_size, void* d_ws, size_t ws_size,
                              hipStream_t stream) {
  const float* x     = (const float*)d_in[0];
  const float* w     = (const float*)d_in[1];
  const float* gamma = (const float*)d_in[2];
  const float* beta  = (const float*)d_in[3];
  const float* mean  = (const float*)d_in[4];
  const float* var   = (const float*)d_in[5];
  float* out = (float*)d_out;

  char* wsb = (char*)d_ws;
  size_t off = 0;
  int*   knn   = (int*)(wsb + off);   off += (size_t)BDIM * NPTS * KNN * 4;   // 2.62 MB
  int*   list  = (int*)(wsb + off);   off += (size_t)BDIM * NPTS * 4;         // 0.13 MB
  int*   cnt   = (int*)(wsb + off);   off += 256;
  float* sqw   = (float*)(wsb + off); off += (size_t)BDIM * NPTS * 4;         // 0.13 MB
  float* sqp   = (float*)(wsb + off); off += (size_t)BDIM * NPTS * 4;         // 0.13 MB
  float* a     = (float*)(wsb + off); off += (size_t)BDIM * NPTS * ODIM * 4;  // 8 MB
  float* cc    = (float*)(wsb + off); off += (size_t)BDIM * NPTS * ODIM * 4;  // 8 MB
  char*  img   = wsb + off;           off += (size_t)BDIM * NT128 * 32768;    // 8 MB
  (void)ws_size;

  pre_kernel  <<<BDIM * NPTS / 64, 256, 0, stream>>>(x, w, sqw, sqp, a, cc, img, cnt);
  fused_knn   <<<512, 512, 0, stream>>>(img, sqw, sqp, knn, list, cnt,
                                        a, cc, gamma, beta, mean, var, out);
  fallback_knn<<<2048, 256, 0, stream>>>(x, sqw, cnt, list, knn,
                                         a, cc, gamma, beta, mean, var, out);
}

// Round 14
// 209.460 us; speedup vs baseline: 6.3096x; 1.0009x over previous
//
#include <hip/hip_runtime.h>
#include <cstdint>
#include <cstddef>

#define NPTS 4096
#define CDIM 64
#define BDIM 8
#define KNN  20
#define ODIM 64
#define NT128 32          // 128-col tile images per batch (img layout)
#define NT64  64          // 64-col compute tiles per batch (fused)

typedef unsigned long long u64;
typedef unsigned int u32;
typedef _Float16 f16;
using f16x8 = __attribute__((ext_vector_type(8))) _Float16;
using f32x4 = __attribute__((ext_vector_type(4))) float;
#define SENT   (~0ull)
#define FINF (__builtin_inff())

__device__ __forceinline__ int swz(int r) { return (r & 7) ^ ((r >> 3) & 7); }

// order-preserving float->u32 flip (ascending float == ascending u32)
__device__ __forceinline__ unsigned flip_f32(float d) {
  unsigned bits = __float_as_uint(d);
  return bits ^ (unsigned)(((int)bits >> 31) | 0x80000000u);
}

// wave64 all-reduce min (DPP), uniform via readlane 63  (R3-validated)
__device__ __forceinline__ unsigned wave_min_u32(unsigned v) {
  unsigned t;
  t = (unsigned)__builtin_amdgcn_update_dpp((int)v, (int)v, 0x111, 0xF, 0xF, false); v = t < v ? t : v;
  t = (unsigned)__builtin_amdgcn_update_dpp((int)v, (int)v, 0x112, 0xF, 0xF, false); v = t < v ? t : v;
  t = (unsigned)__builtin_amdgcn_update_dpp((int)v, (int)v, 0x114, 0xF, 0xF, false); v = t < v ? t : v;
  t = (unsigned)__builtin_amdgcn_update_dpp((int)v, (int)v, 0x118, 0xF, 0xF, false); v = t < v ? t : v;
  t = (unsigned)__builtin_amdgcn_update_dpp((int)v, (int)v, 0x142, 0xA, 0xF, false); v = t < v ? t : v;
  t = (unsigned)__builtin_amdgcn_update_dpp((int)v, (int)v, 0x143, 0xC, 0xF, false); v = t < v ? t : v;
  return (unsigned)__builtin_amdgcn_readlane((int)v, 63);
}

// 16-lane all-reduce min, float (quad xor1, xor2, row_ror4, row_ror8)
__device__ __forceinline__ float rmin16f(float v) {
  int t;
  t = __builtin_amdgcn_update_dpp(__float_as_int(v), __float_as_int(v), 0xB1,  0xF, 0xF, false);
  v = fminf(v, __int_as_float(t));
  t = __builtin_amdgcn_update_dpp(__float_as_int(v), __float_as_int(v), 0x4E,  0xF, 0xF, false);
  v = fminf(v, __int_as_float(t));
  t = __builtin_amdgcn_update_dpp(__float_as_int(v), __float_as_int(v), 0x124, 0xF, 0xF, false);
  v = fminf(v, __int_as_float(t));
  t = __builtin_amdgcn_update_dpp(__float_as_int(v), __float_as_int(v), 0x128, 0xF, 0xF, false);
  v = fminf(v, __int_as_float(t));
  return v;
}
__device__ __forceinline__ u32 rmin16u(u32 v) {
  int t;
  t = __builtin_amdgcn_update_dpp((int)v, (int)v, 0xB1,  0xF, 0xF, false); v = ((u32)t < v) ? (u32)t : v;
  t = __builtin_amdgcn_update_dpp((int)v, (int)v, 0x4E,  0xF, 0xF, false); v = ((u32)t < v) ? (u32)t : v;
  t = __builtin_amdgcn_update_dpp((int)v, (int)v, 0x124, 0xF, 0xF, false); v = ((u32)t < v) ? (u32)t : v;
  t = __builtin_amdgcn_update_dpp((int)v, (int)v, 0x128, 0xF, 0xF, false); v = ((u32)t < v) ? (u32)t : v;
  return v;
}

// med3 insertion into ascending sorted-8 (8 independent ops, drops max)
__device__ __forceinline__ void insert_med3(float (&Lr)[8], float key) {
  Lr[7] = __builtin_amdgcn_fmed3f(key, Lr[6], Lr[7]);
  Lr[6] = __builtin_amdgcn_fmed3f(key, Lr[5], Lr[6]);
  Lr[5] = __builtin_amdgcn_fmed3f(key, Lr[4], Lr[5]);
  Lr[4] = __builtin_amdgcn_fmed3f(key, Lr[3], Lr[4]);
  Lr[3] = __builtin_amdgcn_fmed3f(key, Lr[2], Lr[3]);
  Lr[2] = __builtin_amdgcn_fmed3f(key, Lr[1], Lr[2]);
  Lr[1] = __builtin_amdgcn_fmed3f(key, Lr[0], Lr[1]);
  Lr[0] = fminf(key, Lr[0]);
}

// branchless insert into ascending sorted-8 of u64 keys (bubble, drops max)
__device__ __forceinline__ void ins8u(u64 (&L)[8], u64 v) {
  u64 c = v;
  #pragma unroll
  for (int j = 0; j < 8; ++j) {
    u64 lo = c < L[j] ? c : L[j];
    u64 hi = c < L[j] ? L[j] : c;
    L[j] = lo; c = hi;
  }
}

// async global->LDS, 16B per lane; LDS dest is wave-uniform base + lane*16
__device__ __forceinline__ void gl16(const char* g, char* l) {
  __builtin_amdgcn_global_load_lds(
      (const __attribute__((address_space(1))) unsigned int*)g,
      (__attribute__((address_space(3))) unsigned int*)l, 16, 0, 0);
}
// stage one 64-col tile (hi 8KB + lo 8KB) into a 16KB LDS buffer (256 thr)
__device__ __forceinline__ void stage64(const char* src_hi, char* dst, int t256) {
  const int w = t256 >> 6, lane = t256 & 63;
  const int off = w * 2048 + (lane << 4);
  gl16(src_hi + off,                 dst + w * 2048);
  gl16(src_hi + off + 1024,          dst + w * 2048 + 1024);
  gl16(src_hi + 16384 + off,         dst + 8192 + w * 2048);
  gl16(src_hi + 16384 + off + 1024,  dst + 8192 + w * 2048 + 1024);
}

// ---------------------------------------------------------------------------
// pre: ONE pass over x per 64-n segment (512 blocks, 2/CU):
//  - sq (ascending-c, one thread per n — BIT-IDENTICAL to R3-R13) + sqp + cnt=0
//  - fp16 hi/lo img bytes (identical swizzled layout)
//  - proj a/cc (identical fma order)
// ---------------------------------------------------------------------------
__global__ __launch_bounds__(256) void pre_kernel(const float* __restrict__ x,
                                                  const float* __restrict__ w,
                                                  float* __restrict__ sq,
                                                  float* __restrict__ sqp,
                                                  float* __restrict__ a,
                                                  float* __restrict__ cc,
                                                  char* __restrict__ img,
                                                  int* __restrict__ cnt) {
  __shared__ float xs[CDIM][64];     // 16KB [c][n']
  __shared__ float wa[CDIM][ODIM];   // 16KB
  __shared__ float wc[CDIM][ODIM];   // 16KB
  __shared__ char  limg[16384];      // 16KB (hi 8K + lo 8K for these 64 n)

  const int tid = threadIdx.x;
  const int blk = blockIdx.x;
  const int b = blk >> 6, seg = blk & 63;
  const int n0 = seg * 64;
  if (blk == 0 && tid == 0) *cnt = 0;

  const float* xb = x + (size_t)b * CDIM * NPTS;
  #pragma unroll
  for (int p = 0; p < 16; ++p) {
    int idx = p * 256 + tid;                 // 0..4095
    int c = idx >> 6, n = idx & 63;
    xs[c][n] = xb[(size_t)c * NPTS + n0 + n];
  }
  #pragma unroll
  for (int p = 0; p < 16; ++p) {
    int idx = p * 256 + tid;
    int o = idx & 63, c = idx >> 6;
    float w1 = w[o * 128 + c], w2 = w[o * 128 + 64 + c];
    wa[c][o] = w1 - w2;
    wc[c][o] = w2;
  }
  __syncthreads();

  // sq: ascending c per n, single thread per n (bit-identical)
  if (tid < 64) {
    float s = 0.f;
    #pragma unroll
    for (int c = 0; c < CDIM; ++c) { float v = xs[c][tid]; s += v * v; }
    int n = n0 + tid;
    sq[b * NPTS + n] = s;
    int t = n >> 6, j0 = n & 63;
    sqp[(((size_t)b * NT64 + t) * 16 + (j0 & 15)) * 4 + (j0 >> 4)] = s;
  }

  // proj: identical per-o accumulation order as R12/R13
  {
    const int og = tid >> 6, nl = tid & 63;
    float aa[16], ac[16];
    #pragma unroll
    for (int qq = 0; qq < 16; ++qq) { aa[qq] = ac[qq] = 0.f; }
    #pragma unroll 4
    for (int c = 0; c < CDIM; ++c) {
      float xv = xs[c][nl];
      #pragma unroll
      for (int q4 = 0; q4 < 4; ++q4) {
        float4 va = *(const float4*)&wa[c][og * 16 + q4 * 4];
        float4 vc = *(const float4*)&wc[c][og * 16 + q4 * 4];
        aa[q4*4+0] += va.x * xv; aa[q4*4+1] += va.y * xv;
        aa[q4*4+2] += va.z * xv; aa[q4*4+3] += va.w * xv;
        ac[q4*4+0] += vc.x * xv; ac[q4*4+1] += vc.y * xv;
        ac[q4*4+2] += vc.z * xv; ac[q4*4+3] += vc.w * xv;
      }
    }
    size_t ga = (size_t)(b * NPTS + n0 + nl) * ODIM + og * 16;
    #pragma unroll
    for (int q4 = 0; q4 < 4; ++q4) {
      *(float4*)&a [ga + q4 * 4] = *(float4*)&aa[q4 * 4];
      *(float4*)&cc[ga + q4 * 4] = *(float4*)&ac[q4 * 4];
    }
  }

  // img: identical bytes/layout to R12/R13
  {
    const int npl = tid & 63;
    const int half = tid >> 6;                // c-base half*16
    const int np128 = (seg & 1) * 64 + npl;
    const int sw = swz(np128) << 4;
    #pragma unroll
    for (int oct = 0; oct < 2; ++oct) {
      const int cb = half * 16 + oct * 8;
      f16x8 hv, lv;
      #pragma unroll
      for (int j = 0; j < 8; ++j) {
        float v = xs[cb + j][npl];
        f16 h = (f16)v;
        hv[j] = h;
        lv[j] = (f16)(v - (float)h);
      }
      int byt = (npl * 128 + cb * 2) ^ sw;    // within this 8KB half
      *(f16x8*)(limg + byt) = hv;
      *(f16x8*)(limg + 8192 + byt) = lv;
    }
  }
  __syncthreads();
  {
    char* dstbase = img + ((size_t)b * NT128 + (seg >> 1)) * 32768
                        + (size_t)(seg & 1) * 8192;
    #pragma unroll
    for (int i = 0; i < 2; ++i) {
      *(float4*)(dstbase + i * 4096 + tid * 16) =
          *(const float4*)(limg + i * 4096 + tid * 16);
      *(float4*)(dstbase + 16384 + i * 4096 + tid * 16) =
          *(const float4*)(limg + 8192 + i * 4096 + tid * 16);
    }
  }
}

// ---------------------------------------------------------------------------
// Fused dist+top20+OUT — compute BYTE-IDENTICAL to R13. Only change:
// amdgpu_waves_per_eu(4,4) pins the occupancy target to our real LDS-bound
// occupancy (2 blocks x 8 waves / CU = 4 waves/EU), giving the allocator a
// 128-VGPR budget with NO incentive to squeeze into 64 via AGPR offload
// (R13: VGPR_Count=64 < ~70 live values -> accvgpr read/write pairs around
// every med3 = the measured 3x VALU-issue inflation).
// ---------------------------------------------------------------------------
__global__
__attribute__((amdgpu_flat_work_group_size(512, 512)))
__attribute__((amdgpu_waves_per_eu(4, 4)))
void fused_knn(const char* __restrict__ img,
               const float* __restrict__ sq,
               const float* __restrict__ sqp,
               int* __restrict__ knn,
               int* __restrict__ list,
               int* __restrict__ cnt,
               const float* __restrict__ pa,
               const float* __restrict__ pcc,
               const float* __restrict__ gamma,
               const float* __restrict__ beta,
               const float* __restrict__ mean,
               const float* __restrict__ var,
               float* __restrict__ pout) {
  __shared__ char XB[2][2][16384];     // [grp][dbuf] — 64 KB

  const int tid  = threadIdx.x;
  const int grp  = tid >> 8;           // 0: tiles 0-31, 1: tiles 32-63
  const int t256 = tid & 255;
  const int lane = tid & 63;
  const int w4   = t256 >> 6;          // wave within group (0..3)
  const int q = lane >> 4;
  const int s = lane & 15;

  const int blk = blockIdx.x;
  const int b  = blk >> 6;
  const int r0 = (blk & 63) * 64;
  const char* imgb = img + (size_t)b * (NT128 * 32768);
  const float* sqb = sq + (size_t)b * NPTS;
  const float4* sqp4 = (const float4*)(sqp + (size_t)b * NT64 * 64);

  const int tb = grp * 32;             // group tile base
  #define TSRC(tile) (imgb + (size_t)((tile) >> 1) * 32768 + (size_t)((tile) & 1) * 8192)

  stage64(TSRC(tb), XB[grp][0], t256);   // group's tile 0

  f16x8 Ah[2], Al[2];
  {
    const int grow = r0 + w4 * 16 + s;
    const char* at = imgb + (size_t)(grow >> 7) * 32768;
    const int nn = grow & 127;
    const int swn = swz(nn) << 4;
    #pragma unroll
    for (int ks = 0; ks < 2; ++ks) {
      int byt = (nn * 128 + (ks * 32 + q * 8) * 2) ^ swn;
      Ah[ks] = *(const f16x8*)(at + byt);
      Al[ks] = *(const f16x8*)(at + 16384 + byt);
    }
  }

  float sqr[4];
  #pragma unroll
  for (int reg = 0; reg < 4; ++reg) sqr[reg] = sqb[r0 + w4 * 16 + q * 4 + reg];

  float L[4][8];
  #pragma unroll
  for (int reg = 0; reg < 4; ++reg)
    #pragma unroll
    for (int j = 0; j < 8; ++j) L[reg][j] = FINF;

  __syncthreads();                 // tile-0 staging drained (both groups)

  for (int t = 0; t < 32; ++t) {
    #pragma unroll
    for (int reg = 0; reg < 4; ++reg)
      #pragma unroll
      for (int jj = 0; jj < 8; ++jj)
        asm volatile("" : "+v"(L[reg][jj]));

    if (t + 1 < 32)
      stage64(TSRC(tb + t + 1), XB[grp][(t + 1) & 1], t256);
    const char* XBc = XB[grp][t & 1];
    const int tile = tb + t;
    const float4 sm4 = sqp4[tile * 16 + s];   // sq[tile*64 + e*16 + s]
    #pragma unroll
    for (int e = 0; e < 4; ++e) {
      const int j = e * 16 + s;
      const int swj = swz(j) << 4;
      f32x4 acc = {0.f, 0.f, 0.f, 0.f};
      #pragma unroll
      for (int ks = 0; ks < 2; ++ks) {
        int byt = (j * 128 + (ks * 32 + q * 8) * 2) ^ swj;
        f16x8 Bh = *(const f16x8*)(XBc + byt);
        f16x8 Bl = *(const f16x8*)(XBc + 8192 + byt);
        acc = __builtin_amdgcn_mfma_f32_16x16x32_f16(Ah[ks], Bh, acc, 0, 0, 0);
        acc = __builtin_amdgcn_mfma_f32_16x16x32_f16(Ah[ks], Bl, acc, 0, 0, 0);
        acc = __builtin_amdgcn_mfma_f32_16x16x32_f16(Al[ks], Bh, acc, 0, 0, 0);
      }
      asm volatile("" : "+v"(acc));
      const float sm = (&sm4.x)[e];
      const u32 klo = (u32)(tile * 4 + e);    // = mcol >> 4
      #pragma unroll
      for (int reg = 0; reg < 4; ++reg) {
        float v = (sqr[reg] + sm) - 2.0f * acc[reg];   // same expr as R4-R13
        float key = __uint_as_float((__float_as_uint(v) & 0xFFFFFF00u) | klo);
        insert_med3(L[reg], key);
      }
    }
    __syncthreads();
  }

  // merge: group-1 dumps lists; group-0 merges (exact union top-8)
  float* mbuf = (float*)XB;              // [0, 32768)
  int*   kbuf = (int*)((char*)XB + 32768);          // 64 x 20 ints
  float* tile = (float*)((char*)XB + 40960);        // 64 x 65 floats
  if (grp == 1) {
    #pragma unroll
    for (int reg = 0; reg < 4; ++reg)
      #pragma unroll
      for (int j = 0; j < 8; ++j)
        mbuf[((reg * 8 + j) * 4 + w4) * 64 + lane] = L[reg][j];
  }
  __syncthreads();

  if (grp == 0) {
    #pragma unroll
    for (int reg = 0; reg < 4; ++reg)
      #pragma unroll
      for (int j = 0; j < 8; ++j)
        insert_med3(L[reg], mbuf[((reg * 8 + j) * 4 + w4) * 64 + lane]);

    // pops: 21 rounds per row; certificates identical to R12/R13
    #pragma unroll
    for (int reg = 0; reg < 4; ++reg) {
      bool flg = false;
      int iA = 0, iB = 0;
      u32 k20 = 0, k21 = 0;
      for (int r = 0; r < KNN + 1; ++r) {
        float head = L[reg][0];
        float wkey = rmin16f(head);
        unsigned long long bal = __ballot(head == wkey);
        unsigned qm = (unsigned)((bal >> (q * 16)) & 0xFFFFull);
        int swin = __ffs((int)qm) - 1;
        flg = flg || ((qm & (qm - 1u)) != 0u);
        u32 kb = __float_as_uint(wkey);
        int idx = (int)(((kb & 0xFFu) << 4) | (u32)swin);
        if (r < 16) { if (s == r) iA = idx; }
        else if (r < KNN) { if (s == r - 16) iB = idx; }
        if (r == KNN - 1) k20 = kb;
        if (r == KNN)     k21 = kb;
        bool own = (head == wkey) && (s == swin);
        #pragma unroll
        for (int jj = 0; jj < 7; ++jj) L[reg][jj] = own ? L[reg][jj + 1] : L[reg][jj];
        L[reg][7] = own ? FINF : L[reg][7];
      }
      flg = flg || ((k20 >> 8) == (k21 >> 8));
      u32 alive = (__float_as_uint(L[reg][0]) == __float_as_uint(FINF)) ? 0u : 1u;
      flg = flg || (rmin16u(alive) == 0u);
      const int lrow = w4 * 16 + q * 4 + reg;
      size_t grow = (size_t)b * NPTS + r0 + lrow;
      knn[grow * KNN + s] = iA;
      kbuf[lrow * KNN + s] = iA;
      if (s < 4) { knn[grow * KNN + 16 + s] = iB; kbuf[lrow * KNN + 16 + s] = iB; }
      if (s == 0 && flg) { int p = atomicAdd(cnt, 1); list[p] = (int)grow; }
    }
  }
  __syncthreads();

  // inline out: all 8 waves, 8 rows each
  {
    const int wv8 = tid >> 6;
    float inv  = gamma[lane] / sqrtf(var[lane] + 1e-5f);
    float bias = beta[lane] - mean[lane] * inv;
    for (int rr = 0; rr < 8; ++rr) {
      int row = wv8 * 8 + rr;
      size_t base = (size_t)b * NPTS + r0 + row;
      float av = pa[base * ODIM + lane];
      const int* kr = kbuf + row * KNN;
      float m = -INFINITY;
      #pragma unroll
      for (int k = 0; k < KNN; ++k) {
        int jj = kr[k];
        m = fmaxf(m, av + pcc[((size_t)b * NPTS + jj) * ODIM + lane]);
      }
      float v = m * inv + bias;
      tile[row * 65 + lane] = v > 0.f ? v : 0.f;
    }
  }
  __syncthreads();
  #pragma unroll
  for (int t8 = 0; t8 < 8; ++t8) {
    int o = (tid >> 6) * 8 + t8;
    pout[((size_t)b * ODIM + o) * NPTS + r0 + lane] = tile[lane * 65 + o];
  }
  #undef TSRC
}

// ---------------------------------------------------------------------------
// Exact fp32 brute-force for flagged rows (R7-R13-validated) + out fixup.
// ---------------------------------------------------------------------------
__global__ __launch_bounds__(256) void fallback_knn(const float* __restrict__ x,
                                                    const float* __restrict__ sq,
                                                    const int* __restrict__ cnt,
                                                    const int* __restrict__ list,
                                                    int* __restrict__ knn,
                                                    const float* __restrict__ pa,
                                                    const float* __restrict__ pcc,
                                                    const float* __restrict__ gamma,
                                                    const float* __restrict__ beta,
                                                    const float* __restrict__ mean,
                                                    const float* __restrict__ var,
                                                    float* __restrict__ pout) {
  __shared__ float xrl[CDIM];
  __shared__ u64 cand[4 * KNN];
  __shared__ int kfix[KNN];
  const int tid = threadIdx.x, lane = tid & 63, wv = tid >> 6;
  const int count = *cnt;

  for (int it = blockIdx.x; it < count; it += gridDim.x) {
    const int g = list[it];
    const int b = g >> 12, r = g & (NPTS - 1);
    const float* xb  = x  + (size_t)b * CDIM * NPTS;
    const float* sqb = sq + (size_t)b * NPTS;
    if (tid < CDIM) xrl[tid] = xb[(size_t)tid * NPTS + r];
    __syncthreads();
    const float sqr = sqb[r];

    u64 L[8];
    #pragma unroll
    for (int j = 0; j < 8; ++j) L[j] = SENT;
    #pragma unroll
    for (int ii = 0; ii < 4; ++ii) {
      const int i = wv * 4 + ii;
      float a0 = 0.f, a1 = 0.f, a2 = 0.f, a3 = 0.f;
      const float* xp = xb + i * 256 + lane * 4;
      #pragma unroll
      for (int c4 = 0; c4 < 16; ++c4) {
        float4 xr4 = *(const float4*)&xrl[c4 * 4];
        #pragma unroll
        for (int j = 0; j < 4; ++j) {
          float4 xv = *(const float4*)(xp + (size_t)(c4 * 4 + j) * NPTS);
          float xr = (&xr4.x)[j];
          a0 += xr * xv.x; a1 += xr * xv.y; a2 += xr * xv.z; a3 += xr * xv.w;
        }
      }
      int mb = i * 256 + lane * 4;
      float4 sv = *(const float4*)(sqb + mb);
      ins8u(L, ((u64)flip_f32(sqr + sv.x - 2.0f * a0) << 12) | (unsigned)mb);
      ins8u(L, ((u64)flip_f32(sqr + sv.y - 2.0f * a1) << 12) | (unsigned)(mb + 1));
      ins8u(L, ((u64)flip_f32(sqr + sv.z - 2.0f * a2) << 12) | (unsigned)(mb + 2));
      ins8u(L, ((u64)flip_f32(sqr + sv.w - 2.0f * a3) << 12) | (unsigned)(mb + 3));
    }

    u64 last = 0; bool done = false;
    for (int rr = 0; rr < KNN; ++rr) {
      bool need = (L[0] == SENT) && !done;
      if (__any(need)) {
        if (need) {
          #pragma unroll
          for (int j = 0; j < 8; ++j) L[j] = SENT;
          for (int ii = 0; ii < 4; ++ii) {
            const int i = wv * 4 + ii;
            float a0 = 0.f, a1 = 0.f, a2 = 0.f, a3 = 0.f;
            const float* xp = xb + i * 256 + lane * 4;
            #pragma unroll
            for (int c4 = 0; c4 < 16; ++c4) {
              float4 xr4 = *(const float4*)&xrl[c4 * 4];
              #pragma unroll
              for (int j = 0; j < 4; ++j) {
                float4 xv = *(const float4*)(xp + (size_t)(c4 * 4 + j) * NPTS);
                float xr = (&xr4.x)[j];
                a0 += xr * xv.x; a1 += xr * xv.y; a2 += xr * xv.z; a3 += xr * xv.w;
              }
            }
            int mb = i * 256 + lane * 4;
            float4 sv = *(const float4*)(sqb + mb);
            u64 v;
            v = ((u64)flip_f32(sqr + sv.x - 2.0f * a0) << 12) | (unsigned)mb;       ins8u(L, v > last ? v : SENT);
            v = ((u64)flip_f32(sqr + sv.y - 2.0f * a1) << 12) | (unsigned)(mb + 1); ins8u(L, v > last ? v : SENT);
            v = ((u64)flip_f32(sqr + sv.z - 2.0f * a2) << 12) | (unsigned)(mb + 2); ins8u(L, v > last ? v : SENT);
            v = ((u64)flip_f32(sqr + sv.w - 2.0f * a3) << 12) | (unsigned)(mb + 3); ins8u(L, v > last ? v : SENT);
          }
          if (L[0] == SENT) done = true;
        }
      }
      unsigned keyH = (unsigned)(L[0] >> 12);
      unsigned wkey = wave_min_u32(keyH);
      unsigned mc   = (keyH == wkey) ? (unsigned)(L[0] & 0xFFF) : 0xFFFFFFFFu;
      unsigned wm   = wave_min_u32(mc);
      u64 wsel = ((u64)wkey << 12) | wm;
      if (lane == rr) cand[wv * KNN + rr] = wsel;
      bool win = (L[0] == wsel);
      #pragma unroll
      for (int j = 0; j < 7; ++j) L[j] = win ? L[j + 1] : L[j];
      L[7] = win ? SENT : L[7];
      last = wsel;
    }
    __syncthreads();

    if (wv == 0) {                       // merge 80 candidates -> top 20
      u64 c0 = cand[lane < 4 * KNN ? lane : 0];
      if (lane >= 4 * KNN) c0 = SENT;
      u64 c1 = (lane < 4 * KNN - 64) ? cand[64 + lane] : SENT;
      int myidx = 0;
      for (int rr = 0; rr < KNN; ++rr) {
        u64 mn = c0 < c1 ? c0 : c1;
        unsigned keyH = (unsigned)(mn >> 12);
        unsigned wkey = wave_min_u32(keyH);
        unsigned mc   = (keyH == wkey) ? (unsigned)(mn & 0xFFF) : 0xFFFFFFFFu;
        unsigned wm   = wave_min_u32(mc);
        u64 wsel = ((u64)wkey << 12) | wm;
        if (lane == rr) myidx = (int)wm;
        if (c0 == wsel)      { c0 = c1; c1 = SENT; }
        else if (c1 == wsel) { c1 = SENT; }
      }
      if (lane < KNN) {
        knn[(size_t)g * KNN + lane] = myidx;
        kfix[lane] = myidx;
      }
    }
    __syncthreads();

    if (wv == 0) {                       // out fixup for this row (lane = o)
      float inv  = gamma[lane] / sqrtf(var[lane] + 1e-5f);
      float bias = beta[lane] - mean[lane] * inv;
      float av = pa[(size_t)g * ODIM + lane];
      float m = -INFINITY;
      #pragma unroll
      for (int k = 0; k < KNN; ++k) {
        int jj = kfix[k];
        m = fmaxf(m, av + pcc[((size_t)b * NPTS + jj) * ODIM + lane]);
      }
      float v = m * inv + bias;
      pout[((size_t)b * ODIM + lane) * NPTS + r] = v > 0.f ? v : 0.f;
    }
    __syncthreads();
  }
}

// ---------------------------------------------------------------------------
extern "C" void kernel_launch(void* const* d_in, const int* in_sizes, int n_in,
                              void* d_out, int out_size, void* d_ws, size_t ws_size,
                              hipStream_t stream) {
  const float* x     = (const float*)d_in[0];
  const float* w     = (const float*)d_in[1];
  const float* gamma = (const float*)d_in[2];
  const float* beta  = (const float*)d_in[3];
  const float* mean  = (const float*)d_in[4];
  const float* var   = (const float*)d_in[5];
  float* out = (float*)d_out;

  char* wsb = (char*)d_ws;
  size_t off = 0;
  int*   knn   = (int*)(wsb + off);   off += (size_t)BDIM * NPTS * KNN * 4;   // 2.62 MB
  int*   list  = (int*)(wsb + off);   off += (size_t)BDIM * NPTS * 4;         // 0.13 MB
  int*   cnt   = (int*)(wsb + off);   off += 256;
  float* sqw   = (float*)(wsb + off); off += (size_t)BDIM * NPTS * 4;         // 0.13 MB
  float* sqp   = (float*)(wsb + off); off += (size_t)BDIM * NPTS * 4;         // 0.13 MB
  float* a     = (float*)(wsb + off); off += (size_t)BDIM * NPTS * ODIM * 4;  // 8 MB
  float* cc    = (float*)(wsb + off); off += (size_t)BDIM * NPTS * ODIM * 4;  // 8 MB
  char*  img   = wsb + off;           off += (size_t)BDIM * NT128 * 32768;    // 8 MB
  (void)ws_size;

  pre_kernel  <<<BDIM * NPTS / 64, 256, 0, stream>>>(x, w, sqw, sqp, a, cc, img, cnt);
  fused_knn   <<<512, 512, 0, stream>>>(img, sqw, sqp, knn, list, cnt,
                                        a, cc, gamma, beta, mean, var, out);
  fallback_knn<<<2048, 256, 0, stream>>>(x, sqw, cnt, list, knn,
                                         a, cc, gamma, beta, mean, var, out);
}